// Round 6
// baseline (4402.448 us; speedup 1.0000x reference)
//
#include <hip/hip_runtime.h>
#include <math.h>

// ---------------- constants ----------------
#define B_   128
#define T_   288
#define U_   256
#define H_   4
#define HD_  64
#define MT   (B_*T_)     // 36864 rows
#define EPSF 1e-6f

typedef _Float16 h2_t  __attribute__((ext_vector_type(2)));
typedef _Float16 f16x8 __attribute__((ext_vector_type(8)));
typedef float    f32x4 __attribute__((ext_vector_type(4)));

// ---------------- generic tiled fp32 GEMM ----------------
// C[M,N](ldc) = alpha * A[M,K](lda) @ B[K,N](ldb)  (+ bias[N])
// TB=true: B given row-major [N,K] (i.e. compute A @ B^T)
// Batched via blockIdx.z: z1=z/zdiv, z2=z%zdiv; base += z1*s?1 + z2*s?2.
template<bool TB>
__global__ __launch_bounds__(256) void gemm_kernel(
    const float* __restrict__ A, const float* __restrict__ Bm,
    float* __restrict__ C, const float* __restrict__ bias,
    int M, int N, int K, int lda, int ldb, int ldc,
    long sA1, long sA2, long sB1, long sB2, long sC1, long sC2,
    int zdiv, float alpha)
{
  int z  = blockIdx.z;
  int z1 = z / zdiv, z2 = z - z1 * zdiv;
  A  += (long)z1*sA1 + (long)z2*sA2;
  Bm += (long)z1*sB1 + (long)z2*sB2;
  C  += (long)z1*sC1 + (long)z2*sC2;

  __shared__ float As[16][68];
  __shared__ float Bs[16][68];

  const int tid = threadIdx.x;
  const int tx  = tid & 15;     // 0..15 (n)
  const int ty  = tid >> 4;     // 0..15 (m)
  const int rowBase = blockIdx.y * 64;
  const int colBase = blockIdx.x * 64;

  float acc[4][4] = {};

  const int lr = tid >> 2;         // 0..63
  const int lk = (tid & 3) << 2;   // 0,4,8,12

  for (int k0 = 0; k0 < K; k0 += 16) {
    // A tile: [64 rows][16 k], stored transposed As[k][m]
    {
      float4 a4 = {0.f,0.f,0.f,0.f};
      int ar = rowBase + lr;
      if (ar < M) a4 = *(const float4*)(A + (long)ar*lda + k0 + lk);
      As[lk+0][lr]=a4.x; As[lk+1][lr]=a4.y; As[lk+2][lr]=a4.z; As[lk+3][lr]=a4.w;
    }
    if (TB) {
      float4 b4 = {0.f,0.f,0.f,0.f};
      int bn = colBase + lr;
      if (bn < N) b4 = *(const float4*)(Bm + (long)bn*ldb + k0 + lk);
      Bs[lk+0][lr]=b4.x; Bs[lk+1][lr]=b4.y; Bs[lk+2][lr]=b4.z; Bs[lk+3][lr]=b4.w;
    } else {
      int bk  = tid >> 4;          // 0..15
      int bn4 = (tid & 15) << 2;   // 0..60
      float4 b4 = {0.f,0.f,0.f,0.f};
      if (colBase + bn4 < N) b4 = *(const float4*)(Bm + (long)(k0+bk)*ldb + colBase + bn4);
      *(float4*)(&Bs[bk][bn4]) = b4;
    }
    __syncthreads();
    #pragma unroll
    for (int k = 0; k < 16; ++k) {
      float4 av = *(const float4*)(&As[k][ty<<2]);
      float4 bv = *(const float4*)(&Bs[k][tx<<2]);
      acc[0][0]+=av.x*bv.x; acc[0][1]+=av.x*bv.y; acc[0][2]+=av.x*bv.z; acc[0][3]+=av.x*bv.w;
      acc[1][0]+=av.y*bv.x; acc[1][1]+=av.y*bv.y; acc[1][2]+=av.y*bv.z; acc[1][3]+=av.y*bv.w;
      acc[2][0]+=av.z*bv.x; acc[2][1]+=av.z*bv.y; acc[2][2]+=av.z*bv.z; acc[2][3]+=av.z*bv.w;
      acc[3][0]+=av.w*bv.x; acc[3][1]+=av.w*bv.y; acc[3][2]+=av.w*bv.z; acc[3][3]+=av.w*bv.w;
    }
    __syncthreads();
  }

  const int cn = colBase + (tx << 2);
  if (cn < N) {
    float4 bb = {0.f,0.f,0.f,0.f};
    if (bias) bb = *(const float4*)(bias + cn);
    #pragma unroll
    for (int i = 0; i < 4; ++i) {
      int r = rowBase + (ty << 2) + i;
      if (r < M) {
        float4 v;
        v.x = acc[i][0]*alpha + bb.x;
        v.y = acc[i][1]*alpha + bb.y;
        v.z = acc[i][2]*alpha + bb.z;
        v.w = acc[i][3]*alpha + bb.w;
        *(float4*)(C + (long)r*ldc + cn) = v;
      }
    }
  }
}

// ---------------- LayerNorm over 256 cols ----------------
// out[row] = LN(in[row] (+skip_pre[row])) * s + b (+ skip_post[row])
__global__ __launch_bounds__(256) void ln256_kernel(
    const float* __restrict__ in, const float* __restrict__ skip_pre,
    const float* __restrict__ skip_post,
    const float* __restrict__ s, const float* __restrict__ b,
    float* __restrict__ out)
{
  __shared__ float sb[4];
  long row = blockIdx.x;
  int tid  = threadIdx.x;
  long idx = row*256 + tid;
  float v = in[idx];
  if (skip_pre) v += skip_pre[idx];
  float m = v;
  for (int o = 32; o; o >>= 1) m += __shfl_xor(m, o);
  if ((tid & 63) == 0) sb[tid >> 6] = m;
  __syncthreads();
  m = (sb[0]+sb[1]+sb[2]+sb[3]) * (1.f/256.f);
  __syncthreads();
  float d = v - m;
  float var = d*d;
  for (int o = 32; o; o >>= 1) var += __shfl_xor(var, o);
  if ((tid & 63) == 0) sb[tid >> 6] = var;
  __syncthreads();
  var = (sb[0]+sb[1]+sb[2]+sb[3]) * (1.f/256.f);
  float y = d * rsqrtf(var + EPSF) * s[tid] + b[tid];
  if (skip_post) y += skip_post[idx];
  out[idx] = y;
}

// ---------------- GRU scan: MFMA, 4 batches / 16 waves ----------------
// One time step = one [16,256]@[256,768] GEMM on the matrix pipe (rows
// 4..15 of M are self-contained padding). 1024 threads = 16 waves; wave w
// owns units [16w,16w+16) x 3 gates (24 MFMAs/step/wave).
//
// ROUND-6 FIXES (rounds 3-5 all spilled the weights to scratch):
//  1. amdgpu_waves_per_eu(4,4) pins the RA budget at 512/4 = 128 VGPRs;
//     without it the backend's memory-bound heuristic targets 2x occupancy
//     and halves the budget (observed: 128-of-256, 64-of-128).
//  2. All 24 weight fragments are INDIVIDUALLY NAMED f16x8 variables
//     (no arrays -> nothing for the allocator to demote as a unit).
//
// C/D layout (verified rounds 3-5): col=lane&15 (unit), row=(lane>>4)*4+r
// (batch row m=lq*4+r) -> phase B is register-local, ONE barrier/step.
// h in LDS, double-buffered, layout (halves):
//   F(m,k) = (k>>5)*512 + (((k>>3)&3)^(m&3))*128 + m*8 + (k&7)
// Read (m=l16, k=kk*32+lq*8+e): conflict-free lane-linear ds_read_b128.
// Write (m=lq*4+r, k=16*wid+l16): scalar u16, ~8-way (accepted).
__global__ __attribute__((amdgpu_waves_per_eu(4, 4)))
__launch_bounds__(1024) void gru_mfma_kernel(
    const float* __restrict__ xg,   // [B,T,768]
    const float* __restrict__ Wh,   // [256,768]
    const float* __restrict__ bhn,  // [256]
    float* __restrict__ g)          // [B,T,256]
{
  const int tid  = threadIdx.x;
  const int wid  = tid >> 6;        // 0..15
  const int lane = tid & 63;
  const int l16  = lane & 15;
  const int lq   = lane >> 4;       // 0..3
  const int bbase = blockIdx.x * 4; // 4 real batches per block

  __shared__ __align__(16) _Float16 hfrag[2][4096];   // 8KB per buffer

  // ---- weight fragments as named registers: k = kk*32 + lq*8 + e ----
#define LOAD_BF(VAR, GA, KK) { \
    f16x8 v_; \
    const int col_ = (GA)*256 + wid*16 + l16; \
    const int kb_  = (KK)*32 + lq*8; \
    _Pragma("unroll") \
    for (int e_ = 0; e_ < 8; ++e_) \
      v_[e_] = (_Float16)Wh[(long)(kb_+e_)*768 + col_]; \
    VAR = v_; }

  f16x8 br0,br1,br2,br3,br4,br5,br6,br7;
  f16x8 bz0,bz1,bz2,bz3,bz4,bz5,bz6,bz7;
  f16x8 bn0,bn1,bn2,bn3,bn4,bn5,bn6,bn7;
  LOAD_BF(br0,0,0) LOAD_BF(br1,0,1) LOAD_BF(br2,0,2) LOAD_BF(br3,0,3)
  LOAD_BF(br4,0,4) LOAD_BF(br5,0,5) LOAD_BF(br6,0,6) LOAD_BF(br7,0,7)
  LOAD_BF(bz0,1,0) LOAD_BF(bz1,1,1) LOAD_BF(bz2,1,2) LOAD_BF(bz3,1,3)
  LOAD_BF(bz4,1,4) LOAD_BF(bz5,1,5) LOAD_BF(bz6,1,6) LOAD_BF(bz7,1,7)
  LOAD_BF(bn0,2,0) LOAD_BF(bn1,2,1) LOAD_BF(bn2,2,2) LOAD_BF(bn3,2,3)
  LOAD_BF(bn4,2,4) LOAD_BF(bn5,2,5) LOAD_BF(bn6,2,6) LOAD_BF(bn7,2,7)
#undef LOAD_BF

  const float bnb = bhn[wid*16 + l16];

  for (int i = tid; i < 4096; i += 1024) hfrag[0][i] = (_Float16)0.f;

  // ---- per-lane state: unit u = wid*16+l16, batch rows m = lq*4+r ----
  float hp0 = 0.f, hp1 = 0.f, hp2 = 0.f, hp3 = 0.f;
  float xn0 = 0.f, xn1 = 0.f, xn2 = 0.f, xn3 = 0.f;
  f32x4 accR = {0,0,0,0}, accZ = {0,0,0,0}, accN = {0,0,0,0};

  const long xgB = (long)T_ * 768;
  const float* xgb = xg + (long)bbase*xgB + wid*16 + l16;
  float*       gb  = g  + (long)bbase*T_*256 + wid*16 + l16;

  // t=0 gate inputs (real rows lq==0 only)
#define PREFETCH(R, XN, TT) { \
    float vr_ = 0.f, vz_ = 0.f, vn_ = 0.f; \
    if (lq == 0) { \
      const float* p_ = xgb + (long)(R)*xgB + (long)(TT)*768; \
      vr_ = p_[0]; vz_ = p_[256]; vn_ = p_[512]; \
    } \
    accR[R] = vr_; accZ[R] = vz_; XN = vn_; accN[R] = 0.f; }

  PREFETCH(0, xn0, 0) PREFETCH(1, xn1, 0) PREFETCH(2, xn2, 0) PREFETCH(3, xn3, 0)
  __syncthreads();

  // read base (halves): conflict-free lane-linear pattern
  const int rbase = ((lq ^ (l16 & 3)) << 7) + (l16 << 3);
  // write pieces: region(r) = ((2*wid + (l16>>3)) ^ r) & 3
  const int wreg  = 2*wid + (l16 >> 3);
  const int wbase = (wid >> 1)*512 + (l16 & 7);

#define STEP_KK(KK, BR, BZ, BN) { \
    f16x8 af_ = *(const f16x8*)&hfrag[cb][((KK) << 9) + rbase]; \
    accN = __builtin_amdgcn_mfma_f32_16x16x32_f16(af_, BN, accN, 0, 0, 0); \
    accR = __builtin_amdgcn_mfma_f32_16x16x32_f16(af_, BR, accR, 0, 0, 0); \
    accZ = __builtin_amdgcn_mfma_f32_16x16x32_f16(af_, BZ, accZ, 0, 0, 0); }

#define PHASE_B(R, HP, XN, TT) { \
    const float rr_ = 1.f / (1.f + __expf(-accR[R])); \
    const float z_  = 1.f / (1.f + __expf(-accZ[R])); \
    const float nx_ = XN + rr_ * (accN[R] + bnb); \
    const float e2_ = __expf(2.f * nx_); \
    const float nv_ = (e2_ - 1.f) / (e2_ + 1.f); \
    const float hn_ = (1.f - z_) * nv_ + z_ * HP; \
    HP = hn_; \
    const int m_ = lq*4 + (R); \
    hfrag[cb ^ 1][wbase + (((wreg ^ (R)) & 3) << 7) + m_*8] = (_Float16)hn_; \
    if (lq == 0) gb[(long)(R)*T_*256 + (long)(TT)*256] = hn_; }

  int cb = 0;
  for (int t = 0; t < T_; ++t) {
    // ---- phase A: 24 MFMAs; A-frags conflict-free from LDS ----
    STEP_KK(0, br0, bz0, bn0)
    STEP_KK(1, br1, bz1, bn1)
    STEP_KK(2, br2, bz2, bn2)
    STEP_KK(3, br3, bz3, bn3)
    STEP_KK(4, br4, bz4, bn4)
    STEP_KK(5, br5, bz5, bn5)
    STEP_KK(6, br6, bz6, bn6)
    STEP_KK(7, br7, bz7, bn7)

    // ---- phase B + next-step prefetch straight into accumulators ----
    const int tn = (t < T_ - 1) ? (t + 1) : t;   // uniform clamp, no branch
    PHASE_B(0, hp0, xn0, t)  PREFETCH(0, xn0, tn)
    PHASE_B(1, hp1, xn1, t)  PREFETCH(1, xn1, tn)
    PHASE_B(2, hp2, xn2, t)  PREFETCH(2, xn2, tn)
    PHASE_B(3, hp3, xn3, t)  PREFETCH(3, xn3, tn)

    __syncthreads();   // publish hfrag[cb^1] for next step's phase A
    cb ^= 1;
  }
#undef STEP_KK
#undef PHASE_B
#undef PREFETCH
}

// ---------------- softmax over 288 cols, in place ----------------
__global__ __launch_bounds__(128) void softmax288_kernel(float* __restrict__ S)
{
  __shared__ float sb[2];
  long row = blockIdx.x;
  float* p = S + row * T_;
  int tid = threadIdx.x;
  float v0 = p[tid], v1 = p[tid+128];
  float v2 = (tid < 32) ? p[tid+256] : -1e30f;
  float mx = fmaxf(fmaxf(v0, v1), v2);
  for (int o = 32; o; o >>= 1) mx = fmaxf(mx, __shfl_xor(mx, o));
  if ((tid & 63) == 0) sb[tid >> 6] = mx;
  __syncthreads();
  mx = fmaxf(sb[0], sb[1]);
  __syncthreads();
  v0 = __expf(v0 - mx);
  v1 = __expf(v1 - mx);
  v2 = (tid < 32) ? __expf(v2 - mx) : 0.f;
  float sm = v0 + v1 + v2;
  for (int o = 32; o; o >>= 1) sm += __shfl_xor(sm, o);
  if ((tid & 63) == 0) sb[tid >> 6] = sm;
  __syncthreads();
  float inv = 1.f / (sb[0] + sb[1]);
  p[tid] = v0*inv; p[tid+128] = v1*inv;
  if (tid < 32) p[tid+256] = v2*inv;
}

// ---------------- mean over T ----------------
__global__ __launch_bounds__(256) void meanT_kernel(
    const float* __restrict__ x, float* __restrict__ xm)
{
  int b = blockIdx.x, u = threadIdx.x;
  const float* p = x + (long)b*T_*U_ + u;
  float s = 0.f;
  for (int t = 0; t < T_; ++t) s += p[(long)t*U_];
  xm[b*U_ + u] = s * (1.f/(float)T_);
}

// ---------------- MLP head: one block per batch ----------------
__global__ __launch_bounds__(128) void head_kernel(
    const float* __restrict__ xm, const float* __restrict__ other,
    const float* __restrict__ m1W, const float* __restrict__ m1b,
    const float* __restrict__ l1s, const float* __restrict__ l1b,
    const float* __restrict__ m2W, const float* __restrict__ m2b,
    const float* __restrict__ l2s, const float* __restrict__ l2b,
    const float* __restrict__ oW,  const float* __restrict__ ob,
    float* __restrict__ outp)
{
  __shared__ float c[320];
  __shared__ float h1[128];
  __shared__ float sb[2];
  int b = blockIdx.x, tid = threadIdx.x;
  c[tid]       = xm[b*256 + tid];
  c[tid + 128] = xm[b*256 + tid + 128];
  if (tid < 64) c[256 + tid] = other[b*64 + tid];
  __syncthreads();
  // h1 = LN(relu(c @ m1W + m1b))
  float s = m1b[tid];
  for (int i = 0; i < 320; ++i) s += c[i] * m1W[i*128 + tid];
  s = fmaxf(s, 0.f);
  float m = s;
  for (int o = 32; o; o >>= 1) m += __shfl_xor(m, o);
  if ((tid & 63) == 0) sb[tid >> 6] = m;
  __syncthreads();
  m = (sb[0] + sb[1]) * (1.f/128.f);
  __syncthreads();
  float d = s - m, var = d*d;
  for (int o = 32; o; o >>= 1) var += __shfl_xor(var, o);
  if ((tid & 63) == 0) sb[tid >> 6] = var;
  __syncthreads();
  var = (sb[0] + sb[1]) * (1.f/128.f);
  h1[tid] = d * rsqrtf(var + EPSF) * l1s[tid] + l1b[tid];
  __syncthreads();
  // h2 = LN(relu(h1 @ m2W + m2b)), then out = h2 @ oW + ob  (wave 0 only)
  if (tid < 64) {
    float s2 = m2b[tid];
    for (int i = 0; i < 128; ++i) s2 += h1[i] * m2W[i*64 + tid];
    s2 = fmaxf(s2, 0.f);
    float m2 = s2;
    for (int o = 32; o; o >>= 1) m2 += __shfl_xor(m2, o);
    m2 *= (1.f/64.f);
    float d2 = s2 - m2, v2 = d2*d2;
    for (int o = 32; o; o >>= 1) v2 += __shfl_xor(v2, o);
    v2 *= (1.f/64.f);
    float h2v = d2 * rsqrtf(v2 + EPSF) * l2s[tid] + l2b[tid];
    float y = h2v * oW[tid];
    for (int o = 32; o; o >>= 1) y += __shfl_xor(y, o);
    if (tid == 0) outp[b] = y + ob[0];
  }
}

// ---------------- host orchestration ----------------
static inline void gemm_nn(hipStream_t st, const float* A, const float* Bm, float* C,
                           const float* bias, int M, int N, int K,
                           int lda, int ldb, int ldc, float alpha)
{
  dim3 g((N + 63)/64, (M + 63)/64, 1);
  gemm_kernel<false><<<g, 256, 0, st>>>(A, Bm, C, bias, M, N, K, lda, ldb, ldc,
                                        0,0,0,0,0,0, 1, alpha);
}

extern "C" void kernel_launch(void* const* d_in, const int* in_sizes, int n_in,
                              void* d_out, int out_size, void* d_ws, size_t ws_size,
                              hipStream_t stream)
{
  const float* cgm   = (const float*)d_in[0];
  const float* other = (const float*)d_in[1];
  const float* d0_W  = (const float*)d_in[2];
  const float* d0_b  = (const float*)d_in[3];
  const float* ln0_s = (const float*)d_in[4];
  const float* ln0_b = (const float*)d_in[5];
  const float* gWi   = (const float*)d_in[6];
  const float* gbi   = (const float*)d_in[7];
  const float* gWh   = (const float*)d_in[8];
  const float* gbhn  = (const float*)d_in[9];
  const float* ln1_s = (const float*)d_in[10];
  const float* ln1_b = (const float*)d_in[11];
  const float* Wq    = (const float*)d_in[12];
  const float* bq    = (const float*)d_in[13];
  const float* Wk    = (const float*)d_in[14];
  const float* bk    = (const float*)d_in[15];
  const float* Wv    = (const float*)d_in[16];
  const float* bv    = (const float*)d_in[17];
  const float* Wo    = (const float*)d_in[18];
  const float* bo    = (const float*)d_in[19];
  const float* ln2_s = (const float*)d_in[20];
  const float* ln2_b = (const float*)d_in[21];
  const float* m1W   = (const float*)d_in[22];
  const float* m1b   = (const float*)d_in[23];
  const float* l1s   = (const float*)d_in[24];
  const float* l1b   = (const float*)d_in[25];
  const float* m2W   = (const float*)d_in[26];
  const float* m2b   = (const float*)d_in[27];
  const float* l2s   = (const float*)d_in[28];
  const float* l2b   = (const float*)d_in[29];
  const float* oW    = (const float*)d_in[30];
  const float* ob    = (const float*)d_in[31];
  float* out = (float*)d_out;

  // workspace layout (floats); total ~231 MB
  float* ws    = (float*)d_ws;
  float* big   = ws;                  // 28,311,552  (xg, later qkv, later wo tmp)
  float* x     = big  + 28311552;     //  9,437,184
  float* go    = x    +  9437184;     //  9,437,184  (gru out, later attn out)
  float* Sbuf  = go   +  9437184;     // 10,616,832  (scores, 32-batch chunk)
  float* xmean = Sbuf + 10616832;     //     32,768
  (void)ws_size; (void)in_sizes; (void)n_in; (void)out_size;

  // x = LN(cgm @ d0_W + d0_b)
  gemm_nn(stream, cgm, d0_W, big, d0_b, MT, 256, 16, 16, 256, 256, 1.f);
  ln256_kernel<<<MT, 256, 0, stream>>>(big, nullptr, nullptr, ln0_s, ln0_b, x);

  for (int i = 0; i < 2; ++i) {
    const float* Wi_i = gWi + (long)i*196608;
    const float* Wh_i = gWh + (long)i*196608;

    // xg = x @ Wi + bi
    gemm_nn(stream, x, Wi_i, big, gbi + i*768, MT, 768, 256, 256, 768, 768, 1.f);
    // GRU scan (MFMA, 4 batches per workgroup, 32 workgroups, 1024 thr)
    gru_mfma_kernel<<<32, 1024, 0, stream>>>(big, Wh_i, gbhn + i*256, go);
    // x = LN(g) + x
    ln256_kernel<<<MT, 256, 0, stream>>>(go, nullptr, x, ln1_s + i*256, ln1_b + i*256, x);

    // qkv into big: row layout [q(256) | k(256) | v(256)]
    gemm_nn(stream, x, Wq + (long)i*65536, big,       bq + i*256, MT, 256, 256, 256, 256, 768, 1.f);
    gemm_nn(stream, x, Wk + (long)i*65536, big + 256, bk + i*256, MT, 256, 256, 256, 256, 768, 1.f);
    gemm_nn(stream, x, Wv + (long)i*65536, big + 512, bv + i*256, MT, 256, 256, 256, 256, 768, 1.f);

    // attention in 4 chunks of 32 batches (S buffer = 42.5 MB)
    for (int cb = 0; cb < 4; ++cb) {
      const float* qb = big + (long)cb*32*T_*768;
      {
        dim3 g(5, 5, 128);   // z = local_b*4 + head
        gemm_kernel<true><<<g, 256, 0, stream>>>(
            qb, qb + 256, Sbuf, nullptr,
            T_, T_, 64, 768, 768, T_,
            (long)T_*768, 64, (long)T_*768, 64, (long)4*T_*T_, (long)T_*T_,
            4, 0.125f);
      }
      softmax288_kernel<<<32*4*T_, 128, 0, stream>>>(Sbuf);
      {
        dim3 g(1, 5, 128);
        gemm_kernel<false><<<g, 256, 0, stream>>>(
            Sbuf, qb + 512, go + (long)cb*32*T_*256, nullptr,
            T_, 64, T_, T_, 768, 256,
            (long)4*T_*T_, (long)T_*T_, (long)T_*768, 64, (long)T_*256, 64,
            4, 1.f);
      }
    }

    // a = o @ Wo + bo ; x = LN(a + x)
    gemm_nn(stream, go, Wo + (long)i*65536, big, bo + i*256, MT, 256, 256, 256, 256, 256, 1.f);
    ln256_kernel<<<MT, 256, 0, stream>>>(big, x, nullptr, ln2_s + i*256, ln2_b + i*256, x);
  }

  meanT_kernel<<<128, 256, 0, stream>>>(x, xmean);
  head_kernel<<<128, 128, 0, stream>>>(xmean, other, m1W, m1b, l1s, l1b,
                                       m2W, m2b, l2s, l2b, oW, ob, out);
}

// Round 7
// 2683.910 us; speedup vs baseline: 1.6403x; 1.6403x over previous
//
#include <hip/hip_runtime.h>
#include <math.h>

// ---------------- constants ----------------
#define B_   128
#define T_   288
#define U_   256
#define H_   4
#define HD_  64
#define MT   (B_*T_)     // 36864 rows
#define EPSF 1e-6f

typedef _Float16 h2_t __attribute__((ext_vector_type(2)));

#if defined(__has_builtin)
#  if __has_builtin(__builtin_amdgcn_fdot2)
#    define HAS_FDOT2 1
#  endif
#endif
#ifndef HAS_FDOT2
#  define HAS_FDOT2 0
#endif

// ---------------- generic tiled fp32 GEMM ----------------
// C[M,N](ldc) = alpha * A[M,K](lda) @ B[K,N](ldb)  (+ bias[N])
// TB=true: B given row-major [N,K] (i.e. compute A @ B^T)
// Batched via blockIdx.z: z1=z/zdiv, z2=z%zdiv; base += z1*s?1 + z2*s?2.
template<bool TB>
__global__ __launch_bounds__(256) void gemm_kernel(
    const float* __restrict__ A, const float* __restrict__ Bm,
    float* __restrict__ C, const float* __restrict__ bias,
    int M, int N, int K, int lda, int ldb, int ldc,
    long sA1, long sA2, long sB1, long sB2, long sC1, long sC2,
    int zdiv, float alpha)
{
  int z  = blockIdx.z;
  int z1 = z / zdiv, z2 = z - z1 * zdiv;
  A  += (long)z1*sA1 + (long)z2*sA2;
  Bm += (long)z1*sB1 + (long)z2*sB2;
  C  += (long)z1*sC1 + (long)z2*sC2;

  __shared__ float As[16][68];
  __shared__ float Bs[16][68];

  const int tid = threadIdx.x;
  const int tx  = tid & 15;     // 0..15 (n)
  const int ty  = tid >> 4;     // 0..15 (m)
  const int rowBase = blockIdx.y * 64;
  const int colBase = blockIdx.x * 64;

  float acc[4][4] = {};

  const int lr = tid >> 2;         // 0..63
  const int lk = (tid & 3) << 2;   // 0,4,8,12

  for (int k0 = 0; k0 < K; k0 += 16) {
    // A tile: [64 rows][16 k], stored transposed As[k][m]
    {
      float4 a4 = {0.f,0.f,0.f,0.f};
      int ar = rowBase + lr;
      if (ar < M) a4 = *(const float4*)(A + (long)ar*lda + k0 + lk);
      As[lk+0][lr]=a4.x; As[lk+1][lr]=a4.y; As[lk+2][lr]=a4.z; As[lk+3][lr]=a4.w;
    }
    if (TB) {
      float4 b4 = {0.f,0.f,0.f,0.f};
      int bn = colBase + lr;
      if (bn < N) b4 = *(const float4*)(Bm + (long)bn*ldb + k0 + lk);
      Bs[lk+0][lr]=b4.x; Bs[lk+1][lr]=b4.y; Bs[lk+2][lr]=b4.z; Bs[lk+3][lr]=b4.w;
    } else {
      int bk  = tid >> 4;          // 0..15
      int bn4 = (tid & 15) << 2;   // 0..60
      float4 b4 = {0.f,0.f,0.f,0.f};
      if (colBase + bn4 < N) b4 = *(const float4*)(Bm + (long)(k0+bk)*ldb + colBase + bn4);
      *(float4*)(&Bs[bk][bn4]) = b4;
    }
    __syncthreads();
    #pragma unroll
    for (int k = 0; k < 16; ++k) {
      float4 av = *(const float4*)(&As[k][ty<<2]);
      float4 bv = *(const float4*)(&Bs[k][tx<<2]);
      acc[0][0]+=av.x*bv.x; acc[0][1]+=av.x*bv.y; acc[0][2]+=av.x*bv.z; acc[0][3]+=av.x*bv.w;
      acc[1][0]+=av.y*bv.x; acc[1][1]+=av.y*bv.y; acc[1][2]+=av.y*bv.z; acc[1][3]+=av.y*bv.w;
      acc[2][0]+=av.z*bv.x; acc[2][1]+=av.z*bv.y; acc[2][2]+=av.z*bv.z; acc[2][3]+=av.z*bv.w;
      acc[3][0]+=av.w*bv.x; acc[3][1]+=av.w*bv.y; acc[3][2]+=av.w*bv.z; acc[3][3]+=av.w*bv.w;
    }
    __syncthreads();
  }

  const int cn = colBase + (tx << 2);
  if (cn < N) {
    float4 bb = {0.f,0.f,0.f,0.f};
    if (bias) bb = *(const float4*)(bias + cn);
    #pragma unroll
    for (int i = 0; i < 4; ++i) {
      int r = rowBase + (ty << 2) + i;
      if (r < M) {
        float4 v;
        v.x = acc[i][0]*alpha + bb.x;
        v.y = acc[i][1]*alpha + bb.y;
        v.z = acc[i][2]*alpha + bb.z;
        v.w = acc[i][3]*alpha + bb.w;
        *(float4*)(C + (long)r*ldc + cn) = v;
      }
    }
  }
}

// ---------------- QKV weight/bias pack: [256,768] = Wq|Wk|Wv ----------------
__global__ __launch_bounds__(256) void packqkv_kernel(
    const float* __restrict__ Wq, const float* __restrict__ Wk,
    const float* __restrict__ Wv, const float* __restrict__ bq,
    const float* __restrict__ bk, const float* __restrict__ bv,
    float* __restrict__ wp, float* __restrict__ bp)
{
  int idx = blockIdx.x * 256 + threadIdx.x;
  if (idx < 196608) {
    int k = idx / 768, c = idx - k * 768;
    float v;
    if (c < 256)      v = Wq[k*256 + c];
    else if (c < 512) v = Wk[k*256 + (c - 256)];
    else              v = Wv[k*256 + (c - 512)];
    wp[idx] = v;
  }
  if (idx < 768) {
    float v;
    if (idx < 256)      v = bq[idx];
    else if (idx < 512) v = bk[idx - 256];
    else                v = bv[idx - 512];
    bp[idx] = v;
  }
}

// ---------------- LayerNorm over 256 cols: one wave per row ----------------
// out[row] = LN(in[row] (+skip_pre[row])) * s + b (+ skip_post[row])
// 4 rows per 256-thread block; float4 per lane; shuffle-only reduction.
__global__ __launch_bounds__(256) void ln256_kernel(
    const float* __restrict__ in, const float* __restrict__ skip_pre,
    const float* __restrict__ skip_post,
    const float* __restrict__ s, const float* __restrict__ b,
    float* __restrict__ out)
{
  const int wid  = threadIdx.x >> 6;
  const int lane = threadIdx.x & 63;
  const long row  = (long)blockIdx.x * 4 + wid;
  const long base = row * 256 + lane * 4;

  float4 v = *(const float4*)(in + base);
  if (skip_pre) {
    float4 sp = *(const float4*)(skip_pre + base);
    v.x += sp.x; v.y += sp.y; v.z += sp.z; v.w += sp.w;
  }
  float m = v.x + v.y + v.z + v.w;
  for (int o = 32; o; o >>= 1) m += __shfl_xor(m, o);
  m *= (1.f/256.f);
  float4 d = { v.x - m, v.y - m, v.z - m, v.w - m };
  float var = d.x*d.x + d.y*d.y + d.z*d.z + d.w*d.w;
  for (int o = 32; o; o >>= 1) var += __shfl_xor(var, o);
  var *= (1.f/256.f);
  const float inv = rsqrtf(var + EPSF);
  float4 sv = *(const float4*)(s + lane*4);
  float4 bv = *(const float4*)(b + lane*4);
  float4 y;
  y.x = d.x*inv*sv.x + bv.x;
  y.y = d.y*inv*sv.y + bv.y;
  y.z = d.z*inv*sv.z + bv.z;
  y.w = d.w*inv*sv.w + bv.w;
  if (skip_post) {
    float4 sp = *(const float4*)(skip_post + base);
    y.x += sp.x; y.y += sp.y; y.z += sp.z; y.w += sp.w;
  }
  *(float4*)(out + base) = y;
}

// ---------------- GRU scan: one workgroup per batch (round-0 kernel) ----
// Wh held register-resident as packed f16 pairs (96 VGPRs/thread),
// fp32 accumulation via v_dot2_f32_f16. h kept fp32 (master) + f16 (dot input).
__global__ __launch_bounds__(1024, 1) void gru_scan_kernel(
    const float* __restrict__ xg,   // [B,T,768]
    const float* __restrict__ Wh,   // [256,768]
    const float* __restrict__ bhn,  // [256]
    float* __restrict__ g)          // [B,T,256]
{
  const int b   = blockIdx.x;
  const int tid = threadIdx.x;
  const int u   = tid & 255;   // unit
  const int kq  = tid >> 8;    // k-quarter (64 h values)

  __shared__ float hf[256];
  __shared__ h2_t  hh2s[128];
  __shared__ float part[4][3][256];

  h2_t wr[32], wz[32], wn[32];
  #pragma unroll
  for (int r = 0; r < 32; ++r) {
    const float* p0 = Wh + (long)(kq*64 + 2*r)*768 + u;
    const float* p1 = p0 + 768;
    h2_t a; a.x = (_Float16)p0[0];   a.y = (_Float16)p1[0];   wr[r] = a;
    h2_t c; c.x = (_Float16)p0[256]; c.y = (_Float16)p1[256]; wz[r] = c;
    h2_t d; d.x = (_Float16)p0[512]; d.y = (_Float16)p1[512]; wn[r] = d;
  }
  float bn = (kq == 0) ? bhn[u] : 0.f;
  if (tid < 256) hf[tid] = 0.f;
  if (tid < 128) { h2_t zz; zz.x = (_Float16)0.f; zz.y = (_Float16)0.f; hh2s[tid] = zz; }
  __syncthreads();

  const float* xgb = xg + (long)b*T_*768;
  float* gb = g + (long)b*T_*256;

  for (int t = 0; t < T_; ++t) {
    float xr = 0.f, xz = 0.f, xn = 0.f;
    if (kq == 0) {  // prefetch input gates; latency hidden behind dot phase
      const float* xt = xgb + (long)t*768;
      xr = xt[u]; xz = xt[u+256]; xn = xt[u+512];
    }
    float ar = 0.f, az = 0.f, an = 0.f;
    #pragma unroll
    for (int r = 0; r < 32; ++r) {
      h2_t hv = hh2s[kq*32 + r];   // wave-uniform address -> broadcast, conflict-free
#if HAS_FDOT2
      ar = __builtin_amdgcn_fdot2(hv, wr[r], ar, false);
      az = __builtin_amdgcn_fdot2(hv, wz[r], az, false);
      an = __builtin_amdgcn_fdot2(hv, wn[r], an, false);
#else
      ar += (float)hv.x*(float)wr[r].x + (float)hv.y*(float)wr[r].y;
      az += (float)hv.x*(float)wz[r].x + (float)hv.y*(float)wz[r].y;
      an += (float)hv.x*(float)wn[r].x + (float)hv.y*(float)wn[r].y;
#endif
    }
    part[kq][0][u] = ar; part[kq][1][u] = az; part[kq][2][u] = an;
    __syncthreads();
    if (kq == 0) {
      float hr = part[0][0][u]+part[1][0][u]+part[2][0][u]+part[3][0][u] + xr;
      float hz = part[0][1][u]+part[1][1][u]+part[2][1][u]+part[3][1][u] + xz;
      float hn = part[0][2][u]+part[1][2][u]+part[2][2][u]+part[3][2][u];
      float rr = 1.f / (1.f + __expf(-hr));
      float z  = 1.f / (1.f + __expf(-hz));
      float nx = xn + rr * (hn + bn);
      float e2 = __expf(2.f * nx);
      float nv = (e2 - 1.f) / (e2 + 1.f);
      float hnew = (1.f - z) * nv + z * hf[u];
      hf[u] = hnew;
      ((_Float16*)hh2s)[u] = (_Float16)hnew;
      gb[(long)t*256 + u] = hnew;
    }
    __syncthreads();
  }
}

// ---------------- softmax over 288 cols: one wave per row, in place ------
// 4 rows per 256-thread block; float4 + 32-lane tail; shuffle-only.
__global__ __launch_bounds__(256) void softmax288_kernel(float* __restrict__ S)
{
  const int wid  = threadIdx.x >> 6;
  const int lane = threadIdx.x & 63;
  long row = (long)blockIdx.x * 4 + wid;
  float* p = S + row * T_;

  float4 v = *(const float4*)(p + lane*4);
  float v4 = (lane < 32) ? p[256 + lane] : -1e30f;
  float mx = fmaxf(fmaxf(fmaxf(v.x, v.y), fmaxf(v.z, v.w)), v4);
  for (int o = 32; o; o >>= 1) mx = fmaxf(mx, __shfl_xor(mx, o));
  v.x = __expf(v.x - mx); v.y = __expf(v.y - mx);
  v.z = __expf(v.z - mx); v.w = __expf(v.w - mx);
  v4  = (lane < 32) ? __expf(v4 - mx) : 0.f;
  float sm = v.x + v.y + v.z + v.w + v4;
  for (int o = 32; o; o >>= 1) sm += __shfl_xor(sm, o);
  const float inv = 1.f / sm;
  v.x *= inv; v.y *= inv; v.z *= inv; v.w *= inv;
  *(float4*)(p + lane*4) = v;
  if (lane < 32) p[256 + lane] = v4 * inv;
}

// ---------------- mean over T ----------------
__global__ __launch_bounds__(256) void meanT_kernel(
    const float* __restrict__ x, float* __restrict__ xm)
{
  int b = blockIdx.x, u = threadIdx.x;
  const float* p = x + (long)b*T_*U_ + u;
  float s = 0.f;
  for (int t = 0; t < T_; ++t) s += p[(long)t*U_];
  xm[b*U_ + u] = s * (1.f/(float)T_);
}

// ---------------- MLP head: one block per batch ----------------
__global__ __launch_bounds__(128) void head_kernel(
    const float* __restrict__ xm, const float* __restrict__ other,
    const float* __restrict__ m1W, const float* __restrict__ m1b,
    const float* __restrict__ l1s, const float* __restrict__ l1b,
    const float* __restrict__ m2W, const float* __restrict__ m2b,
    const float* __restrict__ l2s, const float* __restrict__ l2b,
    const float* __restrict__ oW,  const float* __restrict__ ob,
    float* __restrict__ outp)
{
  __shared__ float c[320];
  __shared__ float h1[128];
  __shared__ float sb[2];
  int b = blockIdx.x, tid = threadIdx.x;
  c[tid]       = xm[b*256 + tid];
  c[tid + 128] = xm[b*256 + tid + 128];
  if (tid < 64) c[256 + tid] = other[b*64 + tid];
  __syncthreads();
  // h1 = LN(relu(c @ m1W + m1b))
  float s = m1b[tid];
  for (int i = 0; i < 320; ++i) s += c[i] * m1W[i*128 + tid];
  s = fmaxf(s, 0.f);
  float m = s;
  for (int o = 32; o; o >>= 1) m += __shfl_xor(m, o);
  if ((tid & 63) == 0) sb[tid >> 6] = m;
  __syncthreads();
  m = (sb[0] + sb[1]) * (1.f/128.f);
  __syncthreads();
  float d = s - m, var = d*d;
  for (int o = 32; o; o >>= 1) var += __shfl_xor(var, o);
  if ((tid & 63) == 0) sb[tid >> 6] = var;
  __syncthreads();
  var = (sb[0] + sb[1]) * (1.f/128.f);
  h1[tid] = d * rsqrtf(var + EPSF) * l1s[tid] + l1b[tid];
  __syncthreads();
  // h2 = LN(relu(h1 @ m2W + m2b)), then out = h2 @ oW + ob  (wave 0 only)
  if (tid < 64) {
    float s2 = m2b[tid];
    for (int i = 0; i < 128; ++i) s2 += h1[i] * m2W[i*64 + tid];
    s2 = fmaxf(s2, 0.f);
    float m2 = s2;
    for (int o = 32; o; o >>= 1) m2 += __shfl_xor(m2, o);
    m2 *= (1.f/64.f);
    float d2 = s2 - m2, v2 = d2*d2;
    for (int o = 32; o; o >>= 1) v2 += __shfl_xor(v2, o);
    v2 *= (1.f/64.f);
    float h2v = d2 * rsqrtf(v2 + EPSF) * l2s[tid] + l2b[tid];
    float y = h2v * oW[tid];
    for (int o = 32; o; o >>= 1) y += __shfl_xor(y, o);
    if (tid == 0) outp[b] = y + ob[0];
  }
}

// ---------------- host orchestration ----------------
static inline void gemm_nn(hipStream_t st, const float* A, const float* Bm, float* C,
                           const float* bias, int M, int N, int K,
                           int lda, int ldb, int ldc, float alpha)
{
  dim3 g((N + 63)/64, (M + 63)/64, 1);
  gemm_kernel<false><<<g, 256, 0, st>>>(A, Bm, C, bias, M, N, K, lda, ldb, ldc,
                                        0,0,0,0,0,0, 1, alpha);
}

extern "C" void kernel_launch(void* const* d_in, const int* in_sizes, int n_in,
                              void* d_out, int out_size, void* d_ws, size_t ws_size,
                              hipStream_t stream)
{
  const float* cgm   = (const float*)d_in[0];
  const float* other = (const float*)d_in[1];
  const float* d0_W  = (const float*)d_in[2];
  const float* d0_b  = (const float*)d_in[3];
  const float* ln0_s = (const float*)d_in[4];
  const float* ln0_b = (const float*)d_in[5];
  const float* gWi   = (const float*)d_in[6];
  const float* gbi   = (const float*)d_in[7];
  const float* gWh   = (const float*)d_in[8];
  const float* gbhn  = (const float*)d_in[9];
  const float* ln1_s = (const float*)d_in[10];
  const float* ln1_b = (const float*)d_in[11];
  const float* Wq    = (const float*)d_in[12];
  const float* bq    = (const float*)d_in[13];
  const float* Wk    = (const float*)d_in[14];
  const float* bk    = (const float*)d_in[15];
  const float* Wv    = (const float*)d_in[16];
  const float* bv    = (const float*)d_in[17];
  const float* Wo    = (const float*)d_in[18];
  const float* bo    = (const float*)d_in[19];
  const float* ln2_s = (const float*)d_in[20];
  const float* ln2_b = (const float*)d_in[21];
  const float* m1W   = (const float*)d_in[22];
  const float* m1b   = (const float*)d_in[23];
  const float* l1s   = (const float*)d_in[24];
  const float* l1b   = (const float*)d_in[25];
  const float* m2W   = (const float*)d_in[26];
  const float* m2b   = (const float*)d_in[27];
  const float* l2s   = (const float*)d_in[28];
  const float* l2b   = (const float*)d_in[29];
  const float* oW    = (const float*)d_in[30];
  const float* ob    = (const float*)d_in[31];
  float* out = (float*)d_out;

  // workspace layout (floats)
  float* ws   = (float*)d_ws;
  float* big  = ws;                   // 28,311,552  (xg, later qkv, later wo tmp)
  float* x    = big  + 28311552;      //  9,437,184
  float* go   = x    +  9437184;      //  9,437,184  (gru out, later attn out)
  float* Sbuf = go   +  9437184;      // scores; size depends on chunking
  (void)in_sizes; (void)n_in; (void)out_size;

  // attention chunking: 1 chunk if workspace allows (S=170MB), else 2, else 4
  const size_t wsf = ws_size / sizeof(float);
  const long base_f = 28311552L + 9437184L + 9437184L;
  int nch;
  long sfloats;
  if      (wsf >= (size_t)(base_f + 512L*T_*T_ + 32768)) { nch = 1; sfloats = 512L*T_*T_; }
  else if (wsf >= (size_t)(base_f + 256L*T_*T_ + 32768)) { nch = 2; sfloats = 256L*T_*T_; }
  else                                                    { nch = 4; sfloats = 128L*T_*T_; }
  const int nb = 128 / nch;           // batches per chunk
  float* xmean = Sbuf + sfloats;      // 32,768

  // x = LN(cgm @ d0_W + d0_b)
  gemm_nn(stream, cgm, d0_W, big, d0_b, MT, 256, 16, 16, 256, 256, 1.f);
  ln256_kernel<<<MT/4, 256, 0, stream>>>(big, nullptr, nullptr, ln0_s, ln0_b, x);

  for (int i = 0; i < 2; ++i) {
    const float* Wi_i = gWi + (long)i*196608;
    const float* Wh_i = gWh + (long)i*196608;

    // xg = x @ Wi + bi
    gemm_nn(stream, x, Wi_i, big, gbi + i*768, MT, 768, 256, 256, 768, 768, 1.f);
    // GRU scan
    gru_scan_kernel<<<128, 1024, 0, stream>>>(big, Wh_i, gbhn + i*256, go);
    // x = LN(g) + x
    ln256_kernel<<<MT/4, 256, 0, stream>>>(go, nullptr, x, ln1_s + i*256, ln1_b + i*256, x);

    // qkv in ONE gemm: pack Wq|Wk|Wv into Sbuf (dead until attention), then
    // C row layout [q(256) | k(256) | v(256)]
    {
      float* wp = Sbuf;            // 196,608 floats
      float* bp = Sbuf + 196608;   // 768 floats
      packqkv_kernel<<<768, 256, 0, stream>>>(
          Wq + (long)i*65536, Wk + (long)i*65536, Wv + (long)i*65536,
          bq + i*256, bk + i*256, bv + i*256, wp, bp);
      gemm_nn(stream, x, wp, big, bp, MT, 768, 256, 256, 768, 768, 1.f);
    }

    // attention in nch chunks of nb batches
    for (int cb = 0; cb < nch; ++cb) {
      const float* qb = big + (long)cb*nb*T_*768;
      {
        dim3 g(5, 5, nb*4);   // z = local_b*4 + head
        gemm_kernel<true><<<g, 256, 0, stream>>>(
            qb, qb + 256, Sbuf, nullptr,
            T_, T_, 64, 768, 768, T_,
            (long)T_*768, 64, (long)T_*768, 64, (long)4*T_*T_, (long)T_*T_,
            4, 0.125f);
      }
      softmax288_kernel<<<(nb*4*T_)/4, 256, 0, stream>>>(Sbuf);
      {
        dim3 g(1, 5, nb*4);
        gemm_kernel<false><<<g, 256, 0, stream>>>(
            Sbuf, qb + 512, go + (long)cb*nb*T_*256, nullptr,
            T_, 64, T_, T_, 768, 256,
            (long)4*T_*T_, (long)T_*T_, (long)T_*768, 64, (long)T_*256, 64,
            4, 1.f);
      }
    }

    // a = o @ Wo + bo ; x = LN(a + x)
    gemm_nn(stream, go, Wo + (long)i*65536, big, bo + i*256, MT, 256, 256, 256, 256, 256, 1.f);
    ln256_kernel<<<MT/4, 256, 0, stream>>>(big, x, nullptr, ln2_s + i*256, ln2_b + i*256, x);
  }

  meanT_kernel<<<128, 256, 0, stream>>>(x, xmean);
  head_kernel<<<128, 128, 0, stream>>>(xmean, other, m1W, m1b, l1s, l1b,
                                       m2W, m2b, l2s, l2b, oW, ob, out);
}

// Round 8
// 1922.686 us; speedup vs baseline: 2.2897x; 1.3959x over previous
//
#include <hip/hip_runtime.h>
#include <math.h>

// ---------------- constants ----------------
#define B_   128
#define T_   288
#define U_   256
#define H_   4
#define HD_  64
#define MT   (B_*T_)     // 36864 rows
#define EPSF 1e-6f

typedef _Float16 h2_t  __attribute__((ext_vector_type(2)));
typedef _Float16 f16x4 __attribute__((ext_vector_type(4)));
typedef _Float16 f16x8 __attribute__((ext_vector_type(8)));
typedef float    f32x4 __attribute__((ext_vector_type(4)));

#if defined(__has_builtin)
#  if __has_builtin(__builtin_amdgcn_fdot2)
#    define HAS_FDOT2 1
#  endif
#endif
#ifndef HAS_FDOT2
#  define HAS_FDOT2 0
#endif

// ---------------- generic tiled fp32 GEMM (d0 + attention QK/PV) ----------
template<bool TB>
__global__ __launch_bounds__(256) void gemm_kernel(
    const float* __restrict__ A, const float* __restrict__ Bm,
    float* __restrict__ C, const float* __restrict__ bias,
    int M, int N, int K, int lda, int ldb, int ldc,
    long sA1, long sA2, long sB1, long sB2, long sC1, long sC2,
    int zdiv, float alpha)
{
  int z  = blockIdx.z;
  int z1 = z / zdiv, z2 = z - z1 * zdiv;
  A  += (long)z1*sA1 + (long)z2*sA2;
  Bm += (long)z1*sB1 + (long)z2*sB2;
  C  += (long)z1*sC1 + (long)z2*sC2;

  __shared__ float As[16][68];
  __shared__ float Bs[16][68];

  const int tid = threadIdx.x;
  const int tx  = tid & 15;     // 0..15 (n)
  const int ty  = tid >> 4;     // 0..15 (m)
  const int rowBase = blockIdx.y * 64;
  const int colBase = blockIdx.x * 64;

  float acc[4][4] = {};

  const int lr = tid >> 2;         // 0..63
  const int lk = (tid & 3) << 2;   // 0,4,8,12

  for (int k0 = 0; k0 < K; k0 += 16) {
    {
      float4 a4 = {0.f,0.f,0.f,0.f};
      int ar = rowBase + lr;
      if (ar < M) a4 = *(const float4*)(A + (long)ar*lda + k0 + lk);
      As[lk+0][lr]=a4.x; As[lk+1][lr]=a4.y; As[lk+2][lr]=a4.z; As[lk+3][lr]=a4.w;
    }
    if (TB) {
      float4 b4 = {0.f,0.f,0.f,0.f};
      int bn = colBase + lr;
      if (bn < N) b4 = *(const float4*)(Bm + (long)bn*ldb + k0 + lk);
      Bs[lk+0][lr]=b4.x; Bs[lk+1][lr]=b4.y; Bs[lk+2][lr]=b4.z; Bs[lk+3][lr]=b4.w;
    } else {
      int bk  = tid >> 4;
      int bn4 = (tid & 15) << 2;
      float4 b4 = {0.f,0.f,0.f,0.f};
      if (colBase + bn4 < N) b4 = *(const float4*)(Bm + (long)(k0+bk)*ldb + colBase + bn4);
      *(float4*)(&Bs[bk][bn4]) = b4;
    }
    __syncthreads();
    #pragma unroll
    for (int k = 0; k < 16; ++k) {
      float4 av = *(const float4*)(&As[k][ty<<2]);
      float4 bv = *(const float4*)(&Bs[k][tx<<2]);
      acc[0][0]+=av.x*bv.x; acc[0][1]+=av.x*bv.y; acc[0][2]+=av.x*bv.z; acc[0][3]+=av.x*bv.w;
      acc[1][0]+=av.y*bv.x; acc[1][1]+=av.y*bv.y; acc[1][2]+=av.y*bv.z; acc[1][3]+=av.y*bv.w;
      acc[2][0]+=av.z*bv.x; acc[2][1]+=av.z*bv.y; acc[2][2]+=av.z*bv.z; acc[2][3]+=av.z*bv.w;
      acc[3][0]+=av.w*bv.x; acc[3][1]+=av.w*bv.y; acc[3][2]+=av.w*bv.z; acc[3][3]+=av.w*bv.w;
    }
    __syncthreads();
  }

  const int cn = colBase + (tx << 2);
  if (cn < N) {
    float4 bb = {0.f,0.f,0.f,0.f};
    if (bias) bb = *(const float4*)(bias + cn);
    #pragma unroll
    for (int i = 0; i < 4; ++i) {
      int r = rowBase + (ty << 2) + i;
      if (r < M) {
        float4 v;
        v.x = acc[i][0]*alpha + bb.x;
        v.y = acc[i][1]*alpha + bb.y;
        v.z = acc[i][2]*alpha + bb.z;
        v.w = acc[i][3]*alpha + bb.w;
        *(float4*)(C + (long)r*ldc + cn) = v;
      }
    }
  }
}

// ---------------- f16 MFMA GEMM: C[M,N] f32 = A16[M,K] @ Bt16[N,K]^T + bias
// 64x64 tile, BK=32, 256 thr = 4 waves in 2x2 grid, each wave a 32x32 quadrant
// (2x2 MFMA 16x16x32 tiles). Fragment convention verified rounds 3-6:
//  a-frag lane(l16,lq)[e] = A[m0+l16][k0+lq*8+e]
//  b-frag lane(l16,lq)[e] = Bt[n0+l16][k0+lq*8+e]   (= B[k][n])
//  C/D: row_in_16 = lq*4+r, col_in_16 = l16
// LDS rows padded to 40 f16 (80 B) -> b128 reads/writes ~2-way (free).
__global__ __launch_bounds__(256) void gemm16_kernel(
    const _Float16* __restrict__ A, const _Float16* __restrict__ Bt,
    float* __restrict__ C, const float* __restrict__ bias,
    int M, int N, int K)
{
  __shared__ __align__(16) _Float16 Asf[64][40];
  __shared__ __align__(16) _Float16 Bsf[64][40];
  const int tid  = threadIdx.x;
  const int wv   = tid >> 6;
  const int mw   = wv >> 1, nw = wv & 1;
  const int lane = tid & 63, l16 = lane & 15, lq = lane >> 4;
  const int m0 = blockIdx.y * 64, n0 = blockIdx.x * 64;
  const int srow = tid >> 2, sk = (tid & 3) * 8;

  f32x4 acc00 = {0,0,0,0}, acc01 = {0,0,0,0};
  f32x4 acc10 = {0,0,0,0}, acc11 = {0,0,0,0};

  const long arow = (long)(m0 + srow)*K + sk;
  const long brow = (long)(n0 + srow)*K + sk;

  for (int k0 = 0; k0 < K; k0 += 32) {
    *(f16x8*)&Asf[srow][sk] = *(const f16x8*)&A[arow + k0];
    *(f16x8*)&Bsf[srow][sk] = *(const f16x8*)&Bt[brow + k0];
    __syncthreads();
    f16x8 a0 = *(const f16x8*)&Asf[mw*32 +      l16][lq*8];
    f16x8 a1 = *(const f16x8*)&Asf[mw*32 + 16 + l16][lq*8];
    f16x8 b0 = *(const f16x8*)&Bsf[nw*32 +      l16][lq*8];
    f16x8 b1 = *(const f16x8*)&Bsf[nw*32 + 16 + l16][lq*8];
    acc00 = __builtin_amdgcn_mfma_f32_16x16x32_f16(a0, b0, acc00, 0, 0, 0);
    acc01 = __builtin_amdgcn_mfma_f32_16x16x32_f16(a0, b1, acc01, 0, 0, 0);
    acc10 = __builtin_amdgcn_mfma_f32_16x16x32_f16(a1, b0, acc10, 0, 0, 0);
    acc11 = __builtin_amdgcn_mfma_f32_16x16x32_f16(a1, b1, acc11, 0, 0, 0);
    __syncthreads();
  }

  const int rowb = m0 + mw*32 + lq*4;
#define EPI(ACC, MT, NT) { \
    const int col = n0 + nw*32 + (NT)*16 + l16; \
    const float bb = bias ? bias[col] : 0.f; \
    const int rb = rowb + (MT)*16; \
    C[(long)(rb+0)*N + col] = ACC[0] + bb; \
    C[(long)(rb+1)*N + col] = ACC[1] + bb; \
    C[(long)(rb+2)*N + col] = ACC[2] + bb; \
    C[(long)(rb+3)*N + col] = ACC[3] + bb; }
  EPI(acc00,0,0) EPI(acc01,0,1) EPI(acc10,1,0) EPI(acc11,1,1)
#undef EPI
}

// ---------------- transpose-pack: f32 src[K,N] -> f16 dst[N,K] ------------
__global__ __launch_bounds__(256) void tpack_kernel(
    const float* __restrict__ src, _Float16* __restrict__ dst, int K, int N)
{
  __shared__ float t[32][33];
  const int tx = threadIdx.x & 31, ty = threadIdx.x >> 5;  // 32 x 8
  const int n0 = blockIdx.x * 32, k0 = blockIdx.y * 32;
  #pragma unroll
  for (int i = 0; i < 4; ++i)
    t[ty + 8*i][tx] = src[(long)(k0 + ty + 8*i)*N + n0 + tx];
  __syncthreads();
  #pragma unroll
  for (int i = 0; i < 4; ++i)
    dst[(long)(n0 + ty + 8*i)*K + k0 + tx] = (_Float16)t[tx][ty + 8*i];
}

// ---------------- bias pack bq|bk|bv -> bp[768] ----------------
__global__ __launch_bounds__(256) void packb_kernel(
    const float* __restrict__ bq, const float* __restrict__ bk,
    const float* __restrict__ bv, float* __restrict__ bp)
{
  int t = threadIdx.x;
  bp[t] = bq[t]; bp[256 + t] = bk[t]; bp[512 + t] = bv[t];
}

// ---------------- f32 -> f16 elementwise ----------------
__global__ __launch_bounds__(256) void cvt16_kernel(
    const float* __restrict__ src, _Float16* __restrict__ dst)
{
  const long idx = ((long)blockIdx.x * 256 + threadIdx.x) * 4;
  float4 v = *(const float4*)(src + idx);
  f16x4 o = {(_Float16)v.x, (_Float16)v.y, (_Float16)v.z, (_Float16)v.w};
  *(f16x4*)(dst + idx) = o;
}

// ---------------- LayerNorm over 256 cols: one wave per row ----------------
// out[row] = LN(in[row] (+skip_pre)) * s + b (+ skip_post); optional f16 copy.
__global__ __launch_bounds__(256) void ln256_kernel(
    const float* __restrict__ in, const float* __restrict__ skip_pre,
    const float* __restrict__ skip_post,
    const float* __restrict__ s, const float* __restrict__ b,
    float* __restrict__ out, _Float16* __restrict__ out16)
{
  const int wid  = threadIdx.x >> 6;
  const int lane = threadIdx.x & 63;
  const long row  = (long)blockIdx.x * 4 + wid;
  const long base = row * 256 + lane * 4;

  float4 v = *(const float4*)(in + base);
  if (skip_pre) {
    float4 sp = *(const float4*)(skip_pre + base);
    v.x += sp.x; v.y += sp.y; v.z += sp.z; v.w += sp.w;
  }
  float m = v.x + v.y + v.z + v.w;
  for (int o = 32; o; o >>= 1) m += __shfl_xor(m, o);
  m *= (1.f/256.f);
  float4 d = { v.x - m, v.y - m, v.z - m, v.w - m };
  float var = d.x*d.x + d.y*d.y + d.z*d.z + d.w*d.w;
  for (int o = 32; o; o >>= 1) var += __shfl_xor(var, o);
  var *= (1.f/256.f);
  const float inv = rsqrtf(var + EPSF);
  float4 sv = *(const float4*)(s + lane*4);
  float4 bv = *(const float4*)(b + lane*4);
  float4 y;
  y.x = d.x*inv*sv.x + bv.x;
  y.y = d.y*inv*sv.y + bv.y;
  y.z = d.z*inv*sv.z + bv.z;
  y.w = d.w*inv*sv.w + bv.w;
  if (skip_post) {
    float4 sp = *(const float4*)(skip_post + base);
    y.x += sp.x; y.y += sp.y; y.z += sp.z; y.w += sp.w;
  }
  *(float4*)(out + base) = y;
  if (out16) {
    f16x4 o16 = {(_Float16)y.x, (_Float16)y.y, (_Float16)y.z, (_Float16)y.w};
    *(f16x4*)(out16 + base) = o16;
  }
}

// ---------------- GRU scan: one workgroup per batch ----------------
// Round-0 structure (396 us verified). Round-8 change: the dot-phase h
// broadcast reads the 32 h2 pairs of the quarter as 8x ds_read_b128
// (chunked, 4 pairs live) instead of 32x ds_read_b32 -> LDS wave-instrs
// per step per CU drop 512 -> 128 (the diagnosed bound: ~2970 cyc of LDS
// issue vs 975 VALU).
__global__ __launch_bounds__(1024, 1) void gru_scan_kernel(
    const float* __restrict__ xg,   // [B,T,768]
    const float* __restrict__ Wh,   // [256,768]
    const float* __restrict__ bhn,  // [256]
    float* __restrict__ g)          // [B,T,256]
{
  const int b   = blockIdx.x;
  const int tid = threadIdx.x;
  const int u   = tid & 255;   // unit
  const int kq  = tid >> 8;    // k-quarter (64 h values)

  __shared__ float hf[256];
  __shared__ __align__(16) h2_t hh2s[128];
  __shared__ float part[4][3][256];

  h2_t wr[32], wz[32], wn[32];
  #pragma unroll
  for (int r = 0; r < 32; ++r) {
    const float* p0 = Wh + (long)(kq*64 + 2*r)*768 + u;
    const float* p1 = p0 + 768;
    h2_t a; a.x = (_Float16)p0[0];   a.y = (_Float16)p1[0];   wr[r] = a;
    h2_t c; c.x = (_Float16)p0[256]; c.y = (_Float16)p1[256]; wz[r] = c;
    h2_t d; d.x = (_Float16)p0[512]; d.y = (_Float16)p1[512]; wn[r] = d;
  }
  float bn = (kq == 0) ? bhn[u] : 0.f;
  if (tid < 256) hf[tid] = 0.f;
  if (tid < 128) { h2_t zz; zz.x = (_Float16)0.f; zz.y = (_Float16)0.f; hh2s[tid] = zz; }
  __syncthreads();

  const float* xgb = xg + (long)b*T_*768;
  float* gb = g + (long)b*T_*256;

  for (int t = 0; t < T_; ++t) {
    float xr = 0.f, xz = 0.f, xn = 0.f;
    if (kq == 0) {  // prefetch input gates; latency hidden behind dot phase
      const float* xt = xgb + (long)t*768;
      xr = xt[u]; xz = xt[u+256]; xn = xt[u+512];
    }
    const float4* hq4 = (const float4*)(&hh2s[kq*32]);
    float ar = 0.f, az = 0.f, an = 0.f;
    #pragma unroll
    for (int c = 0; c < 8; ++c) {
      const float4 hc = hq4[c];   // ds_read_b128: 4 h2 pairs
      union { float f; h2_t h; } u0, u1, u2, u3;
      u0.f = hc.x; u1.f = hc.y; u2.f = hc.z; u3.f = hc.w;
#if HAS_FDOT2
      ar = __builtin_amdgcn_fdot2(u0.h, wr[c*4+0], ar, false);
      az = __builtin_amdgcn_fdot2(u0.h, wz[c*4+0], az, false);
      an = __builtin_amdgcn_fdot2(u0.h, wn[c*4+0], an, false);
      ar = __builtin_amdgcn_fdot2(u1.h, wr[c*4+1], ar, false);
      az = __builtin_amdgcn_fdot2(u1.h, wz[c*4+1], az, false);
      an = __builtin_amdgcn_fdot2(u1.h, wn[c*4+1], an, false);
      ar = __builtin_amdgcn_fdot2(u2.h, wr[c*4+2], ar, false);
      az = __builtin_amdgcn_fdot2(u2.h, wz[c*4+2], az, false);
      an = __builtin_amdgcn_fdot2(u2.h, wn[c*4+2], an, false);
      ar = __builtin_amdgcn_fdot2(u3.h, wr[c*4+3], ar, false);
      az = __builtin_amdgcn_fdot2(u3.h, wz[c*4+3], az, false);
      an = __builtin_amdgcn_fdot2(u3.h, wn[c*4+3], an, false);
#else
      ar += (float)u0.h.x*(float)wr[c*4+0].x + (float)u0.h.y*(float)wr[c*4+0].y;
      az += (float)u0.h.x*(float)wz[c*4+0].x + (float)u0.h.y*(float)wz[c*4+0].y;
      an += (float)u0.h.x*(float)wn[c*4+0].x + (float)u0.h.y*(float)wn[c*4+0].y;
      ar += (float)u1.h.x*(float)wr[c*4+1].x + (float)u1.h.y*(float)wr[c*4+1].y;
      az += (float)u1.h.x*(float)wz[c*4+1].x + (float)u1.h.y*(float)wz[c*4+1].y;
      an += (float)u1.h.x*(float)wn[c*4+1].x + (float)u1.h.y*(float)wn[c*4+1].y;
      ar += (float)u2.h.x*(float)wr[c*4+2].x + (float)u2.h.y*(float)wr[c*4+2].y;
      az += (float)u2.h.x*(float)wz[c*4+2].x + (float)u2.h.y*(float)wz[c*4+2].y;
      an += (float)u2.h.x*(float)wn[c*4+2].x + (float)u2.h.y*(float)wn[c*4+2].y;
      ar += (float)u3.h.x*(float)wr[c*4+3].x + (float)u3.h.y*(float)wr[c*4+3].y;
      az += (float)u3.h.x*(float)wz[c*4+3].x + (float)u3.h.y*(float)wz[c*4+3].y;
      an += (float)u3.h.x*(float)wn[c*4+3].x + (float)u3.h.y*(float)wn[c*4+3].y;
#endif
    }
    part[kq][0][u] = ar; part[kq][1][u] = az; part[kq][2][u] = an;
    __syncthreads();
    if (kq == 0) {
      float hr = part[0][0][u]+part[1][0][u]+part[2][0][u]+part[3][0][u] + xr;
      float hz = part[0][1][u]+part[1][1][u]+part[2][1][u]+part[3][1][u] + xz;
      float hn = part[0][2][u]+part[1][2][u]+part[2][2][u]+part[3][2][u];
      float rr = 1.f / (1.f + __expf(-hr));
      float z  = 1.f / (1.f + __expf(-hz));
      float nx = xn + rr * (hn + bn);
      float e2 = __expf(2.f * nx);
      float nv = (e2 - 1.f) / (e2 + 1.f);
      float hnew = (1.f - z) * nv + z * hf[u];
      hf[u] = hnew;
      ((_Float16*)hh2s)[u] = (_Float16)hnew;
      gb[(long)t*256 + u] = hnew;
    }
    __syncthreads();
  }
}

// ---------------- softmax over 288 cols: one wave per row, in place ------
__global__ __launch_bounds__(256) void softmax288_kernel(float* __restrict__ S)
{
  const int wid  = threadIdx.x >> 6;
  const int lane = threadIdx.x & 63;
  long row = (long)blockIdx.x * 4 + wid;
  float* p = S + row * T_;

  float4 v = *(const float4*)(p + lane*4);
  float v4 = (lane < 32) ? p[256 + lane] : -1e30f;
  float mx = fmaxf(fmaxf(fmaxf(v.x, v.y), fmaxf(v.z, v.w)), v4);
  for (int o = 32; o; o >>= 1) mx = fmaxf(mx, __shfl_xor(mx, o));
  v.x = __expf(v.x - mx); v.y = __expf(v.y - mx);
  v.z = __expf(v.z - mx); v.w = __expf(v.w - mx);
  v4  = (lane < 32) ? __expf(v4 - mx) : 0.f;
  float sm = v.x + v.y + v.z + v.w + v4;
  for (int o = 32; o; o >>= 1) sm += __shfl_xor(sm, o);
  const float inv = 1.f / sm;
  v.x *= inv; v.y *= inv; v.z *= inv; v.w *= inv;
  *(float4*)(p + lane*4) = v;
  if (lane < 32) p[256 + lane] = v4 * inv;
}

// ---------------- mean over T ----------------
__global__ __launch_bounds__(256) void meanT_kernel(
    const float* __restrict__ x, float* __restrict__ xm)
{
  int b = blockIdx.x, u = threadIdx.x;
  const float* p = x + (long)b*T_*U_ + u;
  float s = 0.f;
  for (int t = 0; t < T_; ++t) s += p[(long)t*U_];
  xm[b*U_ + u] = s * (1.f/(float)T_);
}

// ---------------- MLP head: one block per batch ----------------
__global__ __launch_bounds__(128) void head_kernel(
    const float* __restrict__ xm, const float* __restrict__ other,
    const float* __restrict__ m1W, const float* __restrict__ m1b,
    const float* __restrict__ l1s, const float* __restrict__ l1b,
    const float* __restrict__ m2W, const float* __restrict__ m2b,
    const float* __restrict__ l2s, const float* __restrict__ l2b,
    const float* __restrict__ oW,  const float* __restrict__ ob,
    float* __restrict__ outp)
{
  __shared__ float c[320];
  __shared__ float h1[128];
  __shared__ float sb[2];
  int b = blockIdx.x, tid = threadIdx.x;
  c[tid]       = xm[b*256 + tid];
  c[tid + 128] = xm[b*256 + tid + 128];
  if (tid < 64) c[256 + tid] = other[b*64 + tid];
  __syncthreads();
  float s = m1b[tid];
  for (int i = 0; i < 320; ++i) s += c[i] * m1W[i*128 + tid];
  s = fmaxf(s, 0.f);
  float m = s;
  for (int o = 32; o; o >>= 1) m += __shfl_xor(m, o);
  if ((tid & 63) == 0) sb[tid >> 6] = m;
  __syncthreads();
  m = (sb[0] + sb[1]) * (1.f/128.f);
  __syncthreads();
  float d = s - m, var = d*d;
  for (int o = 32; o; o >>= 1) var += __shfl_xor(var, o);
  if ((tid & 63) == 0) sb[tid >> 6] = var;
  __syncthreads();
  var = (sb[0] + sb[1]) * (1.f/128.f);
  h1[tid] = d * rsqrtf(var + EPSF) * l1s[tid] + l1b[tid];
  __syncthreads();
  if (tid < 64) {
    float s2 = m2b[tid];
    for (int i = 0; i < 128; ++i) s2 += h1[i] * m2W[i*64 + tid];
    s2 = fmaxf(s2, 0.f);
    float m2 = s2;
    for (int o = 32; o; o >>= 1) m2 += __shfl_xor(m2, o);
    m2 *= (1.f/64.f);
    float d2 = s2 - m2, v2 = d2*d2;
    for (int o = 32; o; o >>= 1) v2 += __shfl_xor(v2, o);
    v2 *= (1.f/64.f);
    float h2v = d2 * rsqrtf(v2 + EPSF) * l2s[tid] + l2b[tid];
    float y = h2v * oW[tid];
    for (int o = 32; o; o >>= 1) y += __shfl_xor(y, o);
    if (tid == 0) outp[b] = y + ob[0];
  }
}

// ---------------- host orchestration ----------------
static inline void gemm_nn(hipStream_t st, const float* A, const float* Bm, float* C,
                           const float* bias, int M, int N, int K,
                           int lda, int ldb, int ldc, float alpha)
{
  dim3 g((N + 63)/64, (M + 63)/64, 1);
  gemm_kernel<false><<<g, 256, 0, st>>>(A, Bm, C, bias, M, N, K, lda, ldb, ldc,
                                        0,0,0,0,0,0, 1, alpha);
}

extern "C" void kernel_launch(void* const* d_in, const int* in_sizes, int n_in,
                              void* d_out, int out_size, void* d_ws, size_t ws_size,
                              hipStream_t stream)
{
  const float* cgm   = (const float*)d_in[0];
  const float* other = (const float*)d_in[1];
  const float* d0_W  = (const float*)d_in[2];
  const float* d0_b  = (const float*)d_in[3];
  const float* ln0_s = (const float*)d_in[4];
  const float* ln0_b = (const float*)d_in[5];
  const float* gWi   = (const float*)d_in[6];
  const float* gbi   = (const float*)d_in[7];
  const float* gWh   = (const float*)d_in[8];
  const float* gbhn  = (const float*)d_in[9];
  const float* ln1_s = (const float*)d_in[10];
  const float* ln1_b = (const float*)d_in[11];
  const float* Wq    = (const float*)d_in[12];
  const float* bq    = (const float*)d_in[13];
  const float* Wk    = (const float*)d_in[14];
  const float* bk    = (const float*)d_in[15];
  const float* Wv    = (const float*)d_in[16];
  const float* bv    = (const float*)d_in[17];
  const float* Wo    = (const float*)d_in[18];
  const float* bo    = (const float*)d_in[19];
  const float* ln2_s = (const float*)d_in[20];
  const float* ln2_b = (const float*)d_in[21];
  const float* m1W   = (const float*)d_in[22];
  const float* m1b   = (const float*)d_in[23];
  const float* l1s   = (const float*)d_in[24];
  const float* l1b   = (const float*)d_in[25];
  const float* m2W   = (const float*)d_in[26];
  const float* m2b   = (const float*)d_in[27];
  const float* l2s   = (const float*)d_in[28];
  const float* l2b   = (const float*)d_in[29];
  const float* oW    = (const float*)d_in[30];
  const float* ob    = (const float*)d_in[31];
  float* out = (float*)d_out;

  // workspace layout (floats)
  float* ws   = (float*)d_ws;
  float* big  = ws;                   // 28,311,552  (xg, later qkv, later wo tmp)
  float* x    = big  + 28311552;      //  9,437,184
  float* go   = x    +  9437184;      //  9,437,184  (gru out, later attn out)
  float* Sbuf = go   +  9437184;      // scores; size depends on chunking
  (void)in_sizes; (void)n_in; (void)out_size;

  // attention chunking: 1 chunk if workspace allows, else 2, else 4
  const size_t wsf = ws_size / sizeof(float);
  const long base_f = 28311552L + 9437184L + 9437184L;
  int nch;
  long sfloats;
  if      (wsf >= (size_t)(base_f + 512L*T_*T_ + 32768)) { nch = 1; sfloats = 512L*T_*T_; }
  else if (wsf >= (size_t)(base_f + 256L*T_*T_ + 32768)) { nch = 2; sfloats = 256L*T_*T_; }
  else                                                    { nch = 4; sfloats = 128L*T_*T_; }
  const int nb = 128 / nch;           // batches per chunk
  float* xmean = Sbuf + sfloats;      // 32,768

  // f16 region carved from Sbuf (lifetime-disjoint from attention scores):
  //  a16: activation f16 copy (x16 between LN and its GEMMs; go16 before Wo)
  //  wt*: transposed f16 weights, packed per layer; dead once attention runs
  _Float16* a16   = (_Float16*)Sbuf;                       // 4,718,592 fl
  _Float16* wtWi  = (_Float16*)(Sbuf + 4718592);           //    98,304 fl
  _Float16* wtQKV = (_Float16*)(Sbuf + 4718592 + 98304);   //    98,304 fl
  _Float16* wtWo  = (_Float16*)(Sbuf + 4718592 + 196608);  //    32,768 fl
  float*    bqkv  =             Sbuf + 4718592 + 229376;   //       768 fl

  // x = LN(cgm @ d0_W + d0_b)  (+ f16 copy for layer-0 xg GEMM)
  gemm_nn(stream, cgm, d0_W, big, d0_b, MT, 256, 16, 16, 256, 256, 1.f);
  ln256_kernel<<<MT/4, 256, 0, stream>>>(big, nullptr, nullptr, ln0_s, ln0_b, x, a16);

  for (int i = 0; i < 2; ++i) {
    const float* Wh_i = gWh + (long)i*196608;

    // xg = x @ Wi + bi  (f16 MFMA; Wi transpose-packed to f16 [768][256])
    tpack_kernel<<<dim3(24, 8), 256, 0, stream>>>(gWi + (long)i*196608, wtWi, 256, 768);
    gemm16_kernel<<<dim3(12, 576), 256, 0, stream>>>(a16, wtWi, big, gbi + i*768, MT, 768, 256);
    // GRU scan
    gru_scan_kernel<<<128, 1024, 0, stream>>>(big, Wh_i, gbhn + i*256, go);
    // x = LN(g) + x  (+ f16 copy for qkv GEMM)
    ln256_kernel<<<MT/4, 256, 0, stream>>>(go, nullptr, x, ln1_s + i*256, ln1_b + i*256, x, a16);

    // qkv in ONE f16 MFMA gemm: W^T packed [768][256], bias packed [768]
    tpack_kernel<<<dim3(8, 8), 256, 0, stream>>>(Wq + (long)i*65536, wtQKV,            256, 256);
    tpack_kernel<<<dim3(8, 8), 256, 0, stream>>>(Wk + (long)i*65536, wtQKV + 256*256,  256, 256);
    tpack_kernel<<<dim3(8, 8), 256, 0, stream>>>(Wv + (long)i*65536, wtQKV + 512*256,  256, 256);
    packb_kernel<<<1, 256, 0, stream>>>(bq + i*256, bk + i*256, bv + i*256, bqkv);
    gemm16_kernel<<<dim3(12, 576), 256, 0, stream>>>(a16, wtQKV, big, bqkv, MT, 768, 256);

    // attention in nch chunks of nb batches (fp32; scores clobber a16/wt* - dead)
    for (int cb = 0; cb < nch; ++cb) {
      const float* qb = big + (long)cb*nb*T_*768;
      {
        dim3 g(5, 5, nb*4);   // z = local_b*4 + head
        gemm_kernel<true><<<g, 256, 0, stream>>>(
            qb, qb + 256, Sbuf, nullptr,
            T_, T_, 64, 768, 768, T_,
            (long)T_*768, 64, (long)T_*768, 64, (long)4*T_*T_, (long)T_*T_,
            4, 0.125f);
      }
      softmax288_kernel<<<(nb*4*T_)/4, 256, 0, stream>>>(Sbuf);
      {
        dim3 g(1, 5, nb*4);
        gemm_kernel<false><<<g, 256, 0, stream>>>(
            Sbuf, qb + 512, go + (long)cb*nb*T_*256, nullptr,
            T_, 64, T_, T_, 768, 256,
            (long)4*T_*T_, (long)T_*T_, (long)T_*768, 64, (long)T_*256, 64,
            4, 1.f);
      }
    }

    // a = o @ Wo + bo  (f16 MFMA; attention done, so a16/wt region free again)
    cvt16_kernel<<<9216, 256, 0, stream>>>(go, a16);
    tpack_kernel<<<dim3(8, 8), 256, 0, stream>>>(Wo + (long)i*65536, wtWo, 256, 256);
    gemm16_kernel<<<dim3(4, 576), 256, 0, stream>>>(a16, wtWo, big, bo + i*256, MT, 256, 256);
    // x = LN(a + x)  (+ f16 copy for next layer's xg GEMM)
    ln256_kernel<<<MT/4, 256, 0, stream>>>(big, x, nullptr, ln2_s + i*256, ln2_b + i*256, x, a16);
  }

  meanT_kernel<<<128, 256, 0, stream>>>(x, xmean);
  head_kernel<<<128, 128, 0, stream>>>(xmean, other, m1W, m1b, l1s, l1b,
                                       m2W, m2b, l2s, l2b, oW, ob, out);
}

// Round 10
// 1700.082 us; speedup vs baseline: 2.5895x; 1.1309x over previous
//
#include <hip/hip_runtime.h>
#include <math.h>

// ---------------- constants ----------------
#define B_   128
#define T_   288
#define U_   256
#define H_   4
#define HD_  64
#define MT   (B_*T_)     // 36864 rows
#define EPSF 1e-6f

typedef _Float16 h2_t  __attribute__((ext_vector_type(2)));
typedef _Float16 f16x4 __attribute__((ext_vector_type(4)));
typedef _Float16 f16x8 __attribute__((ext_vector_type(8)));
typedef float    f32x4 __attribute__((ext_vector_type(4)));

#if defined(__has_builtin)
#  if __has_builtin(__builtin_amdgcn_fdot2)
#    define HAS_FDOT2 1
#  endif
#endif
#ifndef HAS_FDOT2
#  define HAS_FDOT2 0
#endif

// ---------------- generic tiled fp32 GEMM (d0 only) ----------
template<bool TB>
__global__ __launch_bounds__(256) void gemm_kernel(
    const float* __restrict__ A, const float* __restrict__ Bm,
    float* __restrict__ C, const float* __restrict__ bias,
    int M, int N, int K, int lda, int ldb, int ldc,
    long sA1, long sA2, long sB1, long sB2, long sC1, long sC2,
    int zdiv, float alpha)
{
  int z  = blockIdx.z;
  int z1 = z / zdiv, z2 = z - z1 * zdiv;
  A  += (long)z1*sA1 + (long)z2*sA2;
  Bm += (long)z1*sB1 + (long)z2*sB2;
  C  += (long)z1*sC1 + (long)z2*sC2;

  __shared__ float As[16][68];
  __shared__ float Bs[16][68];

  const int tid = threadIdx.x;
  const int tx  = tid & 15;
  const int ty  = tid >> 4;
  const int rowBase = blockIdx.y * 64;
  const int colBase = blockIdx.x * 64;

  float acc[4][4] = {};

  const int lr = tid >> 2;
  const int lk = (tid & 3) << 2;

  for (int k0 = 0; k0 < K; k0 += 16) {
    {
      float4 a4 = {0.f,0.f,0.f,0.f};
      int ar = rowBase + lr;
      if (ar < M) a4 = *(const float4*)(A + (long)ar*lda + k0 + lk);
      As[lk+0][lr]=a4.x; As[lk+1][lr]=a4.y; As[lk+2][lr]=a4.z; As[lk+3][lr]=a4.w;
    }
    if (TB) {
      float4 b4 = {0.f,0.f,0.f,0.f};
      int bn = colBase + lr;
      if (bn < N) b4 = *(const float4*)(Bm + (long)bn*ldb + k0 + lk);
      Bs[lk+0][lr]=b4.x; Bs[lk+1][lr]=b4.y; Bs[lk+2][lr]=b4.z; Bs[lk+3][lr]=b4.w;
    } else {
      int bk  = tid >> 4;
      int bn4 = (tid & 15) << 2;
      float4 b4 = {0.f,0.f,0.f,0.f};
      if (colBase + bn4 < N) b4 = *(const float4*)(Bm + (long)(k0+bk)*ldb + colBase + bn4);
      *(float4*)(&Bs[bk][bn4]) = b4;
    }
    __syncthreads();
    #pragma unroll
    for (int k = 0; k < 16; ++k) {
      float4 av = *(const float4*)(&As[k][ty<<2]);
      float4 bv = *(const float4*)(&Bs[k][tx<<2]);
      acc[0][0]+=av.x*bv.x; acc[0][1]+=av.x*bv.y; acc[0][2]+=av.x*bv.z; acc[0][3]+=av.x*bv.w;
      acc[1][0]+=av.y*bv.x; acc[1][1]+=av.y*bv.y; acc[1][2]+=av.y*bv.z; acc[1][3]+=av.y*bv.w;
      acc[2][0]+=av.z*bv.x; acc[2][1]+=av.z*bv.y; acc[2][2]+=av.z*bv.z; acc[2][3]+=av.z*bv.w;
      acc[3][0]+=av.w*bv.x; acc[3][1]+=av.w*bv.y; acc[3][2]+=av.w*bv.z; acc[3][3]+=av.w*bv.w;
    }
    __syncthreads();
  }

  const int cn = colBase + (tx << 2);
  if (cn < N) {
    float4 bb = {0.f,0.f,0.f,0.f};
    if (bias) bb = *(const float4*)(bias + cn);
    #pragma unroll
    for (int i = 0; i < 4; ++i) {
      int r = rowBase + (ty << 2) + i;
      if (r < M) {
        float4 v;
        v.x = acc[i][0]*alpha + bb.x;
        v.y = acc[i][1]*alpha + bb.y;
        v.z = acc[i][2]*alpha + bb.z;
        v.w = acc[i][3]*alpha + bb.w;
        *(float4*)(C + (long)r*ldc + cn) = v;
      }
    }
  }
}

// ---------------- f16 MFMA GEMM (batched, guarded, f32/f16 out) ----------
// C[M,N] = alpha * A16[M,K](lda) @ Bt16[N,K](ldb)^T + bias[N]
// 64x64 tile, BK=32, 256 thr = 4 waves 2x2. Fragment convention verified
// rounds 3-8: a-frag lane(l16,lq)[e]=A[m0+l16][k0+lq*8+e]; same for Bt;
// C/D row=lq*4+r, col=l16. OOB staging READS are allowed (land in ws
// padding); C writes guarded. Batch z: z1=z/zdiv, z2=z%zdiv (strides in
// elements of the respective buffer type).
template<bool OUT16>
__global__ __launch_bounds__(256) void gemm16_kernel(
    const _Float16* __restrict__ A, const _Float16* __restrict__ Bt,
    void* __restrict__ Cv, const float* __restrict__ bias,
    int M, int N, int K, int lda, int ldb, int ldc,
    long sA1, long sA2, long sB1, long sB2, long sC1, long sC2,
    int zdiv, float alpha)
{
  const int z  = blockIdx.z;
  const int z1 = z / zdiv, z2 = z - z1 * zdiv;
  A  += (long)z1*sA1 + (long)z2*sA2;
  Bt += (long)z1*sB1 + (long)z2*sB2;
  float*    Cf = (float*)Cv    + ((long)z1*sC1 + (long)z2*sC2);
  _Float16* Ch = (_Float16*)Cv + ((long)z1*sC1 + (long)z2*sC2);

  __shared__ __align__(16) _Float16 Asf[64][40];
  __shared__ __align__(16) _Float16 Bsf[64][40];
  const int tid  = threadIdx.x;
  const int wv   = tid >> 6;
  const int mw   = wv >> 1, nw = wv & 1;
  const int lane = tid & 63, l16 = lane & 15, lq = lane >> 4;
  const int m0 = blockIdx.y * 64, n0 = blockIdx.x * 64;
  const int srow = tid >> 2, sk = (tid & 3) * 8;

  f32x4 acc00 = {0,0,0,0}, acc01 = {0,0,0,0};
  f32x4 acc10 = {0,0,0,0}, acc11 = {0,0,0,0};

  const long arow = (long)(m0 + srow)*lda + sk;
  const long brow = (long)(n0 + srow)*ldb + sk;

  for (int k0 = 0; k0 < K; k0 += 32) {
    *(f16x8*)&Asf[srow][sk] = *(const f16x8*)&A[arow + k0];
    *(f16x8*)&Bsf[srow][sk] = *(const f16x8*)&Bt[brow + k0];
    __syncthreads();
    f16x8 a0 = *(const f16x8*)&Asf[mw*32 +      l16][lq*8];
    f16x8 a1 = *(const f16x8*)&Asf[mw*32 + 16 + l16][lq*8];
    f16x8 b0 = *(const f16x8*)&Bsf[nw*32 +      l16][lq*8];
    f16x8 b1 = *(const f16x8*)&Bsf[nw*32 + 16 + l16][lq*8];
    acc00 = __builtin_amdgcn_mfma_f32_16x16x32_f16(a0, b0, acc00, 0, 0, 0);
    acc01 = __builtin_amdgcn_mfma_f32_16x16x32_f16(a0, b1, acc01, 0, 0, 0);
    acc10 = __builtin_amdgcn_mfma_f32_16x16x32_f16(a1, b0, acc10, 0, 0, 0);
    acc11 = __builtin_amdgcn_mfma_f32_16x16x32_f16(a1, b1, acc11, 0, 0, 0);
    __syncthreads();
  }

  const int rowb = m0 + mw*32 + lq*4;
#define EPI(ACC, MT_, NT_) { \
    const int col = n0 + nw*32 + (NT_)*16 + l16; \
    if (col < N) { \
      const float bb = bias ? bias[col] : 0.f; \
      const int rb = rowb + (MT_)*16; \
      _Pragma("unroll") \
      for (int i = 0; i < 4; ++i) { \
        if (rb + i < M) { \
          const float val = ACC[i]*alpha + bb; \
          if (OUT16) Ch[(long)(rb+i)*ldc + col] = (_Float16)val; \
          else       Cf[(long)(rb+i)*ldc + col] = val; \
        } } } }
  EPI(acc00,0,0) EPI(acc01,0,1) EPI(acc10,1,0) EPI(acc11,1,1)
#undef EPI
}

// ---------------- transpose-pack: f32 src[K,N] -> f16 dst[N,K] ------------
__global__ __launch_bounds__(256) void tpack_kernel(
    const float* __restrict__ src, _Float16* __restrict__ dst, int K, int N)
{
  __shared__ float t[32][33];
  const int tx = threadIdx.x & 31, ty = threadIdx.x >> 5;  // 32 x 8
  const int n0 = blockIdx.x * 32, k0 = blockIdx.y * 32;
  #pragma unroll
  for (int i = 0; i < 4; ++i)
    t[ty + 8*i][tx] = src[(long)(k0 + ty + 8*i)*N + n0 + tx];
  __syncthreads();
  #pragma unroll
  for (int i = 0; i < 4; ++i)
    dst[(long)(n0 + ty + 8*i)*K + k0 + tx] = (_Float16)t[tx][ty + 8*i];
}

// ---------------- V transpose: qkv16 [MT][768] -> vt16 [bh][64][288] ------
__global__ __launch_bounds__(256) void vtpack_kernel(
    const _Float16* __restrict__ qkv16, _Float16* __restrict__ vt16)
{
  __shared__ _Float16 tile[64][80];
  const int z  = blockIdx.y;          // b*4 + h
  const int t0 = blockIdx.x * 64;
  const int tr = threadIdx.x >> 2, c4 = (threadIdx.x & 3) * 16;
  const int t  = t0 + tr;
  f16x8 z8 = {};
  const _Float16* src = qkv16 + ((long)((z >> 2)*T_ + t))*768 + 512 + (z & 3)*64 + c4;
  f16x8 v0 = (t < T_) ? *(const f16x8*)src       : z8;
  f16x8 v1 = (t < T_) ? *(const f16x8*)(src + 8) : z8;
  *(f16x8*)&tile[tr][c4]     = v0;
  *(f16x8*)&tile[tr][c4 + 8] = v1;
  __syncthreads();
  _Float16* dst = vt16 + ((long)z*64 + tr)*288 + t0 + c4;
  #pragma unroll
  for (int i = 0; i < 16; ++i)
    if (t0 + c4 + i < T_) dst[i] = tile[c4 + i][tr];
}

// ---------------- bias pack bq|bk|bv -> bp[768] ----------------
__global__ __launch_bounds__(256) void packb_kernel(
    const float* __restrict__ bq, const float* __restrict__ bk,
    const float* __restrict__ bv, float* __restrict__ bp)
{
  int t = threadIdx.x;
  bp[t] = bq[t]; bp[256 + t] = bk[t]; bp[512 + t] = bv[t];
}

// ---------------- LayerNorm over 256 cols: one wave per row ----------------
__global__ __launch_bounds__(256) void ln256_kernel(
    const float* __restrict__ in, const float* __restrict__ skip_pre,
    const float* __restrict__ skip_post,
    const float* __restrict__ s, const float* __restrict__ b,
    float* __restrict__ out, _Float16* __restrict__ out16)
{
  const int wid  = threadIdx.x >> 6;
  const int lane = threadIdx.x & 63;
  const long row  = (long)blockIdx.x * 4 + wid;
  const long base = row * 256 + lane * 4;

  float4 v = *(const float4*)(in + base);
  if (skip_pre) {
    float4 sp = *(const float4*)(skip_pre + base);
    v.x += sp.x; v.y += sp.y; v.z += sp.z; v.w += sp.w;
  }
  float m = v.x + v.y + v.z + v.w;
  for (int o = 32; o; o >>= 1) m += __shfl_xor(m, o);
  m *= (1.f/256.f);
  float4 d = { v.x - m, v.y - m, v.z - m, v.w - m };
  float var = d.x*d.x + d.y*d.y + d.z*d.z + d.w*d.w;
  for (int o = 32; o; o >>= 1) var += __shfl_xor(var, o);
  var *= (1.f/256.f);
  const float inv = rsqrtf(var + EPSF);
  float4 sv = *(const float4*)(s + lane*4);
  float4 bv = *(const float4*)(b + lane*4);
  float4 y;
  y.x = d.x*inv*sv.x + bv.x;
  y.y = d.y*inv*sv.y + bv.y;
  y.z = d.z*inv*sv.z + bv.z;
  y.w = d.w*inv*sv.w + bv.w;
  if (skip_post) {
    float4 sp = *(const float4*)(skip_post + base);
    y.x += sp.x; y.y += sp.y; y.z += sp.z; y.w += sp.w;
  }
  *(float4*)(out + base) = y;
  if (out16) {
    f16x4 o16 = {(_Float16)y.x, (_Float16)y.y, (_Float16)y.z, (_Float16)y.w};
    *(f16x4*)(out16 + base) = o16;
  }
}

// ---------------- GRU scan: one workgroup per batch ----------------
// Round-0 structure (396 us). Round-9/10 change: xg prefetched ONE FULL STEP
// ahead (issued before step t's dot phase, consumed in phase B of t+1) ->
// load-use distance ~3300 cyc >> ~900 cyc HBM latency (was ~800, exposed).
__global__ __launch_bounds__(1024, 1) void gru_scan_kernel(
    const float* __restrict__ xg,   // [B,T,768]
    const float* __restrict__ Wh,   // [256,768]
    const float* __restrict__ bhn,  // [256]
    float* __restrict__ g)          // [B,T,256]
{
  const int b   = blockIdx.x;
  const int tid = threadIdx.x;
  const int u   = tid & 255;   // unit
  const int kq  = tid >> 8;    // k-quarter (64 h values)

  __shared__ float hf[256];
  __shared__ __align__(16) h2_t hh2s[128];
  __shared__ float part[4][3][256];

  h2_t wr[32], wz[32], wn[32];
  #pragma unroll
  for (int r = 0; r < 32; ++r) {
    const float* p0 = Wh + (long)(kq*64 + 2*r)*768 + u;
    const float* p1 = p0 + 768;
    h2_t a; a.x = (_Float16)p0[0];   a.y = (_Float16)p1[0];   wr[r] = a;
    h2_t c; c.x = (_Float16)p0[256]; c.y = (_Float16)p1[256]; wz[r] = c;
    h2_t d; d.x = (_Float16)p0[512]; d.y = (_Float16)p1[512]; wn[r] = d;
  }
  float bn = (kq == 0) ? bhn[u] : 0.f;
  if (tid < 256) hf[tid] = 0.f;
  if (tid < 128) { h2_t zz; zz.x = (_Float16)0.f; zz.y = (_Float16)0.f; hh2s[tid] = zz; }
  __syncthreads();

  const float* xgb = xg + (long)b*T_*768;
  float* gb = g + (long)b*T_*256;

  // deep prefetch: t=0 gates loaded before the loop
  float xr = 0.f, xz = 0.f, xn = 0.f;
  if (kq == 0) { xr = xgb[u]; xz = xgb[u+256]; xn = xgb[u+512]; }

  for (int t = 0; t < T_; ++t) {
    float xrn = 0.f, xzn = 0.f, xnn = 0.f;
    if (kq == 0 && t + 1 < T_) {   // issue next step's loads NOW
      const float* xt = xgb + (long)(t + 1)*768;
      xrn = xt[u]; xzn = xt[u+256]; xnn = xt[u+512];
    }
    const float4* hq4 = (const float4*)(&hh2s[kq*32]);
    float ar = 0.f, az = 0.f, an = 0.f;
    #pragma unroll
    for (int c = 0; c < 8; ++c) {
      const float4 hc = hq4[c];   // ds_read_b128: 4 h2 pairs
      union { float f; h2_t h; } u0, u1, u2, u3;
      u0.f = hc.x; u1.f = hc.y; u2.f = hc.z; u3.f = hc.w;
#if HAS_FDOT2
      ar = __builtin_amdgcn_fdot2(u0.h, wr[c*4+0], ar, false);
      az = __builtin_amdgcn_fdot2(u0.h, wz[c*4+0], az, false);
      an = __builtin_amdgcn_fdot2(u0.h, wn[c*4+0], an, false);
      ar = __builtin_amdgcn_fdot2(u1.h, wr[c*4+1], ar, false);
      az = __builtin_amdgcn_fdot2(u1.h, wz[c*4+1], az, false);
      an = __builtin_amdgcn_fdot2(u1.h, wn[c*4+1], an, false);
      ar = __builtin_amdgcn_fdot2(u2.h, wr[c*4+2], ar, false);
      az = __builtin_amdgcn_fdot2(u2.h, wz[c*4+2], az, false);
      an = __builtin_amdgcn_fdot2(u2.h, wn[c*4+2], an, false);
      ar = __builtin_amdgcn_fdot2(u3.h, wr[c*4+3], ar, false);
      az = __builtin_amdgcn_fdot2(u3.h, wz[c*4+3], az, false);
      an = __builtin_amdgcn_fdot2(u3.h, wn[c*4+3], an, false);
#else
      ar += (float)u0.h.x*(float)wr[c*4+0].x + (float)u0.h.y*(float)wr[c*4+0].y;
      az += (float)u0.h.x*(float)wz[c*4+0].x + (float)u0.h.y*(float)wz[c*4+0].y;
      an += (float)u0.h.x*(float)wn[c*4+0].x + (float)u0.h.y*(float)wn[c*4+0].y;
      ar += (float)u1.h.x*(float)wr[c*4+1].x + (float)u1.h.y*(float)wr[c*4+1].y;
      az += (float)u1.h.x*(float)wz[c*4+1].x + (float)u1.h.y*(float)wz[c*4+1].y;
      an += (float)u1.h.x*(float)wn[c*4+1].x + (float)u1.h.y*(float)wn[c*4+1].y;
      ar += (float)u2.h.x*(float)wr[c*4+2].x + (float)u2.h.y*(float)wr[c*4+2].y;
      az += (float)u2.h.x*(float)wz[c*4+2].x + (float)u2.h.y*(float)wz[c*4+2].y;
      an += (float)u2.h.x*(float)wn[c*4+2].x + (float)u2.h.y*(float)wn[c*4+2].y;
      ar += (float)u3.h.x*(float)wr[c*4+3].x + (float)u3.h.y*(float)wr[c*4+3].y;
      az += (float)u3.h.x*(float)wz[c*4+3].x + (float)u3.h.y*(float)wz[c*4+3].y;
      an += (float)u3.h.x*(float)wn[c*4+3].x + (float)u3.h.y*(float)wn[c*4+3].y;
#endif
    }
    part[kq][0][u] = ar; part[kq][1][u] = az; part[kq][2][u] = an;
    __syncthreads();
    if (kq == 0) {
      float hr = part[0][0][u]+part[1][0][u]+part[2][0][u]+part[3][0][u] + xr;
      float hz = part[0][1][u]+part[1][1][u]+part[2][1][u]+part[3][1][u] + xz;
      float hn = part[0][2][u]+part[1][2][u]+part[2][2][u]+part[3][2][u];
      float rr = 1.f / (1.f + __expf(-hr));
      float z  = 1.f / (1.f + __expf(-hz));
      float nx = xn + rr * (hn + bn);
      float e2 = __expf(2.f * nx);
      float nv = (e2 - 1.f) / (e2 + 1.f);
      float hnew = (1.f - z) * nv + z * hf[u];
      hf[u] = hnew;
      ((_Float16*)hh2s)[u] = (_Float16)hnew;
      gb[(long)t*256 + u] = hnew;
    }
    __syncthreads();
    xr = xrn; xz = xzn; xn = xnn;
  }
}

// ---------------- softmax over 288 cols: one wave per row ------------------
// Reads f32 scores; writes NORMALIZED F16 probs into the upper half of the
// row's own f32 storage ((half*)row + 288). Safe: all loads precede stores
// within the owning wave; rows are block/wave-private. f32 is NOT written
// back (PV consumes only the f16 copy).
__global__ __launch_bounds__(256) void softmax288_kernel(float* __restrict__ S)
{
  const int wid  = threadIdx.x >> 6;
  const int lane = threadIdx.x & 63;
  long row = (long)blockIdx.x * 4 + wid;
  float* p = S + row * T_;
  _Float16* p16 = (_Float16*)p + 288;

  float4 v = *(const float4*)(p + lane*4);
  float v4 = (lane < 32) ? p[256 + lane] : -1e30f;
  float mx = fmaxf(fmaxf(fmaxf(v.x, v.y), fmaxf(v.z, v.w)), v4);
  for (int o = 32; o; o >>= 1) mx = fmaxf(mx, __shfl_xor(mx, o));
  v.x = __expf(v.x - mx); v.y = __expf(v.y - mx);
  v.z = __expf(v.z - mx); v.w = __expf(v.w - mx);
  v4  = (lane < 32) ? __expf(v4 - mx) : 0.f;
  float sm = v.x + v.y + v.z + v.w + v4;
  for (int o = 32; o; o >>= 1) sm += __shfl_xor(sm, o);
  const float inv = 1.f / sm;
  f16x4 o16 = {(_Float16)(v.x*inv), (_Float16)(v.y*inv),
               (_Float16)(v.z*inv), (_Float16)(v.w*inv)};
  *(f16x4*)(p16 + lane*4) = o16;
  if (lane < 32) p16[256 + lane] = (_Float16)(v4 * inv);
}

// ---------------- mean over T ----------------
__global__ __launch_bounds__(256) void meanT_kernel(
    const float* __restrict__ x, float* __restrict__ xm)
{
  int b = blockIdx.x, u = threadIdx.x;
  const float* p = x + (long)b*T_*U_ + u;
  float s = 0.f;
  for (int t = 0; t < T_; ++t) s += p[(long)t*U_];
  xm[b*U_ + u] = s * (1.f/(float)T_);
}

// ---------------- MLP head: one block per batch ----------------
__global__ __launch_bounds__(128) void head_kernel(
    const float* __restrict__ xm, const float* __restrict__ other,
    const float* __restrict__ m1W, const float* __restrict__ m1b,
    const float* __restrict__ l1s, const float* __restrict__ l1b,
    const float* __restrict__ m2W, const float* __restrict__ m2b,
    const float* __restrict__ l2s, const float* __restrict__ l2b,
    const float* __restrict__ oW,  const float* __restrict__ ob,
    float* __restrict__ outp)
{
  __shared__ float c[320];
  __shared__ float h1[128];
  __shared__ float sb[2];
  int b = blockIdx.x, tid = threadIdx.x;
  c[tid]       = xm[b*256 + tid];
  c[tid + 128] = xm[b*256 + tid + 128];
  if (tid < 64) c[256 + tid] = other[b*64 + tid];
  __syncthreads();
  float s = m1b[tid];
  for (int i = 0; i < 320; ++i) s += c[i] * m1W[i*128 + tid];
  s = fmaxf(s, 0.f);
  float m = s;
  for (int o = 32; o; o >>= 1) m += __shfl_xor(m, o);
  if ((tid & 63) == 0) sb[tid >> 6] = m;
  __syncthreads();
  m = (sb[0] + sb[1]) * (1.f/128.f);
  __syncthreads();
  float d = s - m, var = d*d;
  for (int o = 32; o; o >>= 1) var += __shfl_xor(var, o);
  if ((tid & 63) == 0) sb[tid >> 6] = var;
  __syncthreads();
  var = (sb[0] + sb[1]) * (1.f/128.f);
  h1[tid] = d * rsqrtf(var + EPSF) * l1s[tid] + l1b[tid];
  __syncthreads();
  if (tid < 64) {
    float s2 = m2b[tid];
    for (int i = 0; i < 128; ++i) s2 += h1[i] * m2W[i*64 + tid];
    s2 = fmaxf(s2, 0.f);
    float m2 = s2;
    for (int o = 32; o; o >>= 1) m2 += __shfl_xor(m2, o);
    m2 *= (1.f/64.f);
    float d2 = s2 - m2, v2 = d2*d2;
    for (int o = 32; o; o >>= 1) v2 += __shfl_xor(v2, o);
    v2 *= (1.f/64.f);
    float h2v = d2 * rsqrtf(v2 + EPSF) * l2s[tid] + l2b[tid];
    float y = h2v * oW[tid];
    for (int o = 32; o; o >>= 1) y += __shfl_xor(y, o);
    if (tid == 0) outp[b] = y + ob[0];
  }
}

// ---------------- host orchestration ----------------
static inline void gemm_nn(hipStream_t st, const float* A, const float* Bm, float* C,
                           const float* bias, int M, int N, int K,
                           int lda, int ldb, int ldc, float alpha)
{
  dim3 g((N + 63)/64, (M + 63)/64, 1);
  gemm_kernel<false><<<g, 256, 0, st>>>(A, Bm, C, bias, M, N, K, lda, ldb, ldc,
                                        0,0,0,0,0,0, 1, alpha);
}

// plain (non-batched) f16 GEMM: lda=ldb=K
static inline void gemm16(hipStream_t st, const _Float16* A, const _Float16* Bt,
                          void* C, const float* bias, int M, int N, int K,
                          int ldc, bool out16)
{
  dim3 g((N + 63)/64, (M + 63)/64, 1);
  if (out16)
    gemm16_kernel<true ><<<g, 256, 0, st>>>(A, Bt, C, bias, M, N, K, K, K, ldc,
                                            0,0,0,0,0,0, 1, 1.f);
  else
    gemm16_kernel<false><<<g, 256, 0, st>>>(A, Bt, C, bias, M, N, K, K, K, ldc,
                                            0,0,0,0,0,0, 1, 1.f);
}

extern "C" void kernel_launch(void* const* d_in, const int* in_sizes, int n_in,
                              void* d_out, int out_size, void* d_ws, size_t ws_size,
                              hipStream_t stream)
{
  const float* cgm   = (const float*)d_in[0];
  const float* other = (const float*)d_in[1];
  const float* d0_W  = (const float*)d_in[2];
  const float* d0_b  = (const float*)d_in[3];
  const float* ln0_s = (const float*)d_in[4];
  const float* ln0_b = (const float*)d_in[5];
  const float* gWi   = (const float*)d_in[6];
  const float* gbi   = (const float*)d_in[7];
  const float* gWh   = (const float*)d_in[8];
  const float* gbhn  = (const float*)d_in[9];
  const float* ln1_s = (const float*)d_in[10];
  const float* ln1_b = (const float*)d_in[11];
  const float* Wq    = (const float*)d_in[12];
  const float* bq    = (const float*)d_in[13];
  const float* Wk    = (const float*)d_in[14];
  const float* bk    = (const float*)d_in[15];
  const float* Wv    = (const float*)d_in[16];
  const float* bv    = (const float*)d_in[17];
  const float* Wo    = (const float*)d_in[18];
  const float* bo    = (const float*)d_in[19];
  const float* ln2_s = (const float*)d_in[20];
  const float* ln2_b = (const float*)d_in[21];
  const float* m1W   = (const float*)d_in[22];
  const float* m1b   = (const float*)d_in[23];
  const float* l1s   = (const float*)d_in[24];
  const float* l1b   = (const float*)d_in[25];
  const float* m2W   = (const float*)d_in[26];
  const float* m2b   = (const float*)d_in[27];
  const float* l2s   = (const float*)d_in[28];
  const float* l2b   = (const float*)d_in[29];
  const float* oW    = (const float*)d_in[30];
  const float* ob    = (const float*)d_in[31];
  float* out = (float*)d_out;

  // workspace layout (floats)
  float* ws   = (float*)d_ws;
  float* big  = ws;                   // 28,311,552 fl: xg f32, later qkv16+vt16
  float* x    = big  + 28311552;      //  9,437,184
  float* go   = x    +  9437184;      //  9,437,184  (g f32; later o16 f16)
  float* Sbuf = go   +  9437184;      // a16 + scores (lifetime-disjoint)
  (void)in_sizes; (void)n_in; (void)out_size;

  // attention chunking (scores f32; f16 probs ride inside the same rows)
  const size_t wsf = ws_size / sizeof(float);
  const long base_f = 28311552L + 9437184L + 9437184L;
  int nch;
  long sfloats;
  if      (wsf >= (size_t)(base_f + 512L*T_*T_ + 32768)) { nch = 1; sfloats = 512L*T_*T_; }
  else if (wsf >= (size_t)(base_f + 256L*T_*T_ + 32768)) { nch = 2; sfloats = 256L*T_*T_; }
  else                                                    { nch = 4; sfloats = 128L*T_*T_; }
  const int nb = 128 / nch;
  float* xmean = Sbuf + sfloats;

  // f16 views
  _Float16* a16   = (_Float16*)Sbuf;                       // x16 (dead during attn)
  _Float16* qkv16 = (_Float16*)big;                        // 28,311,552 halves
  _Float16* vt16  = (_Float16*)big + 28311552;             //  9,437,184 halves
  _Float16* o16   = (_Float16*)go;                         //  9,437,184 halves
  _Float16* wtWi  = (_Float16*)(Sbuf + 4718592);           //    196,608 halves
  _Float16* wtQKV = (_Float16*)(Sbuf + 4718592 + 98304);   //    196,608 halves
  _Float16* wtWo  = (_Float16*)(Sbuf + 4718592 + 196608);  //     65,536 halves
  float*    bqkv  =             Sbuf + 4718592 + 229376;   //        768 fl

  // x = LN(cgm @ d0_W + d0_b)  (+ f16 copy)
  gemm_nn(stream, cgm, d0_W, big, d0_b, MT, 256, 16, 16, 256, 256, 1.f);
  ln256_kernel<<<MT/4, 256, 0, stream>>>(big, nullptr, nullptr, ln0_s, ln0_b, x, a16);

  for (int i = 0; i < 2; ++i) {
    const float* Wh_i = gWh + (long)i*196608;

    // xg = x @ Wi + bi  (f16 MFMA, f32 out for GRU)
    tpack_kernel<<<dim3(24, 8), 256, 0, stream>>>(gWi + (long)i*196608, wtWi, 256, 768);
    gemm16(stream, a16, wtWi, big, gbi + i*768, MT, 768, 256, 768, false);
    // GRU scan
    gru_scan_kernel<<<128, 1024, 0, stream>>>(big, Wh_i, gbhn + i*256, go);
    // x = LN(g) + x  (+ f16 copy)
    ln256_kernel<<<MT/4, 256, 0, stream>>>(go, nullptr, x, ln1_s + i*256, ln1_b + i*256, x, a16);

    // qkv in ONE f16 MFMA gemm, F16 OUTPUT (only attention consumes it)
    tpack_kernel<<<dim3(8, 8), 256, 0, stream>>>(Wq + (long)i*65536, wtQKV,            256, 256);
    tpack_kernel<<<dim3(8, 8), 256, 0, stream>>>(Wk + (long)i*65536, wtQKV + 256*256,  256, 256);
    tpack_kernel<<<dim3(8, 8), 256, 0, stream>>>(Wv + (long)i*65536, wtQKV + 512*256,  256, 256);
    packb_kernel<<<1, 256, 0, stream>>>(bq + i*256, bk + i*256, bv + i*256, bqkv);
    gemm16(stream, a16, wtQKV, qkv16, bqkv, MT, 768, 256, 768, true);

    // V transpose for PV's Bt operand
    vtpack_kernel<<<dim3(5, 512), 256, 0, stream>>>(qkv16, vt16);

    // attention in nch chunks (all f16 MFMA; scores f32 in Sbuf)
    for (int cb = 0; cb < nch; ++cb) {
      const _Float16* qb16 = qkv16 + (long)cb*nb*T_*768;
      {  // QK^T: A=q, Bt=k, both [288][64] lda/ldb=768
        dim3 g(5, 5, nb*4);
        gemm16_kernel<false><<<g, 256, 0, stream>>>(
            qb16, qb16 + 256, Sbuf, nullptr,
            T_, T_, 64, 768, 768, T_,
            (long)T_*768, 64, (long)T_*768, 64, (long)4*T_*T_, (long)T_*T_,
            4, 0.125f);
      }
      softmax288_kernel<<<(nb*4*T_)/4, 256, 0, stream>>>(Sbuf);
      {  // PV: A=P16 (in-row f16, lda=576 halves), Bt=vt16 (CHUNK-OFFSET!),
         //     C=o16 f16
        dim3 g(1, 5, nb*4);
        gemm16_kernel<true><<<g, 256, 0, stream>>>(
            (const _Float16*)Sbuf + 288,
            vt16 + (long)cb*nb*4*64*288,      // round-10 fix: was base vt16
            o16 + (long)cb*nb*T_*256, nullptr,
            T_, 64, T_, 576, 288, 256,
            (long)4*T_*576, (long)T_*576, (long)4*64*288, (long)64*288,
            (long)T_*256, 64,
            4, 1.f);
      }
    }

    // a = o16 @ Wo + bo (f32 out into big; attention done, wt region free)
    tpack_kernel<<<dim3(8, 8), 256, 0, stream>>>(Wo + (long)i*65536, wtWo, 256, 256);
    gemm16(stream, o16, wtWo, big, bo + i*256, MT, 256, 256, 256, false);
    // x = LN(a + x)  (+ f16 copy)
    ln256_kernel<<<MT/4, 256, 0, stream>>>(big, x, nullptr, ln2_s + i*256, ln2_b + i*256, x, a16);
  }

  meanT_kernel<<<128, 256, 0, stream>>>(x, xmean);
  head_kernel<<<128, 128, 0, stream>>>(xmean, other, m1W, m1b, l1s, l1b,
                                       m2W, m2b, l2s, l2b, oW, ob, out);
}

// Round 11
// 1459.722 us; speedup vs baseline: 3.0159x; 1.1647x over previous
//
#include <hip/hip_runtime.h>
#include <math.h>

// ---------------- constants ----------------
#define B_   128
#define T_   288
#define U_   256
#define H_   4
#define HD_  64
#define MT   (B_*T_)     // 36864 rows
#define EPSF 1e-6f

typedef _Float16 h2_t  __attribute__((ext_vector_type(2)));
typedef _Float16 f16x4 __attribute__((ext_vector_type(4)));
typedef _Float16 f16x8 __attribute__((ext_vector_type(8)));
typedef float    f32x4 __attribute__((ext_vector_type(4)));

#if defined(__has_builtin)
#  if __has_builtin(__builtin_amdgcn_fdot2)
#    define HAS_FDOT2 1
#  endif
#endif
#ifndef HAS_FDOT2
#  define HAS_FDOT2 0
#endif

// ---------------- generic tiled fp32 GEMM (d0 only) ----------
template<bool TB>
__global__ __launch_bounds__(256) void gemm_kernel(
    const float* __restrict__ A, const float* __restrict__ Bm,
    float* __restrict__ C, const float* __restrict__ bias,
    int M, int N, int K, int lda, int ldb, int ldc,
    long sA1, long sA2, long sB1, long sB2, long sC1, long sC2,
    int zdiv, float alpha)
{
  int z  = blockIdx.z;
  int z1 = z / zdiv, z2 = z - z1 * zdiv;
  A  += (long)z1*sA1 + (long)z2*sA2;
  Bm += (long)z1*sB1 + (long)z2*sB2;
  C  += (long)z1*sC1 + (long)z2*sC2;

  __shared__ float As[16][68];
  __shared__ float Bs[16][68];

  const int tid = threadIdx.x;
  const int tx  = tid & 15;
  const int ty  = tid >> 4;
  const int rowBase = blockIdx.y * 64;
  const int colBase = blockIdx.x * 64;

  float acc[4][4] = {};

  const int lr = tid >> 2;
  const int lk = (tid & 3) << 2;

  for (int k0 = 0; k0 < K; k0 += 16) {
    {
      float4 a4 = {0.f,0.f,0.f,0.f};
      int ar = rowBase + lr;
      if (ar < M) a4 = *(const float4*)(A + (long)ar*lda + k0 + lk);
      As[lk+0][lr]=a4.x; As[lk+1][lr]=a4.y; As[lk+2][lr]=a4.z; As[lk+3][lr]=a4.w;
    }
    if (TB) {
      float4 b4 = {0.f,0.f,0.f,0.f};
      int bn = colBase + lr;
      if (bn < N) b4 = *(const float4*)(Bm + (long)bn*ldb + k0 + lk);
      Bs[lk+0][lr]=b4.x; Bs[lk+1][lr]=b4.y; Bs[lk+2][lr]=b4.z; Bs[lk+3][lr]=b4.w;
    } else {
      int bk  = tid >> 4;
      int bn4 = (tid & 15) << 2;
      float4 b4 = {0.f,0.f,0.f,0.f};
      if (colBase + bn4 < N) b4 = *(const float4*)(Bm + (long)(k0+bk)*ldb + colBase + bn4);
      *(float4*)(&Bs[bk][bn4]) = b4;
    }
    __syncthreads();
    #pragma unroll
    for (int k = 0; k < 16; ++k) {
      float4 av = *(const float4*)(&As[k][ty<<2]);
      float4 bv = *(const float4*)(&Bs[k][tx<<2]);
      acc[0][0]+=av.x*bv.x; acc[0][1]+=av.x*bv.y; acc[0][2]+=av.x*bv.z; acc[0][3]+=av.x*bv.w;
      acc[1][0]+=av.y*bv.x; acc[1][1]+=av.y*bv.y; acc[1][2]+=av.y*bv.z; acc[1][3]+=av.y*bv.w;
      acc[2][0]+=av.z*bv.x; acc[2][1]+=av.z*bv.y; acc[2][2]+=av.z*bv.z; acc[2][3]+=av.z*bv.w;
      acc[3][0]+=av.w*bv.x; acc[3][1]+=av.w*bv.y; acc[3][2]+=av.w*bv.z; acc[3][3]+=av.w*bv.w;
    }
    __syncthreads();
  }

  const int cn = colBase + (tx << 2);
  if (cn < N) {
    float4 bb = {0.f,0.f,0.f,0.f};
    if (bias) bb = *(const float4*)(bias + cn);
    #pragma unroll
    for (int i = 0; i < 4; ++i) {
      int r = rowBase + (ty << 2) + i;
      if (r < M) {
        float4 v;
        v.x = acc[i][0]*alpha + bb.x;
        v.y = acc[i][1]*alpha + bb.y;
        v.z = acc[i][2]*alpha + bb.z;
        v.w = acc[i][3]*alpha + bb.w;
        *(float4*)(C + (long)r*ldc + cn) = v;
      }
    }
  }
}

// ---------------- f16 MFMA GEMM (batched, guarded, f32/f16 out) ----------
// C[M,N] = alpha * A16[M,K](lda) @ Bt16[N,K](ldb)^T + bias[N]
// 64x64 tile, BK=32, 256 thr = 4 waves 2x2. Fragment convention verified
// rounds 3-10: a-frag lane(l16,lq)[e]=A[m0+l16][k0+lq*8+e]; same for Bt;
// C/D row=lq*4+r, col=l16.
template<bool OUT16>
__global__ __launch_bounds__(256) void gemm16_kernel(
    const _Float16* __restrict__ A, const _Float16* __restrict__ Bt,
    void* __restrict__ Cv, const float* __restrict__ bias,
    int M, int N, int K, int lda, int ldb, int ldc,
    long sA1, long sA2, long sB1, long sB2, long sC1, long sC2,
    int zdiv, float alpha)
{
  const int z  = blockIdx.z;
  const int z1 = z / zdiv, z2 = z - z1 * zdiv;
  A  += (long)z1*sA1 + (long)z2*sA2;
  Bt += (long)z1*sB1 + (long)z2*sB2;
  float*    Cf = (float*)Cv    + ((long)z1*sC1 + (long)z2*sC2);
  _Float16* Ch = (_Float16*)Cv + ((long)z1*sC1 + (long)z2*sC2);

  __shared__ __align__(16) _Float16 Asf[64][40];
  __shared__ __align__(16) _Float16 Bsf[64][40];
  const int tid  = threadIdx.x;
  const int wv   = tid >> 6;
  const int mw   = wv >> 1, nw = wv & 1;
  const int lane = tid & 63, l16 = lane & 15, lq = lane >> 4;
  const int m0 = blockIdx.y * 64, n0 = blockIdx.x * 64;
  const int srow = tid >> 2, sk = (tid & 3) * 8;

  f32x4 acc00 = {0,0,0,0}, acc01 = {0,0,0,0};
  f32x4 acc10 = {0,0,0,0}, acc11 = {0,0,0,0};

  const long arow = (long)(m0 + srow)*lda + sk;
  const long brow = (long)(n0 + srow)*ldb + sk;

  for (int k0 = 0; k0 < K; k0 += 32) {
    *(f16x8*)&Asf[srow][sk] = *(const f16x8*)&A[arow + k0];
    *(f16x8*)&Bsf[srow][sk] = *(const f16x8*)&Bt[brow + k0];
    __syncthreads();
    f16x8 a0 = *(const f16x8*)&Asf[mw*32 +      l16][lq*8];
    f16x8 a1 = *(const f16x8*)&Asf[mw*32 + 16 + l16][lq*8];
    f16x8 b0 = *(const f16x8*)&Bsf[nw*32 +      l16][lq*8];
    f16x8 b1 = *(const f16x8*)&Bsf[nw*32 + 16 + l16][lq*8];
    acc00 = __builtin_amdgcn_mfma_f32_16x16x32_f16(a0, b0, acc00, 0, 0, 0);
    acc01 = __builtin_amdgcn_mfma_f32_16x16x32_f16(a0, b1, acc01, 0, 0, 0);
    acc10 = __builtin_amdgcn_mfma_f32_16x16x32_f16(a1, b0, acc10, 0, 0, 0);
    acc11 = __builtin_amdgcn_mfma_f32_16x16x32_f16(a1, b1, acc11, 0, 0, 0);
    __syncthreads();
  }

  const int rowb = m0 + mw*32 + lq*4;
#define EPI(ACC, MT_, NT_) { \
    const int col = n0 + nw*32 + (NT_)*16 + l16; \
    if (col < N) { \
      const float bb = bias ? bias[col] : 0.f; \
      const int rb = rowb + (MT_)*16; \
      _Pragma("unroll") \
      for (int i = 0; i < 4; ++i) { \
        if (rb + i < M) { \
          const float val = ACC[i]*alpha + bb; \
          if (OUT16) Ch[(long)(rb+i)*ldc + col] = (_Float16)val; \
          else       Cf[(long)(rb+i)*ldc + col] = val; \
        } } } }
  EPI(acc00,0,0) EPI(acc01,0,1) EPI(acc10,1,0) EPI(acc11,1,1)
#undef EPI
}

// ---------------- fused attention: one (Q-tile, b*h) per block -----------
// 256 thr = 4 waves; wave w owns Q rows [q0+w*16, q0+w*16+16) x ALL 288 keys.
// QK^T: Q a-frag + K b-frags GLOBAL-DIRECT (L1/L2-cached re-reads, ~368MB/
// layer at L2 BW). acc[18] f32x4 in C-layout: row=lq*4+r, col=t*16+l16.
// Softmax: per-row max/sum via __shfl_xor 1/2/4/8 (stays inside the l16
// group; row id (lq,r) is xor-invariant on bits 0-3). Scale folded:
// exp(0.125*(a-m)). P goes through LDS [w][16][296] (row stride 592B,
// conflict-light) to convert C-layout -> A-frag layout. PV: Bt = vt16
// global-direct. OOB Q rows (grid 5x64 vs T=288 + tail waves): reads land
// in workspace, garbage stays row-local (softmax per-row, MFMA C row m
// depends only on A row m); all O writes row-guarded.
__global__ __launch_bounds__(256) void fused_attn_kernel(
    const _Float16* __restrict__ qkv16,  // [B*T][768]  q|k|v
    const _Float16* __restrict__ vt16,   // [B*H][64][288]
    _Float16* __restrict__ o16)          // [B*T][256]
{
  __shared__ __align__(16) _Float16 Pl[4][16][296];
  const int tid  = threadIdx.x;
  const int w    = tid >> 6;
  const int lane = tid & 63, l16 = lane & 15, lq = lane >> 4;
  const int z = blockIdx.y;            // b*4 + h
  const int b = z >> 2, h = z & 3;
  const int q0 = blockIdx.x * 64 + w * 16;
  const long rowbase = (long)b * T_;

  // ---- QK^T ----
  const _Float16* qp = qkv16 + (rowbase + q0 + l16) * 768 + h*64 + lq*8;
  f16x8 qf0 = *(const f16x8*)qp;
  f16x8 qf1 = *(const f16x8*)(qp + 32);
  f32x4 acc[18];
  const _Float16* kp = qkv16 + (rowbase + l16) * 768 + 256 + h*64 + lq*8;
  #pragma unroll
  for (int t = 0; t < 18; ++t) {
    f16x8 kf0 = *(const f16x8*)(kp + (long)t*16*768);
    f16x8 kf1 = *(const f16x8*)(kp + (long)t*16*768 + 32);
    f32x4 a = {0.f, 0.f, 0.f, 0.f};
    a = __builtin_amdgcn_mfma_f32_16x16x32_f16(qf0, kf0, a, 0, 0, 0);
    a = __builtin_amdgcn_mfma_f32_16x16x32_f16(qf1, kf1, a, 0, 0, 0);
    acc[t] = a;
  }

  // ---- row softmax + P (f16) into LDS in A-frag-readable layout ----
  #pragma unroll
  for (int r = 0; r < 4; ++r) {
    float m = -1e30f;
    #pragma unroll
    for (int t = 0; t < 18; ++t) m = fmaxf(m, acc[t][r]);
    m = fmaxf(m, __shfl_xor(m, 1)); m = fmaxf(m, __shfl_xor(m, 2));
    m = fmaxf(m, __shfl_xor(m, 4)); m = fmaxf(m, __shfl_xor(m, 8));
    float p[18];
    float s = 0.f;
    #pragma unroll
    for (int t = 0; t < 18; ++t) {
      p[t] = __expf(0.125f * (acc[t][r] - m));
      s += p[t];
    }
    s += __shfl_xor(s, 1); s += __shfl_xor(s, 2);
    s += __shfl_xor(s, 4); s += __shfl_xor(s, 8);
    const float inv = 1.f / s;
    #pragma unroll
    for (int t = 0; t < 18; ++t)
      Pl[w][lq*4 + r][t*16 + l16] = (_Float16)(p[t] * inv);
  }
  __syncthreads();   // cheap (once per block); orders P writes vs reads

  // ---- PV ----
  f32x4 accO[4] = {{0,0,0,0},{0,0,0,0},{0,0,0,0},{0,0,0,0}};
  const _Float16* vb = vt16 + ((long)z*64 + l16)*288 + lq*8;
  #pragma unroll
  for (int ks = 0; ks < 9; ++ks) {
    f16x8 pa = *(const f16x8*)&Pl[w][l16][ks*32 + lq*8];
    #pragma unroll
    for (int n = 0; n < 4; ++n) {
      f16x8 vf = *(const f16x8*)(vb + (long)n*16*288 + ks*32);
      accO[n] = __builtin_amdgcn_mfma_f32_16x16x32_f16(pa, vf, accO[n], 0, 0, 0);
    }
  }

  // ---- write O (row-guarded) ----
  #pragma unroll
  for (int n = 0; n < 4; ++n) {
    const int col = h*64 + n*16 + l16;
    #pragma unroll
    for (int r = 0; r < 4; ++r) {
      const int row = q0 + lq*4 + r;
      if (row < T_)
        o16[(rowbase + row)*256 + col] = (_Float16)accO[n][r];
    }
  }
}

// ---------------- transpose-pack: f32 src[K,N] -> f16 dst[N,K] ------------
__global__ __launch_bounds__(256) void tpack_kernel(
    const float* __restrict__ src, _Float16* __restrict__ dst, int K, int N)
{
  __shared__ float t[32][33];
  const int tx = threadIdx.x & 31, ty = threadIdx.x >> 5;  // 32 x 8
  const int n0 = blockIdx.x * 32, k0 = blockIdx.y * 32;
  #pragma unroll
  for (int i = 0; i < 4; ++i)
    t[ty + 8*i][tx] = src[(long)(k0 + ty + 8*i)*N + n0 + tx];
  __syncthreads();
  #pragma unroll
  for (int i = 0; i < 4; ++i)
    dst[(long)(n0 + ty + 8*i)*K + k0 + tx] = (_Float16)t[tx][ty + 8*i];
}

// ---------------- V transpose: qkv16 [MT][768] -> vt16 [bh][64][288] ------
__global__ __launch_bounds__(256) void vtpack_kernel(
    const _Float16* __restrict__ qkv16, _Float16* __restrict__ vt16)
{
  __shared__ _Float16 tile[64][80];
  const int z  = blockIdx.y;          // b*4 + h
  const int t0 = blockIdx.x * 64;
  const int tr = threadIdx.x >> 2, c4 = (threadIdx.x & 3) * 16;
  const int t  = t0 + tr;
  f16x8 z8 = {};
  const _Float16* src = qkv16 + ((long)((z >> 2)*T_ + t))*768 + 512 + (z & 3)*64 + c4;
  f16x8 v0 = (t < T_) ? *(const f16x8*)src       : z8;
  f16x8 v1 = (t < T_) ? *(const f16x8*)(src + 8) : z8;
  *(f16x8*)&tile[tr][c4]     = v0;
  *(f16x8*)&tile[tr][c4 + 8] = v1;
  __syncthreads();
  _Float16* dst = vt16 + ((long)z*64 + tr)*288 + t0 + c4;
  #pragma unroll
  for (int i = 0; i < 16; ++i)
    if (t0 + c4 + i < T_) dst[i] = tile[c4 + i][tr];
}

// ---------------- bias pack bq|bk|bv -> bp[768] ----------------
__global__ __launch_bounds__(256) void packb_kernel(
    const float* __restrict__ bq, const float* __restrict__ bk,
    const float* __restrict__ bv, float* __restrict__ bp)
{
  int t = threadIdx.x;
  bp[t] = bq[t]; bp[256 + t] = bk[t]; bp[512 + t] = bv[t];
}

// ---------------- LayerNorm over 256 cols: one wave per row ----------------
__global__ __launch_bounds__(256) void ln256_kernel(
    const float* __restrict__ in, const float* __restrict__ skip_pre,
    const float* __restrict__ skip_post,
    const float* __restrict__ s, const float* __restrict__ b,
    float* __restrict__ out, _Float16* __restrict__ out16)
{
  const int wid  = threadIdx.x >> 6;
  const int lane = threadIdx.x & 63;
  const long row  = (long)blockIdx.x * 4 + wid;
  const long base = row * 256 + lane * 4;

  float4 v = *(const float4*)(in + base);
  if (skip_pre) {
    float4 sp = *(const float4*)(skip_pre + base);
    v.x += sp.x; v.y += sp.y; v.z += sp.z; v.w += sp.w;
  }
  float m = v.x + v.y + v.z + v.w;
  for (int o = 32; o; o >>= 1) m += __shfl_xor(m, o);
  m *= (1.f/256.f);
  float4 d = { v.x - m, v.y - m, v.z - m, v.w - m };
  float var = d.x*d.x + d.y*d.y + d.z*d.z + d.w*d.w;
  for (int o = 32; o; o >>= 1) var += __shfl_xor(var, o);
  var *= (1.f/256.f);
  const float inv = rsqrtf(var + EPSF);
  float4 sv = *(const float4*)(s + lane*4);
  float4 bv = *(const float4*)(b + lane*4);
  float4 y;
  y.x = d.x*inv*sv.x + bv.x;
  y.y = d.y*inv*sv.y + bv.y;
  y.z = d.z*inv*sv.z + bv.z;
  y.w = d.w*inv*sv.w + bv.w;
  if (skip_post) {
    float4 sp = *(const float4*)(skip_post + base);
    y.x += sp.x; y.y += sp.y; y.z += sp.z; y.w += sp.w;
  }
  *(float4*)(out + base) = y;
  if (out16) {
    f16x4 o16 = {(_Float16)y.x, (_Float16)y.y, (_Float16)y.z, (_Float16)y.w};
    *(f16x4*)(out16 + base) = o16;
  }
}

// ---------------- GRU scan: one workgroup per batch ----------------
// EXACT round-8 kernel (397 us measured). Round-10's deep prefetch
// regressed to 420 us (reverted); dot phase reads h as 8x ds_read_b128.
__global__ __launch_bounds__(1024, 1) void gru_scan_kernel(
    const float* __restrict__ xg,   // [B,T,768]
    const float* __restrict__ Wh,   // [256,768]
    const float* __restrict__ bhn,  // [256]
    float* __restrict__ g)          // [B,T,256]
{
  const int b   = blockIdx.x;
  const int tid = threadIdx.x;
  const int u   = tid & 255;   // unit
  const int kq  = tid >> 8;    // k-quarter (64 h values)

  __shared__ float hf[256];
  __shared__ __align__(16) h2_t hh2s[128];
  __shared__ float part[4][3][256];

  h2_t wr[32], wz[32], wn[32];
  #pragma unroll
  for (int r = 0; r < 32; ++r) {
    const float* p0 = Wh + (long)(kq*64 + 2*r)*768 + u;
    const float* p1 = p0 + 768;
    h2_t a; a.x = (_Float16)p0[0];   a.y = (_Float16)p1[0];   wr[r] = a;
    h2_t c; c.x = (_Float16)p0[256]; c.y = (_Float16)p1[256]; wz[r] = c;
    h2_t d; d.x = (_Float16)p0[512]; d.y = (_Float16)p1[512]; wn[r] = d;
  }
  float bn = (kq == 0) ? bhn[u] : 0.f;
  if (tid < 256) hf[tid] = 0.f;
  if (tid < 128) { h2_t zz; zz.x = (_Float16)0.f; zz.y = (_Float16)0.f; hh2s[tid] = zz; }
  __syncthreads();

  const float* xgb = xg + (long)b*T_*768;
  float* gb = g + (long)b*T_*256;

  for (int t = 0; t < T_; ++t) {
    float xr = 0.f, xz = 0.f, xn = 0.f;
    if (kq == 0) {  // prefetch input gates; latency hidden behind dot phase
      const float* xt = xgb + (long)t*768;
      xr = xt[u]; xz = xt[u+256]; xn = xt[u+512];
    }
    const float4* hq4 = (const float4*)(&hh2s[kq*32]);
    float ar = 0.f, az = 0.f, an = 0.f;
    #pragma unroll
    for (int c = 0; c < 8; ++c) {
      const float4 hc = hq4[c];   // ds_read_b128: 4 h2 pairs
      union { float f; h2_t h; } u0, u1, u2, u3;
      u0.f = hc.x; u1.f = hc.y; u2.f = hc.z; u3.f = hc.w;
#if HAS_FDOT2
      ar = __builtin_amdgcn_fdot2(u0.h, wr[c*4+0], ar, false);
      az = __builtin_amdgcn_fdot2(u0.h, wz[c*4+0], az, false);
      an = __builtin_amdgcn_fdot2(u0.h, wn[c*4+0], an, false);
      ar = __builtin_amdgcn_fdot2(u1.h, wr[c*4+1], ar, false);
      az = __builtin_amdgcn_fdot2(u1.h, wz[c*4+1], az, false);
      an = __builtin_amdgcn_fdot2(u1.h, wn[c*4+1], an, false);
      ar = __builtin_amdgcn_fdot2(u2.h, wr[c*4+2], ar, false);
      az = __builtin_amdgcn_fdot2(u2.h, wz[c*4+2], az, false);
      an = __builtin_amdgcn_fdot2(u2.h, wn[c*4+2], an, false);
      ar = __builtin_amdgcn_fdot2(u3.h, wr[c*4+3], ar, false);
      az = __builtin_amdgcn_fdot2(u3.h, wz[c*4+3], az, false);
      an = __builtin_amdgcn_fdot2(u3.h, wn[c*4+3], an, false);
#else
      ar += (float)u0.h.x*(float)wr[c*4+0].x + (float)u0.h.y*(float)wr[c*4+0].y;
      az += (float)u0.h.x*(float)wz[c*4+0].x + (float)u0.h.y*(float)wz[c*4+0].y;
      an += (float)u0.h.x*(float)wn[c*4+0].x + (float)u0.h.y*(float)wn[c*4+0].y;
      ar += (float)u1.h.x*(float)wr[c*4+1].x + (float)u1.h.y*(float)wr[c*4+1].y;
      az += (float)u1.h.x*(float)wz[c*4+1].x + (float)u1.h.y*(float)wz[c*4+1].y;
      an += (float)u1.h.x*(float)wn[c*4+1].x + (float)u1.h.y*(float)wn[c*4+1].y;
      ar += (float)u2.h.x*(float)wr[c*4+2].x + (float)u2.h.y*(float)wr[c*4+2].y;
      az += (float)u2.h.x*(float)wz[c*4+2].x + (float)u2.h.y*(float)wz[c*4+2].y;
      an += (float)u2.h.x*(float)wn[c*4+2].x + (float)u2.h.y*(float)wn[c*4+2].y;
      ar += (float)u3.h.x*(float)wr[c*4+3].x + (float)u3.h.y*(float)wr[c*4+3].y;
      az += (float)u3.h.x*(float)wz[c*4+3].x + (float)u3.h.y*(float)wz[c*4+3].y;
      an += (float)u3.h.x*(float)wn[c*4+3].x + (float)u3.h.y*(float)wn[c*4+3].y;
#endif
    }
    part[kq][0][u] = ar; part[kq][1][u] = az; part[kq][2][u] = an;
    __syncthreads();
    if (kq == 0) {
      float hr = part[0][0][u]+part[1][0][u]+part[2][0][u]+part[3][0][u] + xr;
      float hz = part[0][1][u]+part[1][1][u]+part[2][1][u]+part[3][1][u] + xz;
      float hn = part[0][2][u]+part[1][2][u]+part[2][2][u]+part[3][2][u];
      float rr = 1.f / (1.f + __expf(-hr));
      float z  = 1.f / (1.f + __expf(-hz));
      float nx = xn + rr * (hn + bn);
      float e2 = __expf(2.f * nx);
      float nv = (e2 - 1.f) / (e2 + 1.f);
      float hnew = (1.f - z) * nv + z * hf[u];
      hf[u] = hnew;
      ((_Float16*)hh2s)[u] = (_Float16)hnew;
      gb[(long)t*256 + u] = hnew;
    }
    __syncthreads();
  }
}

// ---------------- mean over T ----------------
__global__ __launch_bounds__(256) void meanT_kernel(
    const float* __restrict__ x, float* __restrict__ xm)
{
  int b = blockIdx.x, u = threadIdx.x;
  const float* p = x + (long)b*T_*U_ + u;
  float s = 0.f;
  for (int t = 0; t < T_; ++t) s += p[(long)t*U_];
  xm[b*U_ + u] = s * (1.f/(float)T_);
}

// ---------------- MLP head: one block per batch ----------------
__global__ __launch_bounds__(128) void head_kernel(
    const float* __restrict__ xm, const float* __restrict__ other,
    const float* __restrict__ m1W, const float* __restrict__ m1b,
    const float* __restrict__ l1s, const float* __restrict__ l1b,
    const float* __restrict__ m2W, const float* __restrict__ m2b,
    const float* __restrict__ l2s, const float* __restrict__ l2b,
    const float* __restrict__ oW,  const float* __restrict__ ob,
    float* __restrict__ outp)
{
  __shared__ float c[320];
  __shared__ float h1[128];
  __shared__ float sb[2];
  int b = blockIdx.x, tid = threadIdx.x;
  c[tid]       = xm[b*256 + tid];
  c[tid + 128] = xm[b*256 + tid + 128];
  if (tid < 64) c[256 + tid] = other[b*64 + tid];
  __syncthreads();
  float s = m1b[tid];
  for (int i = 0; i < 320; ++i) s += c[i] * m1W[i*128 + tid];
  s = fmaxf(s, 0.f);
  float m = s;
  for (int o = 32; o; o >>= 1) m += __shfl_xor(m, o);
  if ((tid & 63) == 0) sb[tid >> 6] = m;
  __syncthreads();
  m = (sb[0] + sb[1]) * (1.f/128.f);
  __syncthreads();
  float d = s - m, var = d*d;
  for (int o = 32; o; o >>= 1) var += __shfl_xor(var, o);
  if ((tid & 63) == 0) sb[tid >> 6] = var;
  __syncthreads();
  var = (sb[0] + sb[1]) * (1.f/128.f);
  h1[tid] = d * rsqrtf(var + EPSF) * l1s[tid] + l1b[tid];
  __syncthreads();
  if (tid < 64) {
    float s2 = m2b[tid];
    for (int i = 0; i < 128; ++i) s2 += h1[i] * m2W[i*64 + tid];
    s2 = fmaxf(s2, 0.f);
    float m2 = s2;
    for (int o = 32; o; o >>= 1) m2 += __shfl_xor(m2, o);
    m2 *= (1.f/64.f);
    float d2 = s2 - m2, v2 = d2*d2;
    for (int o = 32; o; o >>= 1) v2 += __shfl_xor(v2, o);
    v2 *= (1.f/64.f);
    float h2v = d2 * rsqrtf(v2 + EPSF) * l2s[tid] + l2b[tid];
    float y = h2v * oW[tid];
    for (int o = 32; o; o >>= 1) y += __shfl_xor(y, o);
    if (tid == 0) outp[b] = y + ob[0];
  }
}

// ---------------- host orchestration ----------------
static inline void gemm_nn(hipStream_t st, const float* A, const float* Bm, float* C,
                           const float* bias, int M, int N, int K,
                           int lda, int ldb, int ldc, float alpha)
{
  dim3 g((N + 63)/64, (M + 63)/64, 1);
  gemm_kernel<false><<<g, 256, 0, st>>>(A, Bm, C, bias, M, N, K, lda, ldb, ldc,
                                        0,0,0,0,0,0, 1, alpha);
}

// plain (non-batched) f16 GEMM: lda=ldb=K
static inline void gemm16(hipStream_t st, const _Float16* A, const _Float16* Bt,
                          void* C, const float* bias, int M, int N, int K,
                          int ldc, bool out16)
{
  dim3 g((N + 63)/64, (M + 63)/64, 1);
  if (out16)
    gemm16_kernel<true ><<<g, 256, 0, st>>>(A, Bt, C, bias, M, N, K, K, K, ldc,
                                            0,0,0,0,0,0, 1, 1.f);
  else
    gemm16_kernel<false><<<g, 256, 0, st>>>(A, Bt, C, bias, M, N, K, K, K, ldc,
                                            0,0,0,0,0,0, 1, 1.f);
}

extern "C" void kernel_launch(void* const* d_in, const int* in_sizes, int n_in,
                              void* d_out, int out_size, void* d_ws, size_t ws_size,
                              hipStream_t stream)
{
  const float* cgm   = (const float*)d_in[0];
  const float* other = (const float*)d_in[1];
  const float* d0_W  = (const float*)d_in[2];
  const float* d0_b  = (const float*)d_in[3];
  const float* ln0_s = (const float*)d_in[4];
  const float* ln0_b = (const float*)d_in[5];
  const float* gWi   = (const float*)d_in[6];
  const float* gbi   = (const float*)d_in[7];
  const float* gWh   = (const float*)d_in[8];
  const float* gbhn  = (const float*)d_in[9];
  const float* ln1_s = (const float*)d_in[10];
  const float* ln1_b = (const float*)d_in[11];
  const float* Wq    = (const float*)d_in[12];
  const float* bq    = (const float*)d_in[13];
  const float* Wk    = (const float*)d_in[14];
  const float* bk    = (const float*)d_in[15];
  const float* Wv    = (const float*)d_in[16];
  const float* bv    = (const float*)d_in[17];
  const float* Wo    = (const float*)d_in[18];
  const float* bo    = (const float*)d_in[19];
  const float* ln2_s = (const float*)d_in[20];
  const float* ln2_b = (const float*)d_in[21];
  const float* m1W   = (const float*)d_in[22];
  const float* m1b   = (const float*)d_in[23];
  const float* l1s   = (const float*)d_in[24];
  const float* l1b   = (const float*)d_in[25];
  const float* m2W   = (const float*)d_in[26];
  const float* m2b   = (const float*)d_in[27];
  const float* l2s   = (const float*)d_in[28];
  const float* l2b   = (const float*)d_in[29];
  const float* oW    = (const float*)d_in[30];
  const float* ob    = (const float*)d_in[31];
  float* out = (float*)d_out;

  // workspace layout (floats)
  float* ws   = (float*)d_ws;
  float* big  = ws;                   // 28,311,552 fl: xg f32 | qkv16+vt16 f16
  float* x    = big  + 28311552;      //  9,437,184
  float* go   = x    +  9437184;      //  9,437,184  (g f32; later o16 f16)
  float* Sbuf = go   +  9437184;      // a16 + packed weights + xmean
  (void)in_sizes; (void)n_in; (void)out_size; (void)ws_size;

  // f16 views
  _Float16* a16   = (_Float16*)Sbuf;                       // 9,437,184 halves
  _Float16* qkv16 = (_Float16*)big;                        // 28,311,552 halves
  _Float16* vt16  = (_Float16*)big + 28311552;             //  9,437,184 halves
  _Float16* o16   = (_Float16*)go;                         //  9,437,184 halves
  _Float16* wtWi  = (_Float16*)(Sbuf + 4718592);           //    196,608 halves
  _Float16* wtQKV = (_Float16*)(Sbuf + 4718592 + 98304);   //    196,608 halves
  _Float16* wtWo  = (_Float16*)(Sbuf + 4718592 + 196608);  //     65,536 halves
  float*    bqkv  =             Sbuf + 4718592 + 229376;   //        768 fl
  float*    xmean =             Sbuf + 4718592 + 230144;   //     32,768 fl

  // x = LN(cgm @ d0_W + d0_b)  (+ f16 copy)
  gemm_nn(stream, cgm, d0_W, big, d0_b, MT, 256, 16, 16, 256, 256, 1.f);
  ln256_kernel<<<MT/4, 256, 0, stream>>>(big, nullptr, nullptr, ln0_s, ln0_b, x, a16);

  for (int i = 0; i < 2; ++i) {
    const float* Wh_i = gWh + (long)i*196608;

    // xg = x @ Wi + bi  (f16 MFMA, f32 out for GRU)
    tpack_kernel<<<dim3(24, 8), 256, 0, stream>>>(gWi + (long)i*196608, wtWi, 256, 768);
    gemm16(stream, a16, wtWi, big, gbi + i*768, MT, 768, 256, 768, false);
    // GRU scan
    gru_scan_kernel<<<128, 1024, 0, stream>>>(big, Wh_i, gbhn + i*256, go);
    // x = LN(g) + x  (+ f16 copy)
    ln256_kernel<<<MT/4, 256, 0, stream>>>(go, nullptr, x, ln1_s + i*256, ln1_b + i*256, x, a16);

    // qkv in ONE f16 MFMA gemm, f16 output (only attention consumes it)
    tpack_kernel<<<dim3(8, 8), 256, 0, stream>>>(Wq + (long)i*65536, wtQKV,            256, 256);
    tpack_kernel<<<dim3(8, 8), 256, 0, stream>>>(Wk + (long)i*65536, wtQKV + 256*256,  256, 256);
    tpack_kernel<<<dim3(8, 8), 256, 0, stream>>>(Wv + (long)i*65536, wtQKV + 512*256,  256, 256);
    packb_kernel<<<1, 256, 0, stream>>>(bq + i*256, bk + i*256, bv + i*256, bqkv);
    gemm16(stream, a16, wtQKV, qkv16, bqkv, MT, 768, 256, 768, true);

    // V transpose, then FUSED attention (no score round-trip)
    vtpack_kernel<<<dim3(5, 512), 256, 0, stream>>>(qkv16, vt16);
    fused_attn_kernel<<<dim3(5, 512), 256, 0, stream>>>(qkv16, vt16, o16);

    // a = o16 @ Wo + bo (f32 out into big)
    tpack_kernel<<<dim3(8, 8), 256, 0, stream>>>(Wo + (long)i*65536, wtWo, 256, 256);
    gemm16(stream, o16, wtWo, big, bo + i*256, MT, 256, 256, 256, false);
    // x = LN(a + x)  (+ f16 copy)
    ln256_kernel<<<MT/4, 256, 0, stream>>>(big, x, nullptr, ln2_s + i*256, ln2_b + i*256, x, a16);
  }

  meanT_kernel<<<128, 256, 0, stream>>>(x, xmean);
  head_kernel<<<128, 128, 0, stream>>>(xmean, other, m1W, m1b, l1s, l1b,
                                       m2W, m2b, l2s, l2b, oW, ob, out);
}

// Round 12
// 1391.290 us; speedup vs baseline: 3.1643x; 1.0492x over previous
//
#include <hip/hip_runtime.h>
#include <math.h>

// ---------------- constants ----------------
#define B_   128
#define T_   288
#define U_   256
#define H_   4
#define HD_  64
#define MT   (B_*T_)     // 36864 rows
#define EPSF 1e-6f

typedef _Float16 h2_t  __attribute__((ext_vector_type(2)));
typedef _Float16 f16x4 __attribute__((ext_vector_type(4)));
typedef _Float16 f16x8 __attribute__((ext_vector_type(8)));
typedef float    f32x4 __attribute__((ext_vector_type(4)));

#if defined(__has_builtin)
#  if __has_builtin(__builtin_amdgcn_fdot2)
#    define HAS_FDOT2 1
#  endif
#endif
#ifndef HAS_FDOT2
#  define HAS_FDOT2 0
#endif

// ---------------- generic tiled fp32 GEMM (d0 only) ----------
template<bool TB>
__global__ __launch_bounds__(256) void gemm_kernel(
    const float* __restrict__ A, const float* __restrict__ Bm,
    float* __restrict__ C, const float* __restrict__ bias,
    int M, int N, int K, int lda, int ldb, int ldc,
    long sA1, long sA2, long sB1, long sB2, long sC1, long sC2,
    int zdiv, float alpha)
{
  int z  = blockIdx.z;
  int z1 = z / zdiv, z2 = z - z1 * zdiv;
  A  += (long)z1*sA1 + (long)z2*sA2;
  Bm += (long)z1*sB1 + (long)z2*sB2;
  C  += (long)z1*sC1 + (long)z2*sC2;

  __shared__ float As[16][68];
  __shared__ float Bs[16][68];

  const int tid = threadIdx.x;
  const int tx  = tid & 15;
  const int ty  = tid >> 4;
  const int rowBase = blockIdx.y * 64;
  const int colBase = blockIdx.x * 64;

  float acc[4][4] = {};

  const int lr = tid >> 2;
  const int lk = (tid & 3) << 2;

  for (int k0 = 0; k0 < K; k0 += 16) {
    {
      float4 a4 = {0.f,0.f,0.f,0.f};
      int ar = rowBase + lr;
      if (ar < M) a4 = *(const float4*)(A + (long)ar*lda + k0 + lk);
      As[lk+0][lr]=a4.x; As[lk+1][lr]=a4.y; As[lk+2][lr]=a4.z; As[lk+3][lr]=a4.w;
    }
    if (TB) {
      float4 b4 = {0.f,0.f,0.f,0.f};
      int bn = colBase + lr;
      if (bn < N) b4 = *(const float4*)(Bm + (long)bn*ldb + k0 + lk);
      Bs[lk+0][lr]=b4.x; Bs[lk+1][lr]=b4.y; Bs[lk+2][lr]=b4.z; Bs[lk+3][lr]=b4.w;
    } else {
      int bk  = tid >> 4;
      int bn4 = (tid & 15) << 2;
      float4 b4 = {0.f,0.f,0.f,0.f};
      if (colBase + bn4 < N) b4 = *(const float4*)(Bm + (long)(k0+bk)*ldb + colBase + bn4);
      *(float4*)(&Bs[bk][bn4]) = b4;
    }
    __syncthreads();
    #pragma unroll
    for (int k = 0; k < 16; ++k) {
      float4 av = *(const float4*)(&As[k][ty<<2]);
      float4 bv = *(const float4*)(&Bs[k][tx<<2]);
      acc[0][0]+=av.x*bv.x; acc[0][1]+=av.x*bv.y; acc[0][2]+=av.x*bv.z; acc[0][3]+=av.x*bv.w;
      acc[1][0]+=av.y*bv.x; acc[1][1]+=av.y*bv.y; acc[1][2]+=av.y*bv.z; acc[1][3]+=av.y*bv.w;
      acc[2][0]+=av.z*bv.x; acc[2][1]+=av.z*bv.y; acc[2][2]+=av.z*bv.z; acc[2][3]+=av.z*bv.w;
      acc[3][0]+=av.w*bv.x; acc[3][1]+=av.w*bv.y; acc[3][2]+=av.w*bv.z; acc[3][3]+=av.w*bv.w;
    }
    __syncthreads();
  }

  const int cn = colBase + (tx << 2);
  if (cn < N) {
    float4 bb = {0.f,0.f,0.f,0.f};
    if (bias) bb = *(const float4*)(bias + cn);
    #pragma unroll
    for (int i = 0; i < 4; ++i) {
      int r = rowBase + (ty << 2) + i;
      if (r < M) {
        float4 v;
        v.x = acc[i][0]*alpha + bb.x;
        v.y = acc[i][1]*alpha + bb.y;
        v.z = acc[i][2]*alpha + bb.z;
        v.w = acc[i][3]*alpha + bb.w;
        *(float4*)(C + (long)r*ldc + cn) = v;
      }
    }
  }
}

// ---------------- f16 MFMA GEMM, 128x128 tile -----------------------------
// C[M,N] = A16[M,K] @ Bt16[N,K]^T + bias[N].  REQUIRES M%128==0, N%128==0,
// K%32==0 (all callers: M=36864, N in {768,256}, K=256) -> no guards.
// 256 thr = 4 waves (2x2); wave (mw,nw) owns a 64x64 quadrant = 4x4 16-tiles
// (16 MFMA/BK32-iter, 0.5 LDS-reads/MFMA vs 1 for the 64^2 tile; 4x FLOP per
// barrier pair). acc = 64 VGPR; launch_bounds(256,2) -> 256-reg budget.
// Fragment convention (verified rounds 3-11): a/b-frag lane(l16,lq)[e] =
// X[r0+l16][k0+lq*8+e]; C/D row=lq*4+i, col=l16. K-chunk order identical to
// the 64^2 kernel -> bitwise-identical accumulation.
template<bool OUT16>
__global__ __launch_bounds__(256, 2) void gemm128_kernel(
    const _Float16* __restrict__ A, const _Float16* __restrict__ Bt,
    void* __restrict__ Cv, const float* __restrict__ bias,
    int M, int N, int K, int ldc)
{
  __shared__ __align__(16) _Float16 Asf[128][40];
  __shared__ __align__(16) _Float16 Bsf[128][40];
  const int tid  = threadIdx.x;
  const int wv   = tid >> 6;
  const int mw   = wv >> 1, nw = wv & 1;
  const int lane = tid & 63, l16 = lane & 15, lq = lane >> 4;
  const int m0 = blockIdx.y * 128, n0 = blockIdx.x * 128;
  const int srow = tid >> 2, sk = (tid & 3) * 8;

  f32x4 acc[4][4] = {};

  const long arow0 = (long)(m0 + srow)*K + sk;
  const long arow1 = (long)(m0 + srow + 64)*K + sk;
  const long brow0 = (long)(n0 + srow)*K + sk;
  const long brow1 = (long)(n0 + srow + 64)*K + sk;

  for (int k0 = 0; k0 < K; k0 += 32) {
    *(f16x8*)&Asf[srow     ][sk] = *(const f16x8*)&A[arow0 + k0];
    *(f16x8*)&Asf[srow + 64][sk] = *(const f16x8*)&A[arow1 + k0];
    *(f16x8*)&Bsf[srow     ][sk] = *(const f16x8*)&Bt[brow0 + k0];
    *(f16x8*)&Bsf[srow + 64][sk] = *(const f16x8*)&Bt[brow1 + k0];
    __syncthreads();
    f16x8 af[4], bf[4];
    #pragma unroll
    for (int mt = 0; mt < 4; ++mt)
      af[mt] = *(const f16x8*)&Asf[mw*64 + mt*16 + l16][lq*8];
    #pragma unroll
    for (int nt = 0; nt < 4; ++nt)
      bf[nt] = *(const f16x8*)&Bsf[nw*64 + nt*16 + l16][lq*8];
    #pragma unroll
    for (int mt = 0; mt < 4; ++mt)
      #pragma unroll
      for (int nt = 0; nt < 4; ++nt)
        acc[mt][nt] = __builtin_amdgcn_mfma_f32_16x16x32_f16(af[mt], bf[nt], acc[mt][nt], 0, 0, 0);
    __syncthreads();
  }

  float*    Cf = (float*)Cv;
  _Float16* Ch = (_Float16*)Cv;
  #pragma unroll
  for (int nt = 0; nt < 4; ++nt) {
    const int col = n0 + nw*64 + nt*16 + l16;
    const float bb = bias ? bias[col] : 0.f;
    #pragma unroll
    for (int mt = 0; mt < 4; ++mt) {
      const int rb = m0 + mw*64 + mt*16 + lq*4;
      #pragma unroll
      for (int i = 0; i < 4; ++i) {
        const float val = acc[mt][nt][i] + bb;
        if (OUT16) Ch[(long)(rb+i)*ldc + col] = (_Float16)val;
        else       Cf[(long)(rb+i)*ldc + col] = val;
      }
    }
  }
}

// ---------------- fused attention: one (Q-tile, b*h) per block -----------
// (unchanged from round 11 — verified)
__global__ __launch_bounds__(256) void fused_attn_kernel(
    const _Float16* __restrict__ qkv16,  // [B*T][768]  q|k|v
    const _Float16* __restrict__ vt16,   // [B*H][64][288]
    _Float16* __restrict__ o16)          // [B*T][256]
{
  __shared__ __align__(16) _Float16 Pl[4][16][296];
  const int tid  = threadIdx.x;
  const int w    = tid >> 6;
  const int lane = tid & 63, l16 = lane & 15, lq = lane >> 4;
  const int z = blockIdx.y;            // b*4 + h
  const int b = z >> 2, h = z & 3;
  const int q0 = blockIdx.x * 64 + w * 16;
  const long rowbase = (long)b * T_;

  // ---- QK^T ----
  const _Float16* qp = qkv16 + (rowbase + q0 + l16) * 768 + h*64 + lq*8;
  f16x8 qf0 = *(const f16x8*)qp;
  f16x8 qf1 = *(const f16x8*)(qp + 32);
  f32x4 acc[18];
  const _Float16* kp = qkv16 + (rowbase + l16) * 768 + 256 + h*64 + lq*8;
  #pragma unroll
  for (int t = 0; t < 18; ++t) {
    f16x8 kf0 = *(const f16x8*)(kp + (long)t*16*768);
    f16x8 kf1 = *(const f16x8*)(kp + (long)t*16*768 + 32);
    f32x4 a = {0.f, 0.f, 0.f, 0.f};
    a = __builtin_amdgcn_mfma_f32_16x16x32_f16(qf0, kf0, a, 0, 0, 0);
    a = __builtin_amdgcn_mfma_f32_16x16x32_f16(qf1, kf1, a, 0, 0, 0);
    acc[t] = a;
  }

  // ---- row softmax + P (f16) into LDS in A-frag-readable layout ----
  #pragma unroll
  for (int r = 0; r < 4; ++r) {
    float m = -1e30f;
    #pragma unroll
    for (int t = 0; t < 18; ++t) m = fmaxf(m, acc[t][r]);
    m = fmaxf(m, __shfl_xor(m, 1)); m = fmaxf(m, __shfl_xor(m, 2));
    m = fmaxf(m, __shfl_xor(m, 4)); m = fmaxf(m, __shfl_xor(m, 8));
    float p[18];
    float s = 0.f;
    #pragma unroll
    for (int t = 0; t < 18; ++t) {
      p[t] = __expf(0.125f * (acc[t][r] - m));
      s += p[t];
    }
    s += __shfl_xor(s, 1); s += __shfl_xor(s, 2);
    s += __shfl_xor(s, 4); s += __shfl_xor(s, 8);
    const float inv = 1.f / s;
    #pragma unroll
    for (int t = 0; t < 18; ++t)
      Pl[w][lq*4 + r][t*16 + l16] = (_Float16)(p[t] * inv);
  }
  __syncthreads();

  // ---- PV ----
  f32x4 accO[4] = {{0,0,0,0},{0,0,0,0},{0,0,0,0},{0,0,0,0}};
  const _Float16* vb = vt16 + ((long)z*64 + l16)*288 + lq*8;
  #pragma unroll
  for (int ks = 0; ks < 9; ++ks) {
    f16x8 pa = *(const f16x8*)&Pl[w][l16][ks*32 + lq*8];
    #pragma unroll
    for (int n = 0; n < 4; ++n) {
      f16x8 vf = *(const f16x8*)(vb + (long)n*16*288 + ks*32);
      accO[n] = __builtin_amdgcn_mfma_f32_16x16x32_f16(pa, vf, accO[n], 0, 0, 0);
    }
  }

  // ---- write O (row-guarded) ----
  #pragma unroll
  for (int n = 0; n < 4; ++n) {
    const int col = h*64 + n*16 + l16;
    #pragma unroll
    for (int r = 0; r < 4; ++r) {
      const int row = q0 + lq*4 + r;
      if (row < T_)
        o16[(rowbase + row)*256 + col] = (_Float16)accO[n][r];
    }
  }
}

// ---------------- one-shot weight pack (both layers) ----------------------
// blockIdx.z = job: z<10: transpose job (layer i=z/5, matrix m=z%5):
//   m=0: gWi[i]  [256,768] -> wtWi  + i*196608  ([768][256] f16)
//   m=1..3: Wq/Wk/Wv[i] [256,256] -> wtQKV + i*196608 + (m-1)*65536
//   m=4: Wo[i]   [256,256] -> wtWo  + i*65536
// z=10/11: bias pack layer z-10 -> bqkv[(z-10)*768].
// Grid (24,8,12); oversize blocks early-exit (block-uniform, pre-barrier).
__global__ __launch_bounds__(256) void packall_kernel(
    const float* __restrict__ gWi, const float* __restrict__ Wq,
    const float* __restrict__ Wk,  const float* __restrict__ Wv,
    const float* __restrict__ Wo,  const float* __restrict__ bq,
    const float* __restrict__ bk,  const float* __restrict__ bv,
    _Float16* __restrict__ wtWi, _Float16* __restrict__ wtQKV,
    _Float16* __restrict__ wtWo, float* __restrict__ bqkv)
{
  const int z = blockIdx.z;
  if (z >= 10) {                      // bias jobs
    if (blockIdx.x || blockIdx.y) return;
    const int li = z - 10, t = threadIdx.x;
    bqkv[li*768 + t]       = bq[li*256 + t];
    bqkv[li*768 + 256 + t] = bk[li*256 + t];
    bqkv[li*768 + 512 + t] = bv[li*256 + t];
    return;
  }
  const int i = z / 5, m = z - i*5;
  const float* src; _Float16* dst; int N;
  if (m == 0)      { src = gWi + (long)i*196608; dst = wtWi  + (long)i*196608; N = 768; }
  else if (m == 4) { src = Wo  + (long)i*65536;  dst = wtWo  + (long)i*65536;  N = 256; }
  else {
    const float* s3 = (m == 1) ? Wq : (m == 2) ? Wk : Wv;
    src = s3 + (long)i*65536; dst = wtQKV + (long)i*196608 + (long)(m-1)*65536; N = 256;
  }
  const int n0 = blockIdx.x * 32, k0 = blockIdx.y * 32;   // K = 256 always
  if (n0 >= N) return;                                    // block-uniform

  __shared__ float t[32][33];
  const int tx = threadIdx.x & 31, ty = threadIdx.x >> 5;  // 32 x 8
  #pragma unroll
  for (int j = 0; j < 4; ++j)
    t[ty + 8*j][tx] = src[(long)(k0 + ty + 8*j)*N + n0 + tx];
  __syncthreads();
  #pragma unroll
  for (int j = 0; j < 4; ++j)
    dst[(long)(n0 + ty + 8*j)*256 + k0 + tx] = (_Float16)t[tx][ty + 8*j];
}

// ---------------- V transpose: qkv16 [MT][768] -> vt16 [bh][64][288] ------
__global__ __launch_bounds__(256) void vtpack_kernel(
    const _Float16* __restrict__ qkv16, _Float16* __restrict__ vt16)
{
  __shared__ _Float16 tile[64][80];
  const int z  = blockIdx.y;          // b*4 + h
  const int t0 = blockIdx.x * 64;
  const int tr = threadIdx.x >> 2, c4 = (threadIdx.x & 3) * 16;
  const int t  = t0 + tr;
  f16x8 z8 = {};
  const _Float16* src = qkv16 + ((long)((z >> 2)*T_ + t))*768 + 512 + (z & 3)*64 + c4;
  f16x8 v0 = (t < T_) ? *(const f16x8*)src       : z8;
  f16x8 v1 = (t < T_) ? *(const f16x8*)(src + 8) : z8;
  *(f16x8*)&tile[tr][c4]     = v0;
  *(f16x8*)&tile[tr][c4 + 8] = v1;
  __syncthreads();
  _Float16* dst = vt16 + ((long)z*64 + tr)*288 + t0 + c4;
  #pragma unroll
  for (int i = 0; i < 16; ++i)
    if (t0 + c4 + i < T_) dst[i] = tile[c4 + i][tr];
}

// ---------------- LayerNorm over 256 cols: one wave per row ----------------
__global__ __launch_bounds__(256) void ln256_kernel(
    const float* __restrict__ in, const float* __restrict__ skip_pre,
    const float* __restrict__ skip_post,
    const float* __restrict__ s, const float* __restrict__ b,
    float* __restrict__ out, _Float16* __restrict__ out16)
{
  const int wid  = threadIdx.x >> 6;
  const int lane = threadIdx.x & 63;
  const long row  = (long)blockIdx.x * 4 + wid;
  const long base = row * 256 + lane * 4;

  float4 v = *(const float4*)(in + base);
  if (skip_pre) {
    float4 sp = *(const float4*)(skip_pre + base);
    v.x += sp.x; v.y += sp.y; v.z += sp.z; v.w += sp.w;
  }
  float m = v.x + v.y + v.z + v.w;
  for (int o = 32; o; o >>= 1) m += __shfl_xor(m, o);
  m *= (1.f/256.f);
  float4 d = { v.x - m, v.y - m, v.z - m, v.w - m };
  float var = d.x*d.x + d.y*d.y + d.z*d.z + d.w*d.w;
  for (int o = 32; o; o >>= 1) var += __shfl_xor(var, o);
  var *= (1.f/256.f);
  const float inv = rsqrtf(var + EPSF);
  float4 sv = *(const float4*)(s + lane*4);
  float4 bv = *(const float4*)(b + lane*4);
  float4 y;
  y.x = d.x*inv*sv.x + bv.x;
  y.y = d.y*inv*sv.y + bv.y;
  y.z = d.z*inv*sv.z + bv.z;
  y.w = d.w*inv*sv.w + bv.w;
  if (skip_post) {
    float4 sp = *(const float4*)(skip_post + base);
    y.x += sp.x; y.y += sp.y; y.z += sp.z; y.w += sp.w;
  }
  *(float4*)(out + base) = y;
  if (out16) {
    f16x4 o16 = {(_Float16)y.x, (_Float16)y.y, (_Float16)y.z, (_Float16)y.w};
    *(f16x4*)(out16 + base) = o16;
  }
}

// ---------------- GRU scan: one workgroup per batch ----------------
// EXACT round-8 kernel (397 us measured; do not touch — 5 failed attempts).
__global__ __launch_bounds__(1024, 1) void gru_scan_kernel(
    const float* __restrict__ xg,   // [B,T,768]
    const float* __restrict__ Wh,   // [256,768]
    const float* __restrict__ bhn,  // [256]
    float* __restrict__ g)          // [B,T,256]
{
  const int b   = blockIdx.x;
  const int tid = threadIdx.x;
  const int u   = tid & 255;   // unit
  const int kq  = tid >> 8;    // k-quarter (64 h values)

  __shared__ float hf[256];
  __shared__ __align__(16) h2_t hh2s[128];
  __shared__ float part[4][3][256];

  h2_t wr[32], wz[32], wn[32];
  #pragma unroll
  for (int r = 0; r < 32; ++r) {
    const float* p0 = Wh + (long)(kq*64 + 2*r)*768 + u;
    const float* p1 = p0 + 768;
    h2_t a; a.x = (_Float16)p0[0];   a.y = (_Float16)p1[0];   wr[r] = a;
    h2_t c; c.x = (_Float16)p0[256]; c.y = (_Float16)p1[256]; wz[r] = c;
    h2_t d; d.x = (_Float16)p0[512]; d.y = (_Float16)p1[512]; wn[r] = d;
  }
  float bn = (kq == 0) ? bhn[u] : 0.f;
  if (tid < 256) hf[tid] = 0.f;
  if (tid < 128) { h2_t zz; zz.x = (_Float16)0.f; zz.y = (_Float16)0.f; hh2s[tid] = zz; }
  __syncthreads();

  const float* xgb = xg + (long)b*T_*768;
  float* gb = g + (long)b*T_*256;

  for (int t = 0; t < T_; ++t) {
    float xr = 0.f, xz = 0.f, xn = 0.f;
    if (kq == 0) {  // prefetch input gates; latency hidden behind dot phase
      const float* xt = xgb + (long)t*768;
      xr = xt[u]; xz = xt[u+256]; xn = xt[u+512];
    }
    const float4* hq4 = (const float4*)(&hh2s[kq*32]);
    float ar = 0.f, az = 0.f, an = 0.f;
    #pragma unroll
    for (int c = 0; c < 8; ++c) {
      const float4 hc = hq4[c];   // ds_read_b128: 4 h2 pairs
      union { float f; h2_t h; } u0, u1, u2, u3;
      u0.f = hc.x; u1.f = hc.y; u2.f = hc.z; u3.f = hc.w;
#if HAS_FDOT2
      ar = __builtin_amdgcn_fdot2(u0.h, wr[c*4+0], ar, false);
      az = __builtin_amdgcn_fdot2(u0.h, wz[c*4+0], az, false);
      an = __builtin_amdgcn_fdot2(u0.h, wn[c*4+0], an, false);
      ar = __builtin_amdgcn_fdot2(u1.h, wr[c*4+1], ar, false);
      az = __builtin_amdgcn_fdot2(u1.h, wz[c*4+1], az, false);
      an = __builtin_amdgcn_fdot2(u1.h, wn[c*4+1], an, false);
      ar = __builtin_amdgcn_fdot2(u2.h, wr[c*4+2], ar, false);
      az = __builtin_amdgcn_fdot2(u2.h, wz[c*4+2], az, false);
      an = __builtin_amdgcn_fdot2(u2.h, wn[c*4+2], an, false);
      ar = __builtin_amdgcn_fdot2(u3.h, wr[c*4+3], ar, false);
      az = __builtin_amdgcn_fdot2(u3.h, wz[c*4+3], az, false);
      an = __builtin_amdgcn_fdot2(u3.h, wn[c*4+3], an, false);
#else
      ar += (float)u0.h.x*(float)wr[c*4+0].x + (float)u0.h.y*(float)wr[c*4+0].y;
      az += (float)u0.h.x*(float)wz[c*4+0].x + (float)u0.h.y*(float)wz[c*4+0].y;
      an += (float)u0.h.x*(float)wn[c*4+0].x + (float)u0.h.y*(float)wn[c*4+0].y;
      ar += (float)u1.h.x*(float)wr[c*4+1].x + (float)u1.h.y*(float)wr[c*4+1].y;
      az += (float)u1.h.x*(float)wz[c*4+1].x + (float)u1.h.y*(float)wz[c*4+1].y;
      an += (float)u1.h.x*(float)wn[c*4+1].x + (float)u1.h.y*(float)wn[c*4+1].y;
      ar += (float)u2.h.x*(float)wr[c*4+2].x + (float)u2.h.y*(float)wr[c*4+2].y;
      az += (float)u2.h.x*(float)wz[c*4+2].x + (float)u2.h.y*(float)wz[c*4+2].y;
      an += (float)u2.h.x*(float)wn[c*4+2].x + (float)u2.h.y*(float)wn[c*4+2].y;
      ar += (float)u3.h.x*(float)wr[c*4+3].x + (float)u3.h.y*(float)wr[c*4+3].y;
      az += (float)u3.h.x*(float)wz[c*4+3].x + (float)u3.h.y*(float)wz[c*4+3].y;
      an += (float)u3.h.x*(float)wn[c*4+3].x + (float)u3.h.y*(float)wn[c*4+3].y;
#endif
    }
    part[kq][0][u] = ar; part[kq][1][u] = az; part[kq][2][u] = an;
    __syncthreads();
    if (kq == 0) {
      float hr = part[0][0][u]+part[1][0][u]+part[2][0][u]+part[3][0][u] + xr;
      float hz = part[0][1][u]+part[1][1][u]+part[2][1][u]+part[3][1][u] + xz;
      float hn = part[0][2][u]+part[1][2][u]+part[2][2][u]+part[3][2][u];
      float rr = 1.f / (1.f + __expf(-hr));
      float z  = 1.f / (1.f + __expf(-hz));
      float nx = xn + rr * (hn + bn);
      float e2 = __expf(2.f * nx);
      float nv = (e2 - 1.f) / (e2 + 1.f);
      float hnew = (1.f - z) * nv + z * hf[u];
      hf[u] = hnew;
      ((_Float16*)hh2s)[u] = (_Float16)hnew;
      gb[(long)t*256 + u] = hnew;
    }
    __syncthreads();
  }
}

// ---------------- MLP head (mean-over-T fused): one block per batch -------
__global__ __launch_bounds__(128) void head_kernel(
    const float* __restrict__ x, const float* __restrict__ other,
    const float* __restrict__ m1W, const float* __restrict__ m1b,
    const float* __restrict__ l1s, const float* __restrict__ l1b,
    const float* __restrict__ m2W, const float* __restrict__ m2b,
    const float* __restrict__ l2s, const float* __restrict__ l2b,
    const float* __restrict__ oW,  const float* __restrict__ ob,
    float* __restrict__ outp)
{
  __shared__ float c[320];
  __shared__ float h1[128];
  __shared__ float sb[2];
  int b = blockIdx.x, tid = threadIdx.x;
  // mean over T (same t-ascending order as the old meanT kernel)
  {
    const float* xb = x + (long)b*T_*256;
    float s0 = 0.f, s1 = 0.f;
    for (int t = 0; t < T_; ++t) {
      s0 += xb[(long)t*256 + tid];
      s1 += xb[(long)t*256 + tid + 128];
    }
    c[tid]       = s0 * (1.f/(float)T_);
    c[tid + 128] = s1 * (1.f/(float)T_);
  }
  if (tid < 64) c[256 + tid] = other[b*64 + tid];
  __syncthreads();
  float s = m1b[tid];
  for (int i = 0; i < 320; ++i) s += c[i] * m1W[i*128 + tid];
  s = fmaxf(s, 0.f);
  float m = s;
  for (int o = 32; o; o >>= 1) m += __shfl_xor(m, o);
  if ((tid & 63) == 0) sb[tid >> 6] = m;
  __syncthreads();
  m = (sb[0] + sb[1]) * (1.f/128.f);
  __syncthreads();
  float d = s - m, var = d*d;
  for (int o = 32; o; o >>= 1) var += __shfl_xor(var, o);
  if ((tid & 63) == 0) sb[tid >> 6] = var;
  __syncthreads();
  var = (sb[0] + sb[1]) * (1.f/128.f);
  h1[tid] = d * rsqrtf(var + EPSF) * l1s[tid] + l1b[tid];
  __syncthreads();
  if (tid < 64) {
    float s2 = m2b[tid];
    for (int i = 0; i < 128; ++i) s2 += h1[i] * m2W[i*64 + tid];
    s2 = fmaxf(s2, 0.f);
    float m2 = s2;
    for (int o = 32; o; o >>= 1) m2 += __shfl_xor(m2, o);
    m2 *= (1.f/64.f);
    float d2 = s2 - m2, v2 = d2*d2;
    for (int o = 32; o; o >>= 1) v2 += __shfl_xor(v2, o);
    v2 *= (1.f/64.f);
    float h2v = d2 * rsqrtf(v2 + EPSF) * l2s[tid] + l2b[tid];
    float y = h2v * oW[tid];
    for (int o = 32; o; o >>= 1) y += __shfl_xor(y, o);
    if (tid == 0) outp[b] = y + ob[0];
  }
}

// ---------------- host orchestration ----------------
static inline void gemm_nn(hipStream_t st, const float* A, const float* Bm, float* C,
                           const float* bias, int M, int N, int K,
                           int lda, int ldb, int ldc, float alpha)
{
  dim3 g((N + 63)/64, (M + 63)/64, 1);
  gemm_kernel<false><<<g, 256, 0, st>>>(A, Bm, C, bias, M, N, K, lda, ldb, ldc,
                                        0,0,0,0,0,0, 1, alpha);
}

extern "C" void kernel_launch(void* const* d_in, const int* in_sizes, int n_in,
                              void* d_out, int out_size, void* d_ws, size_t ws_size,
                              hipStream_t stream)
{
  const float* cgm   = (const float*)d_in[0];
  const float* other = (const float*)d_in[1];
  const float* d0_W  = (const float*)d_in[2];
  const float* d0_b  = (const float*)d_in[3];
  const float* ln0_s = (const float*)d_in[4];
  const float* ln0_b = (const float*)d_in[5];
  const float* gWi   = (const float*)d_in[6];
  const float* gbi   = (const float*)d_in[7];
  const float* gWh   = (const float*)d_in[8];
  const float* gbhn  = (const float*)d_in[9];
  const float* ln1_s = (const float*)d_in[10];
  const float* ln1_b = (const float*)d_in[11];
  const float* Wq    = (const float*)d_in[12];
  const float* bq    = (const float*)d_in[13];
  const float* Wk    = (const float*)d_in[14];
  const float* bk    = (const float*)d_in[15];
  const float* Wv    = (const float*)d_in[16];
  const float* bv    = (const float*)d_in[17];
  const float* Wo    = (const float*)d_in[18];
  const float* bo    = (const float*)d_in[19];
  const float* ln2_s = (const float*)d_in[20];
  const float* ln2_b = (const float*)d_in[21];
  const float* m1W   = (const float*)d_in[22];
  const float* m1b   = (const float*)d_in[23];
  const float* l1s   = (const float*)d_in[24];
  const float* l1b   = (const float*)d_in[25];
  const float* m2W   = (const float*)d_in[26];
  const float* m2b   = (const float*)d_in[27];
  const float* l2s   = (const float*)d_in[28];
  const float* l2b   = (const float*)d_in[29];
  const float* oW    = (const float*)d_in[30];
  const float* ob    = (const float*)d_in[31];
  float* out = (float*)d_out;

  // workspace layout (floats)
  float* ws   = (float*)d_ws;
  float* big  = ws;                   // 28,311,552 fl: xg f32 | qkv16+vt16 f16
  float* x    = big  + 28311552;      //  9,437,184
  float* go   = x    +  9437184;      //  9,437,184  (g f32; later o16 f16)
  float* Sbuf = go   +  9437184;      // a16 + packed weights
  (void)in_sizes; (void)n_in; (void)out_size; (void)ws_size;

  // f16 views (offsets in halves from Sbuf)
  _Float16* h0    = (_Float16*)Sbuf;
  _Float16* a16   = h0;                          // [0, 9437184)
  _Float16* wtWi  = h0 + 9437184;                // 2 x 196608
  _Float16* wtQKV = h0 + 9830400;                // 2 x 196608
  _Float16* wtWo  = h0 + 10223616;               // 2 x  65536
  float*    bqkv  = Sbuf + 5177344;              // 2 x    768 floats
  _Float16* qkv16 = (_Float16*)big;              // 28,311,552 halves
  _Float16* vt16  = (_Float16*)big + 28311552;   //  9,437,184 halves
  _Float16* o16   = (_Float16*)go;               //  9,437,184 halves

  // one-shot weight packing for BOTH layers (replaces 8 tpack + 2 packb)
  packall_kernel<<<dim3(24, 8, 12), 256, 0, stream>>>(
      gWi, Wq, Wk, Wv, Wo, bq, bk, bv, wtWi, wtQKV, wtWo, bqkv);

  // x = LN(cgm @ d0_W + d0_b)  (+ f16 copy)
  gemm_nn(stream, cgm, d0_W, big, d0_b, MT, 256, 16, 16, 256, 256, 1.f);
  ln256_kernel<<<MT/4, 256, 0, stream>>>(big, nullptr, nullptr, ln0_s, ln0_b, x, a16);

  for (int i = 0; i < 2; ++i) {
    const float* Wh_i = gWh + (long)i*196608;

    // xg = x @ Wi + bi  (128^2-tile f16 MFMA, f32 out for GRU)
    gemm128_kernel<false><<<dim3(6, 288), 256, 0, stream>>>(
        a16, wtWi + (long)i*196608, big, gbi + i*768, MT, 768, 256, 768);
    // GRU scan
    gru_scan_kernel<<<128, 1024, 0, stream>>>(big, Wh_i, gbhn + i*256, go);
    // x = LN(g) + x  (+ f16 copy)
    ln256_kernel<<<MT/4, 256, 0, stream>>>(go, nullptr, x, ln1_s + i*256, ln1_b + i*256, x, a16);

    // qkv in one 128^2-tile f16 MFMA gemm, f16 output
    gemm128_kernel<true><<<dim3(6, 288), 256, 0, stream>>>(
        a16, wtQKV + (long)i*196608, qkv16, bqkv + i*768, MT, 768, 256, 768);

    // V transpose, then fused attention (no score round-trip)
    vtpack_kernel<<<dim3(5, 512), 256, 0, stream>>>(qkv16, vt16);
    fused_attn_kernel<<<dim3(5, 512), 256, 0, stream>>>(qkv16, vt16, o16);

    // a = o16 @ Wo + bo (f32 out into big)
    gemm128_kernel<false><<<dim3(2, 288), 256, 0, stream>>>(
        o16, wtWo + (long)i*65536, big, bo + i*256, MT, 256, 256, 256);
    // x = LN(a + x)  (+ f16 copy)
    ln256_kernel<<<MT/4, 256, 0, stream>>>(big, x, nullptr, ln2_s + i*256, ln2_b + i*256, x, a16);
  }

  head_kernel<<<128, 128, 0, stream>>>(x, other, m1W, m1b, l1s, l1b,
                                       m2W, m2b, l2s, l2b, oW, ob, out);
}

// Round 14
// 1333.912 us; speedup vs baseline: 3.3004x; 1.0430x over previous
//
#include <hip/hip_runtime.h>
#include <math.h>

// ---------------- constants ----------------
#define B_   128
#define T_   288
#define U_   256
#define H_   4
#define HD_  64
#define MT   (B_*T_)     // 36864 rows
#define EPSF 1e-6f

typedef _Float16 h2_t  __attribute__((ext_vector_type(2)));
typedef _Float16 f16x4 __attribute__((ext_vector_type(4)));
typedef _Float16 f16x8 __attribute__((ext_vector_type(8)));
typedef float    f32x4 __attribute__((ext_vector_type(4)));

#if defined(__has_builtin)
#  if __has_builtin(__builtin_amdgcn_fdot2)
#    define HAS_FDOT2 1
#  endif
#endif
#ifndef HAS_FDOT2
#  define HAS_FDOT2 0
#endif

// ---------------- f16 MFMA GEMM, 128x128 tile -----------------------------
// ROUND-12 VERIFIED BODY (register-staged LDS, padded [128][40]).
// Round-13's global_load_lds variant is the prime suspect for the container
// crash and is banned this session.
// C[M,N] = A16[M,K] @ Bt16[N,K]^T + bias[N].  REQUIRES M%128==0, N%128==0,
// K%32==0 (callers: M=36864, N in {768,256}, K=256) -> no guards.
// Fragment convention (verified rounds 3-12): a/b-frag lane(l16,lq)[e] =
// X[r0+l16][k0+lq*8+e]; C/D row=lq*4+i, col=l16.
template<bool OUT16>
__global__ __launch_bounds__(256, 2) void gemm128_kernel(
    const _Float16* __restrict__ A, const _Float16* __restrict__ Bt,
    void* __restrict__ Cv, const float* __restrict__ bias,
    int M, int N, int K, int ldc)
{
  __shared__ __align__(16) _Float16 Asf[128][40];
  __shared__ __align__(16) _Float16 Bsf[128][40];
  const int tid  = threadIdx.x;
  const int wv   = tid >> 6;
  const int mw   = wv >> 1, nw = wv & 1;
  const int lane = tid & 63, l16 = lane & 15, lq = lane >> 4;
  const int m0 = blockIdx.y * 128, n0 = blockIdx.x * 128;
  const int srow = tid >> 2, sk = (tid & 3) * 8;

  f32x4 acc[4][4] = {};

  const long arow0 = (long)(m0 + srow)*K + sk;
  const long arow1 = (long)(m0 + srow + 64)*K + sk;
  const long brow0 = (long)(n0 + srow)*K + sk;
  const long brow1 = (long)(n0 + srow + 64)*K + sk;

  for (int k0 = 0; k0 < K; k0 += 32) {
    *(f16x8*)&Asf[srow     ][sk] = *(const f16x8*)&A[arow0 + k0];
    *(f16x8*)&Asf[srow + 64][sk] = *(const f16x8*)&A[arow1 + k0];
    *(f16x8*)&Bsf[srow     ][sk] = *(const f16x8*)&Bt[brow0 + k0];
    *(f16x8*)&Bsf[srow + 64][sk] = *(const f16x8*)&Bt[brow1 + k0];
    __syncthreads();
    f16x8 af[4], bf[4];
    #pragma unroll
    for (int mt = 0; mt < 4; ++mt)
      af[mt] = *(const f16x8*)&Asf[mw*64 + mt*16 + l16][lq*8];
    #pragma unroll
    for (int nt = 0; nt < 4; ++nt)
      bf[nt] = *(const f16x8*)&Bsf[nw*64 + nt*16 + l16][lq*8];
    #pragma unroll
    for (int mt = 0; mt < 4; ++mt)
      #pragma unroll
      for (int nt = 0; nt < 4; ++nt)
        acc[mt][nt] = __builtin_amdgcn_mfma_f32_16x16x32_f16(af[mt], bf[nt], acc[mt][nt], 0, 0, 0);
    __syncthreads();
  }

  float*    Cf = (float*)Cv;
  _Float16* Ch = (_Float16*)Cv;
  #pragma unroll
  for (int nt = 0; nt < 4; ++nt) {
    const int col = n0 + nw*64 + nt*16 + l16;
    const float bb = bias ? bias[col] : 0.f;
    #pragma unroll
    for (int mt = 0; mt < 4; ++mt) {
      const int rb = m0 + mw*64 + mt*16 + lq*4;
      #pragma unroll
      for (int i = 0; i < 4; ++i) {
        const float val = acc[mt][nt][i] + bb;
        if (OUT16) Ch[(long)(rb+i)*ldc + col] = (_Float16)val;
        else       Cf[(long)(rb+i)*ldc + col] = val;
      }
    }
  }
}

// ---------------- fused attention: one (Q-tile, b*h) per block -----------
// (unchanged from rounds 11-12 — verified)
__global__ __launch_bounds__(256) void fused_attn_kernel(
    const _Float16* __restrict__ qkv16,  // [B*T][768]  q|k|v
    const _Float16* __restrict__ vt16,   // [B*H][64][288]
    _Float16* __restrict__ o16)          // [B*T][256]
{
  __shared__ __align__(16) _Float16 Pl[4][16][296];
  const int tid  = threadIdx.x;
  const int w    = tid >> 6;
  const int lane = tid & 63, l16 = lane & 15, lq = lane >> 4;
  const int z = blockIdx.y;            // b*4 + h
  const int b = z >> 2, h = z & 3;
  const int q0 = blockIdx.x * 64 + w * 16;
  const long rowbase = (long)b * T_;

  // ---- QK^T ----
  const _Float16* qp = qkv16 + (rowbase + q0 + l16) * 768 + h*64 + lq*8;
  f16x8 qf0 = *(const f16x8*)qp;
  f16x8 qf1 = *(const f16x8*)(qp + 32);
  f32x4 acc[18];
  const _Float16* kp = qkv16 + (rowbase + l16) * 768 + 256 + h*64 + lq*8;
  #pragma unroll
  for (int t = 0; t < 18; ++t) {
    f16x8 kf0 = *(const f16x8*)(kp + (long)t*16*768);
    f16x8 kf1 = *(const f16x8*)(kp + (long)t*16*768 + 32);
    f32x4 a = {0.f, 0.f, 0.f, 0.f};
    a = __builtin_amdgcn_mfma_f32_16x16x32_f16(qf0, kf0, a, 0, 0, 0);
    a = __builtin_amdgcn_mfma_f32_16x16x32_f16(qf1, kf1, a, 0, 0, 0);
    acc[t] = a;
  }

  // ---- row softmax + P (f16) into LDS in A-frag-readable layout ----
  #pragma unroll
  for (int r = 0; r < 4; ++r) {
    float m = -1e30f;
    #pragma unroll
    for (int t = 0; t < 18; ++t) m = fmaxf(m, acc[t][r]);
    m = fmaxf(m, __shfl_xor(m, 1)); m = fmaxf(m, __shfl_xor(m, 2));
    m = fmaxf(m, __shfl_xor(m, 4)); m = fmaxf(m, __shfl_xor(m, 8));
    float p[18];
    float s = 0.f;
    #pragma unroll
    for (int t = 0; t < 18; ++t) {
      p[t] = __expf(0.125f * (acc[t][r] - m));
      s += p[t];
    }
    s += __shfl_xor(s, 1); s += __shfl_xor(s, 2);
    s += __shfl_xor(s, 4); s += __shfl_xor(s, 8);
    const float inv = 1.f / s;
    #pragma unroll
    for (int t = 0; t < 18; ++t)
      Pl[w][lq*4 + r][t*16 + l16] = (_Float16)(p[t] * inv);
  }
  __syncthreads();

  // ---- PV ----
  f32x4 accO[4] = {{0,0,0,0},{0,0,0,0},{0,0,0,0},{0,0,0,0}};
  const _Float16* vb = vt16 + ((long)z*64 + l16)*288 + lq*8;
  #pragma unroll
  for (int ks = 0; ks < 9; ++ks) {
    f16x8 pa = *(const f16x8*)&Pl[w][l16][ks*32 + lq*8];
    #pragma unroll
    for (int n = 0; n < 4; ++n) {
      f16x8 vf = *(const f16x8*)(vb + (long)n*16*288 + ks*32);
      accO[n] = __builtin_amdgcn_mfma_f32_16x16x32_f16(pa, vf, accO[n], 0, 0, 0);
    }
  }

  // ---- write O (row-guarded) ----
  #pragma unroll
  for (int n = 0; n < 4; ++n) {
    const int col = h*64 + n*16 + l16;
    #pragma unroll
    for (int r = 0; r < 4; ++r) {
      const int row = q0 + lq*4 + r;
      if (row < T_)
        o16[(rowbase + row)*256 + col] = (_Float16)accO[n][r];
    }
  }
}

// ---------------- one-shot weight pack (both layers) ----------------------
// (unchanged from round 12 — verified)
__global__ __launch_bounds__(256) void packall_kernel(
    const float* __restrict__ gWi, const float* __restrict__ Wq,
    const float* __restrict__ Wk,  const float* __restrict__ Wv,
    const float* __restrict__ Wo,  const float* __restrict__ bq,
    const float* __restrict__ bk,  const float* __restrict__ bv,
    _Float16* __restrict__ wtWi, _Float16* __restrict__ wtQKV,
    _Float16* __restrict__ wtWo, float* __restrict__ bqkv)
{
  const int z = blockIdx.z;
  if (z >= 10) {                      // bias jobs
    if (blockIdx.x || blockIdx.y) return;
    const int li = z - 10, t = threadIdx.x;
    bqkv[li*768 + t]       = bq[li*256 + t];
    bqkv[li*768 + 256 + t] = bk[li*256 + t];
    bqkv[li*768 + 512 + t] = bv[li*256 + t];
    return;
  }
  const int i = z / 5, m = z - i*5;
  const float* src; _Float16* dst; int N;
  if (m == 0)      { src = gWi + (long)i*196608; dst = wtWi  + (long)i*196608; N = 768; }
  else if (m == 4) { src = Wo  + (long)i*65536;  dst = wtWo  + (long)i*65536;  N = 256; }
  else {
    const float* s3 = (m == 1) ? Wq : (m == 2) ? Wk : Wv;
    src = s3 + (long)i*65536; dst = wtQKV + (long)i*196608 + (long)(m-1)*65536; N = 256;
  }
  const int n0 = blockIdx.x * 32, k0 = blockIdx.y * 32;   // K = 256 always
  if (n0 >= N) return;                                    // block-uniform

  __shared__ float t[32][33];
  const int tx = threadIdx.x & 31, ty = threadIdx.x >> 5;  // 32 x 8
  #pragma unroll
  for (int j = 0; j < 4; ++j)
    t[ty + 8*j][tx] = src[(long)(k0 + ty + 8*j)*N + n0 + tx];
  __syncthreads();
  #pragma unroll
  for (int j = 0; j < 4; ++j)
    dst[(long)(n0 + ty + 8*j)*256 + k0 + tx] = (_Float16)t[tx][ty + 8*j];
}

// ---------------- V transpose: qkv16 [MT][768] -> vt16 [bh][64][288] ------
__global__ __launch_bounds__(256) void vtpack_kernel(
    const _Float16* __restrict__ qkv16, _Float16* __restrict__ vt16)
{
  __shared__ _Float16 tile[64][80];
  const int z  = blockIdx.y;          // b*4 + h
  const int t0 = blockIdx.x * 64;
  const int tr = threadIdx.x >> 2, c4 = (threadIdx.x & 3) * 16;
  const int t  = t0 + tr;
  f16x8 z8 = {};
  const _Float16* src = qkv16 + ((long)((z >> 2)*T_ + t))*768 + 512 + (z & 3)*64 + c4;
  f16x8 v0 = (t < T_) ? *(const f16x8*)src       : z8;
  f16x8 v1 = (t < T_) ? *(const f16x8*)(src + 8) : z8;
  *(f16x8*)&tile[tr][c4]     = v0;
  *(f16x8*)&tile[tr][c4 + 8] = v1;
  __syncthreads();
  _Float16* dst = vt16 + ((long)z*64 + tr)*288 + t0 + c4;
  #pragma unroll
  for (int i = 0; i < 16; ++i)
    if (t0 + c4 + i < T_) dst[i] = tile[c4 + i][tr];
}

// ---------------- fused d0 GEMV (K=16) + LayerNorm: one wave per row ------
// x[row] = LN(cgm[row]@d0_W + d0_b) ; also writes f16 copy.
// Sum order: k ascending (matches the old gemm), bias added after the sum.
__global__ __launch_bounds__(256) void d0ln_kernel(
    const float* __restrict__ cgm, const float* __restrict__ d0W,
    const float* __restrict__ d0b, const float* __restrict__ s,
    const float* __restrict__ b, float* __restrict__ out,
    _Float16* __restrict__ out16)
{
  const int wid  = threadIdx.x >> 6;
  const int lane = threadIdx.x & 63;
  const long row  = (long)blockIdx.x * 4 + wid;
  const long base = row * 256 + lane * 4;

  // cgm row (wave-uniform -> scalar loads)
  const float* cr = cgm + row * 16;
  float cs[16];
  #pragma unroll
  for (int k = 0; k < 16; ++k) cs[k] = cr[k];

  float4 v = {0.f, 0.f, 0.f, 0.f};
  #pragma unroll
  for (int k = 0; k < 16; ++k) {
    float4 wr4 = *(const float4*)(d0W + k*256 + lane*4);
    v.x += cs[k]*wr4.x; v.y += cs[k]*wr4.y;
    v.z += cs[k]*wr4.z; v.w += cs[k]*wr4.w;
  }
  float4 bb = *(const float4*)(d0b + lane*4);
  v.x += bb.x; v.y += bb.y; v.z += bb.z; v.w += bb.w;

  float m = v.x + v.y + v.z + v.w;
  for (int o = 32; o; o >>= 1) m += __shfl_xor(m, o);
  m *= (1.f/256.f);
  float4 d = { v.x - m, v.y - m, v.z - m, v.w - m };
  float var = d.x*d.x + d.y*d.y + d.z*d.z + d.w*d.w;
  for (int o = 32; o; o >>= 1) var += __shfl_xor(var, o);
  var *= (1.f/256.f);
  const float inv = rsqrtf(var + EPSF);
  float4 sv = *(const float4*)(s + lane*4);
  float4 bv = *(const float4*)(b + lane*4);
  float4 y;
  y.x = d.x*inv*sv.x + bv.x;
  y.y = d.y*inv*sv.y + bv.y;
  y.z = d.z*inv*sv.z + bv.z;
  y.w = d.w*inv*sv.w + bv.w;
  *(float4*)(out + base) = y;
  f16x4 o16 = {(_Float16)y.x, (_Float16)y.y, (_Float16)y.z, (_Float16)y.w};
  *(f16x4*)(out16 + base) = o16;
}

// ---------------- LayerNorm over 256 cols: one wave per row ----------------
// IN16: `in` is f16 (Wo-out / GRU g); skips stay f32.
template<bool IN16>
__global__ __launch_bounds__(256) void ln256_kernel(
    const void* __restrict__ in, const float* __restrict__ skip_pre,
    const float* __restrict__ skip_post,
    const float* __restrict__ s, const float* __restrict__ b,
    float* __restrict__ out, _Float16* __restrict__ out16)
{
  const int wid  = threadIdx.x >> 6;
  const int lane = threadIdx.x & 63;
  const long row  = (long)blockIdx.x * 4 + wid;
  const long base = row * 256 + lane * 4;

  float4 v;
  if (IN16) {
    f16x4 h4 = *(const f16x4*)((const _Float16*)in + base);
    v.x = (float)h4[0]; v.y = (float)h4[1];
    v.z = (float)h4[2]; v.w = (float)h4[3];
  } else {
    v = *(const float4*)((const float*)in + base);
  }
  if (skip_pre) {
    float4 sp = *(const float4*)(skip_pre + base);
    v.x += sp.x; v.y += sp.y; v.z += sp.z; v.w += sp.w;
  }
  float m = v.x + v.y + v.z + v.w;
  for (int o = 32; o; o >>= 1) m += __shfl_xor(m, o);
  m *= (1.f/256.f);
  float4 d = { v.x - m, v.y - m, v.z - m, v.w - m };
  float var = d.x*d.x + d.y*d.y + d.z*d.z + d.w*d.w;
  for (int o = 32; o; o >>= 1) var += __shfl_xor(var, o);
  var *= (1.f/256.f);
  const float inv = rsqrtf(var + EPSF);
  float4 sv = *(const float4*)(s + lane*4);
  float4 bv = *(const float4*)(b + lane*4);
  float4 y;
  y.x = d.x*inv*sv.x + bv.x;
  y.y = d.y*inv*sv.y + bv.y;
  y.z = d.z*inv*sv.z + bv.z;
  y.w = d.w*inv*sv.w + bv.w;
  if (skip_post) {
    float4 sp = *(const float4*)(skip_post + base);
    y.x += sp.x; y.y += sp.y; y.z += sp.z; y.w += sp.w;
  }
  *(float4*)(out + base) = y;
  if (out16) {
    f16x4 o16 = {(_Float16)y.x, (_Float16)y.y, (_Float16)y.z, (_Float16)y.w};
    *(f16x4*)(out16 + base) = o16;
  }
}

// ---------------- GRU scan: one workgroup per batch ----------------
// Round-8 structure (397 us, frozen). Round-14 delta is I/O ONLY:
// xg read as f16 (3 loads in the kq==0 block), g written as f16.
__global__ __launch_bounds__(1024, 1) void gru_scan_kernel(
    const _Float16* __restrict__ xg,  // [B,T,768] f16
    const float* __restrict__ Wh,     // [256,768]
    const float* __restrict__ bhn,    // [256]
    _Float16* __restrict__ g)         // [B,T,256] f16
{
  const int b   = blockIdx.x;
  const int tid = threadIdx.x;
  const int u   = tid & 255;   // unit
  const int kq  = tid >> 8;    // k-quarter (64 h values)

  __shared__ float hf[256];
  __shared__ __align__(16) h2_t hh2s[128];
  __shared__ float part[4][3][256];

  h2_t wr[32], wz[32], wn[32];
  #pragma unroll
  for (int r = 0; r < 32; ++r) {
    const float* p0 = Wh + (long)(kq*64 + 2*r)*768 + u;
    const float* p1 = p0 + 768;
    h2_t a; a.x = (_Float16)p0[0];   a.y = (_Float16)p1[0];   wr[r] = a;
    h2_t c; c.x = (_Float16)p0[256]; c.y = (_Float16)p1[256]; wz[r] = c;
    h2_t d; d.x = (_Float16)p0[512]; d.y = (_Float16)p1[512]; wn[r] = d;
  }
  float bn = (kq == 0) ? bhn[u] : 0.f;
  if (tid < 256) hf[tid] = 0.f;
  if (tid < 128) { h2_t zz; zz.x = (_Float16)0.f; zz.y = (_Float16)0.f; hh2s[tid] = zz; }
  __syncthreads();

  const _Float16* xgb = xg + (long)b*T_*768;
  _Float16* gb = g + (long)b*T_*256;

  for (int t = 0; t < T_; ++t) {
    float xr = 0.f, xz = 0.f, xn = 0.f;
    if (kq == 0) {  // prefetch input gates; latency hidden behind dot phase
      const _Float16* xt = xgb + (long)t*768;
      xr = (float)xt[u]; xz = (float)xt[u+256]; xn = (float)xt[u+512];
    }
    const float4* hq4 = (const float4*)(&hh2s[kq*32]);
    float ar = 0.f, az = 0.f, an = 0.f;
    #pragma unroll
    for (int c = 0; c < 8; ++c) {
      const float4 hc = hq4[c];   // ds_read_b128: 4 h2 pairs
      union { float f; h2_t h; } u0, u1, u2, u3;
      u0.f = hc.x; u1.f = hc.y; u2.f = hc.z; u3.f = hc.w;
#if HAS_FDOT2
      ar = __builtin_amdgcn_fdot2(u0.h, wr[c*4+0], ar, false);
      az = __builtin_amdgcn_fdot2(u0.h, wz[c*4+0], az, false);
      an = __builtin_amdgcn_fdot2(u0.h, wn[c*4+0], an, false);
      ar = __builtin_amdgcn_fdot2(u1.h, wr[c*4+1], ar, false);
      az = __builtin_amdgcn_fdot2(u1.h, wz[c*4+1], az, false);
      an = __builtin_amdgcn_fdot2(u1.h, wn[c*4+1], an, false);
      ar = __builtin_amdgcn_fdot2(u2.h, wr[c*4+2], ar, false);
      az = __builtin_amdgcn_fdot2(u2.h, wz[c*4+2], az, false);
      an = __builtin_amdgcn_fdot2(u2.h, wn[c*4+2], an, false);
      ar = __builtin_amdgcn_fdot2(u3.h, wr[c*4+3], ar, false);
      az = __builtin_amdgcn_fdot2(u3.h, wz[c*4+3], az, false);
      an = __builtin_amdgcn_fdot2(u3.h, wn[c*4+3], an, false);
#else
      ar += (float)u0.h.x*(float)wr[c*4+0].x + (float)u0.h.y*(float)wr[c*4+0].y;
      az += (float)u0.h.x*(float)wz[c*4+0].x + (float)u0.h.y*(float)wz[c*4+0].y;
      an += (float)u0.h.x*(float)wn[c*4+0].x + (float)u0.h.y*(float)wn[c*4+0].y;
      ar += (float)u1.h.x*(float)wr[c*4+1].x + (float)u1.h.y*(float)wr[c*4+1].y;
      az += (float)u1.h.x*(float)wz[c*4+1].x + (float)u1.h.y*(float)wz[c*4+1].y;
      an += (float)u1.h.x*(float)wn[c*4+1].x + (float)u1.h.y*(float)wn[c*4+1].y;
      ar += (float)u2.h.x*(float)wr[c*4+2].x + (float)u2.h.y*(float)wr[c*4+2].y;
      az += (float)u2.h.x*(float)wz[c*4+2].x + (float)u2.h.y*(float)wz[c*4+2].y;
      an += (float)u2.h.x*(float)wn[c*4+2].x + (float)u2.h.y*(float)wn[c*4+2].y;
      ar += (float)u3.h.x*(float)wr[c*4+3].x + (float)u3.h.y*(float)wr[c*4+3].y;
      az += (float)u3.h.x*(float)wz[c*4+3].x + (float)u3.h.y*(float)wz[c*4+3].y;
      an += (float)u3.h.x*(float)wn[c*4+3].x + (float)u3.h.y*(float)wn[c*4+3].y;
#endif
    }
    part[kq][0][u] = ar; part[kq][1][u] = az; part[kq][2][u] = an;
    __syncthreads();
    if (kq == 0) {
      float hr = part[0][0][u]+part[1][0][u]+part[2][0][u]+part[3][0][u] + xr;
      float hz = part[0][1][u]+part[1][1][u]+part[2][1][u]+part[3][1][u] + xz;
      float hn = part[0][2][u]+part[1][2][u]+part[2][2][u]+part[3][2][u];
      float rr = 1.f / (1.f + __expf(-hr));
      float z  = 1.f / (1.f + __expf(-hz));
      float nx = xn + rr * (hn + bn);
      float e2 = __expf(2.f * nx);
      float nv = (e2 - 1.f) / (e2 + 1.f);
      float hnew = (1.f - z) * nv + z * hf[u];
      hf[u] = hnew;
      ((_Float16*)hh2s)[u] = (_Float16)hnew;
      gb[(long)t*256 + u] = (_Float16)hnew;
    }
    __syncthreads();
  }
}

// ---------------- MLP head (mean-over-T fused): one block per batch -------
__global__ __launch_bounds__(128) void head_kernel(
    const float* __restrict__ x, const float* __restrict__ other,
    const float* __restrict__ m1W, const float* __restrict__ m1b,
    const float* __restrict__ l1s, const float* __restrict__ l1b,
    const float* __restrict__ m2W, const float* __restrict__ m2b,
    const float* __restrict__ l2s, const float* __restrict__ l2b,
    const float* __restrict__ oW,  const float* __restrict__ ob,
    float* __restrict__ outp)
{
  __shared__ float c[320];
  __shared__ float h1[128];
  __shared__ float sb[2];
  int b = blockIdx.x, tid = threadIdx.x;
  {
    const float* xb = x + (long)b*T_*256;
    float s0 = 0.f, s1 = 0.f;
    for (int t = 0; t < T_; ++t) {
      s0 += xb[(long)t*256 + tid];
      s1 += xb[(long)t*256 + tid + 128];
    }
    c[tid]       = s0 * (1.f/(float)T_);
    c[tid + 128] = s1 * (1.f/(float)T_);
  }
  if (tid < 64) c[256 + tid] = other[b*64 + tid];
  __syncthreads();
  float s = m1b[tid];
  for (int i = 0; i < 320; ++i) s += c[i] * m1W[i*128 + tid];
  s = fmaxf(s, 0.f);
  float m = s;
  for (int o = 32; o; o >>= 1) m += __shfl_xor(m, o);
  if ((tid & 63) == 0) sb[tid >> 6] = m;
  __syncthreads();
  m = (sb[0] + sb[1]) * (1.f/128.f);
  __syncthreads();
  float d = s - m, var = d*d;
  for (int o = 32; o; o >>= 1) var += __shfl_xor(var, o);
  if ((tid & 63) == 0) sb[tid >> 6] = var;
  __syncthreads();
  var = (sb[0] + sb[1]) * (1.f/128.f);
  h1[tid] = d * rsqrtf(var + EPSF) * l1s[tid] + l1b[tid];
  __syncthreads();
  if (tid < 64) {
    float s2 = m2b[tid];
    for (int i = 0; i < 128; ++i) s2 += h1[i] * m2W[i*64 + tid];
    s2 = fmaxf(s2, 0.f);
    float m2 = s2;
    for (int o = 32; o; o >>= 1) m2 += __shfl_xor(m2, o);
    m2 *= (1.f/64.f);
    float d2 = s2 - m2, v2 = d2*d2;
    for (int o = 32; o; o >>= 1) v2 += __shfl_xor(v2, o);
    v2 *= (1.f/64.f);
    float h2v = d2 * rsqrtf(v2 + EPSF) * l2s[tid] + l2b[tid];
    float y = h2v * oW[tid];
    for (int o = 32; o; o >>= 1) y += __shfl_xor(y, o);
    if (tid == 0) outp[b] = y + ob[0];
  }
}

// ---------------- host orchestration ----------------
extern "C" void kernel_launch(void* const* d_in, const int* in_sizes, int n_in,
                              void* d_out, int out_size, void* d_ws, size_t ws_size,
                              hipStream_t stream)
{
  const float* cgm   = (const float*)d_in[0];
  const float* other = (const float*)d_in[1];
  const float* d0_W  = (const float*)d_in[2];
  const float* d0_b  = (const float*)d_in[3];
  const float* ln0_s = (const float*)d_in[4];
  const float* ln0_b = (const float*)d_in[5];
  const float* gWi   = (const float*)d_in[6];
  const float* gbi   = (const float*)d_in[7];
  const float* gWh   = (const float*)d_in[8];
  const float* gbhn  = (const float*)d_in[9];
  const float* ln1_s = (const float*)d_in[10];
  const float* ln1_b = (const float*)d_in[11];
  const float* Wq    = (const float*)d_in[12];
  const float* bq    = (const float*)d_in[13];
  const float* Wk    = (const float*)d_in[14];
  const float* bk    = (const float*)d_in[15];
  const float* Wv    = (const float*)d_in[16];
  const float* bv    = (const float*)d_in[17];
  const float* Wo    = (const float*)d_in[18];
  const float* bo    = (const float*)d_in[19];
  const float* ln2_s = (const float*)d_in[20];
  const float* ln2_b = (const float*)d_in[21];
  const float* m1W   = (const float*)d_in[22];
  const float* m1b   = (const float*)d_in[23];
  const float* l1s   = (const float*)d_in[24];
  const float* l1b   = (const float*)d_in[25];
  const float* m2W   = (const float*)d_in[26];
  const float* m2b   = (const float*)d_in[27];
  const float* l2s   = (const float*)d_in[28];
  const float* l2b   = (const float*)d_in[29];
  const float* oW    = (const float*)d_in[30];
  const float* ob    = (const float*)d_in[31];
  float* out = (float*)d_out;

  // workspace layout (floats)
  float* ws   = (float*)d_ws;
  float* big  = ws;                   // xg16 | qkv16 | wo16 (f16) + vt16
  float* x    = big  + 28311552;      //  9,437,184 f32
  float* go   = x    +  9437184;      //  g16, later o16 (f16)
  float* Sbuf = go   +  9437184;      // a16 + packed weights
  (void)in_sizes; (void)n_in; (void)out_size; (void)ws_size;

  // f16 views
  _Float16* h0    = (_Float16*)Sbuf;
  _Float16* a16   = h0;                          // x16 copy
  _Float16* wtWi  = h0 + 9437184;                // 2 x 196608
  _Float16* wtQKV = h0 + 9830400;                // 2 x 196608
  _Float16* wtWo  = h0 + 10223616;               // 2 x  65536
  float*    bqkv  = Sbuf + 5177344;              // 2 x    768 floats
  _Float16* xg16  = (_Float16*)big;              // MT*768 halves
  _Float16* qkv16 = (_Float16*)big;              // MT*768 halves (after GRU)
  _Float16* wo16  = (_Float16*)big;              // MT*256 halves (after attn)
  _Float16* vt16  = (_Float16*)big + 28311552;   // B*H*64*288 halves
  _Float16* g16   = (_Float16*)go;               // MT*256 halves
  _Float16* o16   = (_Float16*)go;               // MT*256 halves (after ln1)

  // one-shot weight packing for BOTH layers
  packall_kernel<<<dim3(24, 8, 12), 256, 0, stream>>>(
      gWi, Wq, Wk, Wv, Wo, bq, bk, bv, wtWi, wtQKV, wtWo, bqkv);

  // x = LN(cgm @ d0_W + d0_b)  -- fused GEMV(K=16)+LN, + f16 copy
  d0ln_kernel<<<MT/4, 256, 0, stream>>>(cgm, d0_W, d0_b, ln0_s, ln0_b, x, a16);

  for (int i = 0; i < 2; ++i) {
    const float* Wh_i = gWh + (long)i*196608;

    // xg = x @ Wi + bi  (128^2 MFMA, F16 OUT)
    gemm128_kernel<true><<<dim3(6, 288), 256, 0, stream>>>(
        a16, wtWi + (long)i*196608, xg16, gbi + i*768, MT, 768, 256, 768);
    // GRU scan (f16 in/out; structure frozen)
    gru_scan_kernel<<<128, 1024, 0, stream>>>(xg16, Wh_i, gbhn + i*256, g16);
    // x = LN(g16) + x  (+ f16 copy)
    ln256_kernel<true><<<MT/4, 256, 0, stream>>>(
        g16, nullptr, x, ln1_s + i*256, ln1_b + i*256, x, a16);

    // qkv in one 128^2 gemm, f16 output
    gemm128_kernel<true><<<dim3(6, 288), 256, 0, stream>>>(
        a16, wtQKV + (long)i*196608, qkv16, bqkv + i*768, MT, 768, 256, 768);

    // V transpose, then fused attention
    vtpack_kernel<<<dim3(5, 512), 256, 0, stream>>>(qkv16, vt16);
    fused_attn_kernel<<<dim3(5, 512), 256, 0, stream>>>(qkv16, vt16, o16);

    // a = o16 @ Wo + bo  (f16 out; qkv16 region is dead now)
    gemm128_kernel<true><<<dim3(2, 288), 256, 0, stream>>>(
        o16, wtWo + (long)i*65536, wo16, bo + i*256, MT, 256, 256, 256);
    // x = LN(wo16 + x)  (+ f16 copy)
    ln256_kernel<true><<<MT/4, 256, 0, stream>>>(
        wo16, x, nullptr, ln2_s + i*256, ln2_b + i*256, x, a16);
  }

  head_kernel<<<128, 128, 0, stream>>>(x, other, m1W, m1b, l1s, l1b,
                                       m2W, m2b, l2s, l2b, oW, ob, out);
}

// Round 15
// 1309.249 us; speedup vs baseline: 3.3626x; 1.0188x over previous
//
#include <hip/hip_runtime.h>
#include <math.h>

// ---------------- constants ----------------
#define B_   128
#define T_   288
#define U_   256
#define H_   4
#define HD_  64
#define MT   (B_*T_)     // 36864 rows
#define EPSF 1e-6f

typedef _Float16 h2_t  __attribute__((ext_vector_type(2)));
typedef _Float16 f16x4 __attribute__((ext_vector_type(4)));
typedef _Float16 f16x8 __attribute__((ext_vector_type(8)));
typedef float    f32x4 __attribute__((ext_vector_type(4)));

#if defined(__has_builtin)
#  if __has_builtin(__builtin_amdgcn_fdot2)
#    define HAS_FDOT2 1
#  endif
#endif
#ifndef HAS_FDOT2
#  define HAS_FDOT2 0
#endif

// ---------------- f16 MFMA GEMM, 128x128 tile -----------------------------
// Round-12 verified body (register-staged LDS, padded [128][40]).
// global_load_lds variant banned (round-13 container crash).
// C[M,N] = A16[M,K] @ Bt16[N,K]^T + bias[N].  REQUIRES M%128==0, N%128==0,
// K%32==0 (callers: M=36864, N in {768,256}, K=256) -> no guards.
template<bool OUT16>
__global__ __launch_bounds__(256, 2) void gemm128_kernel(
    const _Float16* __restrict__ A, const _Float16* __restrict__ Bt,
    void* __restrict__ Cv, const float* __restrict__ bias,
    int M, int N, int K, int ldc)
{
  __shared__ __align__(16) _Float16 Asf[128][40];
  __shared__ __align__(16) _Float16 Bsf[128][40];
  const int tid  = threadIdx.x;
  const int wv   = tid >> 6;
  const int mw   = wv >> 1, nw = wv & 1;
  const int lane = tid & 63, l16 = lane & 15, lq = lane >> 4;
  const int m0 = blockIdx.y * 128, n0 = blockIdx.x * 128;
  const int srow = tid >> 2, sk = (tid & 3) * 8;

  f32x4 acc[4][4] = {};

  const long arow0 = (long)(m0 + srow)*K + sk;
  const long arow1 = (long)(m0 + srow + 64)*K + sk;
  const long brow0 = (long)(n0 + srow)*K + sk;
  const long brow1 = (long)(n0 + srow + 64)*K + sk;

  for (int k0 = 0; k0 < K; k0 += 32) {
    *(f16x8*)&Asf[srow     ][sk] = *(const f16x8*)&A[arow0 + k0];
    *(f16x8*)&Asf[srow + 64][sk] = *(const f16x8*)&A[arow1 + k0];
    *(f16x8*)&Bsf[srow     ][sk] = *(const f16x8*)&Bt[brow0 + k0];
    *(f16x8*)&Bsf[srow + 64][sk] = *(const f16x8*)&Bt[brow1 + k0];
    __syncthreads();
    f16x8 af[4], bf[4];
    #pragma unroll
    for (int mt = 0; mt < 4; ++mt)
      af[mt] = *(const f16x8*)&Asf[mw*64 + mt*16 + l16][lq*8];
    #pragma unroll
    for (int nt = 0; nt < 4; ++nt)
      bf[nt] = *(const f16x8*)&Bsf[nw*64 + nt*16 + l16][lq*8];
    #pragma unroll
    for (int mt = 0; mt < 4; ++mt)
      #pragma unroll
      for (int nt = 0; nt < 4; ++nt)
        acc[mt][nt] = __builtin_amdgcn_mfma_f32_16x16x32_f16(af[mt], bf[nt], acc[mt][nt], 0, 0, 0);
    __syncthreads();
  }

  float*    Cf = (float*)Cv;
  _Float16* Ch = (_Float16*)Cv;
  #pragma unroll
  for (int nt = 0; nt < 4; ++nt) {
    const int col = n0 + nw*64 + nt*16 + l16;
    const float bb = bias ? bias[col] : 0.f;
    #pragma unroll
    for (int mt = 0; mt < 4; ++mt) {
      const int rb = m0 + mw*64 + mt*16 + lq*4;
      #pragma unroll
      for (int i = 0; i < 4; ++i) {
        const float val = acc[mt][nt][i] + bb;
        if (OUT16) Ch[(long)(rb+i)*ldc + col] = (_Float16)val;
        else       Cf[(long)(rb+i)*ldc + col] = val;
      }
    }
  }
}

// ---------------- fused attention: one (Q-tile, b*h) per block -----------
// (unchanged from rounds 11-14 — verified)
__global__ __launch_bounds__(256) void fused_attn_kernel(
    const _Float16* __restrict__ qkv16,  // [B*T][768]  q|k|v
    const _Float16* __restrict__ vt16,   // [B*H][64][288]
    _Float16* __restrict__ o16)          // [B*T][256]
{
  __shared__ __align__(16) _Float16 Pl[4][16][296];
  const int tid  = threadIdx.x;
  const int w    = tid >> 6;
  const int lane = tid & 63, l16 = lane & 15, lq = lane >> 4;
  const int z = blockIdx.y;            // b*4 + h
  const int b = z >> 2, h = z & 3;
  const int q0 = blockIdx.x * 64 + w * 16;
  const long rowbase = (long)b * T_;

  // ---- QK^T ----
  const _Float16* qp = qkv16 + (rowbase + q0 + l16) * 768 + h*64 + lq*8;
  f16x8 qf0 = *(const f16x8*)qp;
  f16x8 qf1 = *(const f16x8*)(qp + 32);
  f32x4 acc[18];
  const _Float16* kp = qkv16 + (rowbase + l16) * 768 + 256 + h*64 + lq*8;
  #pragma unroll
  for (int t = 0; t < 18; ++t) {
    f16x8 kf0 = *(const f16x8*)(kp + (long)t*16*768);
    f16x8 kf1 = *(const f16x8*)(kp + (long)t*16*768 + 32);
    f32x4 a = {0.f, 0.f, 0.f, 0.f};
    a = __builtin_amdgcn_mfma_f32_16x16x32_f16(qf0, kf0, a, 0, 0, 0);
    a = __builtin_amdgcn_mfma_f32_16x16x32_f16(qf1, kf1, a, 0, 0, 0);
    acc[t] = a;
  }

  // ---- row softmax + P (f16) into LDS in A-frag-readable layout ----
  #pragma unroll
  for (int r = 0; r < 4; ++r) {
    float m = -1e30f;
    #pragma unroll
    for (int t = 0; t < 18; ++t) m = fmaxf(m, acc[t][r]);
    m = fmaxf(m, __shfl_xor(m, 1)); m = fmaxf(m, __shfl_xor(m, 2));
    m = fmaxf(m, __shfl_xor(m, 4)); m = fmaxf(m, __shfl_xor(m, 8));
    float p[18];
    float s = 0.f;
    #pragma unroll
    for (int t = 0; t < 18; ++t) {
      p[t] = __expf(0.125f * (acc[t][r] - m));
      s += p[t];
    }
    s += __shfl_xor(s, 1); s += __shfl_xor(s, 2);
    s += __shfl_xor(s, 4); s += __shfl_xor(s, 8);
    const float inv = 1.f / s;
    #pragma unroll
    for (int t = 0; t < 18; ++t)
      Pl[w][lq*4 + r][t*16 + l16] = (_Float16)(p[t] * inv);
  }
  __syncthreads();

  // ---- PV ----
  f32x4 accO[4] = {{0,0,0,0},{0,0,0,0},{0,0,0,0},{0,0,0,0}};
  const _Float16* vb = vt16 + ((long)z*64 + l16)*288 + lq*8;
  #pragma unroll
  for (int ks = 0; ks < 9; ++ks) {
    f16x8 pa = *(const f16x8*)&Pl[w][l16][ks*32 + lq*8];
    #pragma unroll
    for (int n = 0; n < 4; ++n) {
      f16x8 vf = *(const f16x8*)(vb + (long)n*16*288 + ks*32);
      accO[n] = __builtin_amdgcn_mfma_f32_16x16x32_f16(pa, vf, accO[n], 0, 0, 0);
    }
  }

  // ---- write O (row-guarded) ----
  #pragma unroll
  for (int n = 0; n < 4; ++n) {
    const int col = h*64 + n*16 + l16;
    #pragma unroll
    for (int r = 0; r < 4; ++r) {
      const int row = q0 + lq*4 + r;
      if (row < T_)
        o16[(rowbase + row)*256 + col] = (_Float16)accO[n][r];
    }
  }
}

// ---------------- one-shot weight pack (both layers) ----------------------
// (unchanged from rounds 12-14 — verified)
__global__ __launch_bounds__(256) void packall_kernel(
    const float* __restrict__ gWi, const float* __restrict__ Wq,
    const float* __restrict__ Wk,  const float* __restrict__ Wv,
    const float* __restrict__ Wo,  const float* __restrict__ bq,
    const float* __restrict__ bk,  const float* __restrict__ bv,
    _Float16* __restrict__ wtWi, _Float16* __restrict__ wtQKV,
    _Float16* __restrict__ wtWo, float* __restrict__ bqkv)
{
  const int z = blockIdx.z;
  if (z >= 10) {                      // bias jobs
    if (blockIdx.x || blockIdx.y) return;
    const int li = z - 10, t = threadIdx.x;
    bqkv[li*768 + t]       = bq[li*256 + t];
    bqkv[li*768 + 256 + t] = bk[li*256 + t];
    bqkv[li*768 + 512 + t] = bv[li*256 + t];
    return;
  }
  const int i = z / 5, m = z - i*5;
  const float* src; _Float16* dst; int N;
  if (m == 0)      { src = gWi + (long)i*196608; dst = wtWi  + (long)i*196608; N = 768; }
  else if (m == 4) { src = Wo  + (long)i*65536;  dst = wtWo  + (long)i*65536;  N = 256; }
  else {
    const float* s3 = (m == 1) ? Wq : (m == 2) ? Wk : Wv;
    src = s3 + (long)i*65536; dst = wtQKV + (long)i*196608 + (long)(m-1)*65536; N = 256;
  }
  const int n0 = blockIdx.x * 32, k0 = blockIdx.y * 32;   // K = 256 always
  if (n0 >= N) return;                                    // block-uniform

  __shared__ float t[32][33];
  const int tx = threadIdx.x & 31, ty = threadIdx.x >> 5;  // 32 x 8
  #pragma unroll
  for (int j = 0; j < 4; ++j)
    t[ty + 8*j][tx] = src[(long)(k0 + ty + 8*j)*N + n0 + tx];
  __syncthreads();
  #pragma unroll
  for (int j = 0; j < 4; ++j)
    dst[(long)(n0 + ty + 8*j)*256 + k0 + tx] = (_Float16)t[tx][ty + 8*j];
}

// ---------------- V transpose: qkv16 [MT][768] -> vt16 [bh][64][288] ------
__global__ __launch_bounds__(256) void vtpack_kernel(
    const _Float16* __restrict__ qkv16, _Float16* __restrict__ vt16)
{
  __shared__ _Float16 tile[64][80];
  const int z  = blockIdx.y;          // b*4 + h
  const int t0 = blockIdx.x * 64;
  const int tr = threadIdx.x >> 2, c4 = (threadIdx.x & 3) * 16;
  const int t  = t0 + tr;
  f16x8 z8 = {};
  const _Float16* src = qkv16 + ((long)((z >> 2)*T_ + t))*768 + 512 + (z & 3)*64 + c4;
  f16x8 v0 = (t < T_) ? *(const f16x8*)src       : z8;
  f16x8 v1 = (t < T_) ? *(const f16x8*)(src + 8) : z8;
  *(f16x8*)&tile[tr][c4]     = v0;
  *(f16x8*)&tile[tr][c4 + 8] = v1;
  __syncthreads();
  _Float16* dst = vt16 + ((long)z*64 + tr)*288 + t0 + c4;
  #pragma unroll
  for (int i = 0; i < 16; ++i)
    if (t0 + c4 + i < T_) dst[i] = tile[c4 + i][tr];
}

// ---------------- fused d0 GEMV (K=16) + LayerNorm: one wave per row ------
// x16[row] = f16(LN(cgm[row]@d0_W + d0_b)). Sum order: k ascending.
__global__ __launch_bounds__(256) void d0ln_kernel(
    const float* __restrict__ cgm, const float* __restrict__ d0W,
    const float* __restrict__ d0b, const float* __restrict__ s,
    const float* __restrict__ b, _Float16* __restrict__ out16)
{
  const int wid  = threadIdx.x >> 6;
  const int lane = threadIdx.x & 63;
  const long row  = (long)blockIdx.x * 4 + wid;
  const long base = row * 256 + lane * 4;

  const float* cr = cgm + row * 16;
  float cs[16];
  #pragma unroll
  for (int k = 0; k < 16; ++k) cs[k] = cr[k];

  float4 v = {0.f, 0.f, 0.f, 0.f};
  #pragma unroll
  for (int k = 0; k < 16; ++k) {
    float4 wr4 = *(const float4*)(d0W + k*256 + lane*4);
    v.x += cs[k]*wr4.x; v.y += cs[k]*wr4.y;
    v.z += cs[k]*wr4.z; v.w += cs[k]*wr4.w;
  }
  float4 bb = *(const float4*)(d0b + lane*4);
  v.x += bb.x; v.y += bb.y; v.z += bb.z; v.w += bb.w;

  float m = v.x + v.y + v.z + v.w;
  for (int o = 32; o; o >>= 1) m += __shfl_xor(m, o);
  m *= (1.f/256.f);
  float4 d = { v.x - m, v.y - m, v.z - m, v.w - m };
  float var = d.x*d.x + d.y*d.y + d.z*d.z + d.w*d.w;
  for (int o = 32; o; o >>= 1) var += __shfl_xor(var, o);
  var *= (1.f/256.f);
  const float inv = rsqrtf(var + EPSF);
  float4 sv = *(const float4*)(s + lane*4);
  float4 bv = *(const float4*)(b + lane*4);
  f16x4 o16 = {(_Float16)(d.x*inv*sv.x + bv.x),
               (_Float16)(d.y*inv*sv.y + bv.y),
               (_Float16)(d.z*inv*sv.z + bv.z),
               (_Float16)(d.w*inv*sv.w + bv.w)};
  *(f16x4*)(out16 + base) = o16;
}

// ---------------- all-f16 LayerNorm over 256 cols: one wave per row -------
// PRE=true : y = f16( LN(in + skip) )         (attention block)
// PRE=false: y = f16( LN(in) + skip )         (GRU block)
// In-place safe when out==skip: each thread reads its own 4 elems first.
template<bool PRE>
__global__ __launch_bounds__(256) void ln256f16_kernel(
    const _Float16* __restrict__ in, const _Float16* __restrict__ skip,
    const float* __restrict__ s, const float* __restrict__ b,
    _Float16* __restrict__ out)
{
  const int wid  = threadIdx.x >> 6;
  const int lane = threadIdx.x & 63;
  const long row  = (long)blockIdx.x * 4 + wid;
  const long base = row * 256 + lane * 4;

  f16x4 h4 = *(const f16x4*)(in + base);
  f16x4 k4 = *(const f16x4*)(skip + base);
  float4 v = {(float)h4[0], (float)h4[1], (float)h4[2], (float)h4[3]};
  float4 sk = {(float)k4[0], (float)k4[1], (float)k4[2], (float)k4[3]};
  if (PRE) { v.x += sk.x; v.y += sk.y; v.z += sk.z; v.w += sk.w; }

  float m = v.x + v.y + v.z + v.w;
  for (int o = 32; o; o >>= 1) m += __shfl_xor(m, o);
  m *= (1.f/256.f);
  float4 d = { v.x - m, v.y - m, v.z - m, v.w - m };
  float var = d.x*d.x + d.y*d.y + d.z*d.z + d.w*d.w;
  for (int o = 32; o; o >>= 1) var += __shfl_xor(var, o);
  var *= (1.f/256.f);
  const float inv = rsqrtf(var + EPSF);
  float4 sv = *(const float4*)(s + lane*4);
  float4 bv = *(const float4*)(b + lane*4);
  float4 y;
  y.x = d.x*inv*sv.x + bv.x;
  y.y = d.y*inv*sv.y + bv.y;
  y.z = d.z*inv*sv.z + bv.z;
  y.w = d.w*inv*sv.w + bv.w;
  if (!PRE) { y.x += sk.x; y.y += sk.y; y.z += sk.z; y.w += sk.w; }
  f16x4 o16 = {(_Float16)y.x, (_Float16)y.y, (_Float16)y.z, (_Float16)y.w};
  *(f16x4*)(out + base) = o16;
}

// ---------------- GRU scan: one workgroup per batch ----------------
// Round-8 structure (frozen; 383 us with f16 I/O as of round 14).
__global__ __launch_bounds__(1024, 1) void gru_scan_kernel(
    const _Float16* __restrict__ xg,  // [B,T,768] f16
    const float* __restrict__ Wh,     // [256,768]
    const float* __restrict__ bhn,    // [256]
    _Float16* __restrict__ g)         // [B,T,256] f16
{
  const int b   = blockIdx.x;
  const int tid = threadIdx.x;
  const int u   = tid & 255;   // unit
  const int kq  = tid >> 8;    // k-quarter (64 h values)

  __shared__ float hf[256];
  __shared__ __align__(16) h2_t hh2s[128];
  __shared__ float part[4][3][256];

  h2_t wr[32], wz[32], wn[32];
  #pragma unroll
  for (int r = 0; r < 32; ++r) {
    const float* p0 = Wh + (long)(kq*64 + 2*r)*768 + u;
    const float* p1 = p0 + 768;
    h2_t a; a.x = (_Float16)p0[0];   a.y = (_Float16)p1[0];   wr[r] = a;
    h2_t c; c.x = (_Float16)p0[256]; c.y = (_Float16)p1[256]; wz[r] = c;
    h2_t d; d.x = (_Float16)p0[512]; d.y = (_Float16)p1[512]; wn[r] = d;
  }
  float bn = (kq == 0) ? bhn[u] : 0.f;
  if (tid < 256) hf[tid] = 0.f;
  if (tid < 128) { h2_t zz; zz.x = (_Float16)0.f; zz.y = (_Float16)0.f; hh2s[tid] = zz; }
  __syncthreads();

  const _Float16* xgb = xg + (long)b*T_*768;
  _Float16* gb = g + (long)b*T_*256;

  for (int t = 0; t < T_; ++t) {
    float xr = 0.f, xz = 0.f, xn = 0.f;
    if (kq == 0) {  // prefetch input gates; latency hidden behind dot phase
      const _Float16* xt = xgb + (long)t*768;
      xr = (float)xt[u]; xz = (float)xt[u+256]; xn = (float)xt[u+512];
    }
    const float4* hq4 = (const float4*)(&hh2s[kq*32]);
    float ar = 0.f, az = 0.f, an = 0.f;
    #pragma unroll
    for (int c = 0; c < 8; ++c) {
      const float4 hc = hq4[c];   // ds_read_b128: 4 h2 pairs
      union { float f; h2_t h; } u0, u1, u2, u3;
      u0.f = hc.x; u1.f = hc.y; u2.f = hc.z; u3.f = hc.w;
#if HAS_FDOT2
      ar = __builtin_amdgcn_fdot2(u0.h, wr[c*4+0], ar, false);
      az = __builtin_amdgcn_fdot2(u0.h, wz[c*4+0], az, false);
      an = __builtin_amdgcn_fdot2(u0.h, wn[c*4+0], an, false);
      ar = __builtin_amdgcn_fdot2(u1.h, wr[c*4+1], ar, false);
      az = __builtin_amdgcn_fdot2(u1.h, wz[c*4+1], az, false);
      an = __builtin_amdgcn_fdot2(u1.h, wn[c*4+1], an, false);
      ar = __builtin_amdgcn_fdot2(u2.h, wr[c*4+2], ar, false);
      az = __builtin_amdgcn_fdot2(u2.h, wz[c*4+2], az, false);
      an = __builtin_amdgcn_fdot2(u2.h, wn[c*4+2], an, false);
      ar = __builtin_amdgcn_fdot2(u3.h, wr[c*4+3], ar, false);
      az = __builtin_amdgcn_fdot2(u3.h, wz[c*4+3], az, false);
      an = __builtin_amdgcn_fdot2(u3.h, wn[c*4+3], an, false);
#else
      ar += (float)u0.h.x*(float)wr[c*4+0].x + (float)u0.h.y*(float)wr[c*4+0].y;
      az += (float)u0.h.x*(float)wz[c*4+0].x + (float)u0.h.y*(float)wz[c*4+0].y;
      an += (float)u0.h.x*(float)wn[c*4+0].x + (float)u0.h.y*(float)wn[c*4+0].y;
      ar += (float)u1.h.x*(float)wr[c*4+1].x + (float)u1.h.y*(float)wr[c*4+1].y;
      az += (float)u1.h.x*(float)wz[c*4+1].x + (float)u1.h.y*(float)wz[c*4+1].y;
      an += (float)u1.h.x*(float)wn[c*4+1].x + (float)u1.h.y*(float)wn[c*4+1].y;
      ar += (float)u2.h.x*(float)wr[c*4+2].x + (float)u2.h.y*(float)wr[c*4+2].y;
      az += (float)u2.h.x*(float)wz[c*4+2].x + (float)u2.h.y*(float)wz[c*4+2].y;
      an += (float)u2.h.x*(float)wn[c*4+2].x + (float)u2.h.y*(float)wn[c*4+2].y;
      ar += (float)u3.h.x*(float)wr[c*4+3].x + (float)u3.h.y*(float)wr[c*4+3].y;
      az += (float)u3.h.x*(float)wz[c*4+3].x + (float)u3.h.y*(float)wz[c*4+3].y;
      an += (float)u3.h.x*(float)wn[c*4+3].x + (float)u3.h.y*(float)wn[c*4+3].y;
#endif
    }
    part[kq][0][u] = ar; part[kq][1][u] = az; part[kq][2][u] = an;
    __syncthreads();
    if (kq == 0) {
      float hr = part[0][0][u]+part[1][0][u]+part[2][0][u]+part[3][0][u] + xr;
      float hz = part[0][1][u]+part[1][1][u]+part[2][1][u]+part[3][1][u] + xz;
      float hn = part[0][2][u]+part[1][2][u]+part[2][2][u]+part[3][2][u];
      float rr = 1.f / (1.f + __expf(-hr));
      float z  = 1.f / (1.f + __expf(-hz));
      float nx = xn + rr * (hn + bn);
      float e2 = __expf(2.f * nx);
      float nv = (e2 - 1.f) / (e2 + 1.f);
      float hnew = (1.f - z) * nv + z * hf[u];
      hf[u] = hnew;
      ((_Float16*)hh2s)[u] = (_Float16)hnew;
      gb[(long)t*256 + u] = (_Float16)hnew;
    }
    __syncthreads();
  }
}

// ---------------- MLP head (mean-over-T fused): one block per batch -------
// reads the f16 residual stream; accumulates in f32.
__global__ __launch_bounds__(128) void head_kernel(
    const _Float16* __restrict__ x16, const float* __restrict__ other,
    const float* __restrict__ m1W, const float* __restrict__ m1b,
    const float* __restrict__ l1s, const float* __restrict__ l1b,
    const float* __restrict__ m2W, const float* __restrict__ m2b,
    const float* __restrict__ l2s, const float* __restrict__ l2b,
    const float* __restrict__ oW,  const float* __restrict__ ob,
    float* __restrict__ outp)
{
  __shared__ float c[320];
  __shared__ float h1[128];
  __shared__ float sb[2];
  int b = blockIdx.x, tid = threadIdx.x;
  {
    const _Float16* xb = x16 + (long)b*T_*256;
    float s0 = 0.f, s1 = 0.f;
    for (int t = 0; t < T_; ++t) {
      s0 += (float)xb[(long)t*256 + tid];
      s1 += (float)xb[(long)t*256 + tid + 128];
    }
    c[tid]       = s0 * (1.f/(float)T_);
    c[tid + 128] = s1 * (1.f/(float)T_);
  }
  if (tid < 64) c[256 + tid] = other[b*64 + tid];
  __syncthreads();
  float s = m1b[tid];
  for (int i = 0; i < 320; ++i) s += c[i] * m1W[i*128 + tid];
  s = fmaxf(s, 0.f);
  float m = s;
  for (int o = 32; o; o >>= 1) m += __shfl_xor(m, o);
  if ((tid & 63) == 0) sb[tid >> 6] = m;
  __syncthreads();
  m = (sb[0] + sb[1]) * (1.f/128.f);
  __syncthreads();
  float d = s - m, var = d*d;
  for (int o = 32; o; o >>= 1) var += __shfl_xor(var, o);
  if ((tid & 63) == 0) sb[tid >> 6] = var;
  __syncthreads();
  var = (sb[0] + sb[1]) * (1.f/128.f);
  h1[tid] = d * rsqrtf(var + EPSF) * l1s[tid] + l1b[tid];
  __syncthreads();
  if (tid < 64) {
    float s2 = m2b[tid];
    for (int i = 0; i < 128; ++i) s2 += h1[i] * m2W[i*64 + tid];
    s2 = fmaxf(s2, 0.f);
    float m2 = s2;
    for (int o = 32; o; o >>= 1) m2 += __shfl_xor(m2, o);
    m2 *= (1.f/64.f);
    float d2 = s2 - m2, v2 = d2*d2;
    for (int o = 32; o; o >>= 1) v2 += __shfl_xor(v2, o);
    v2 *= (1.f/64.f);
    float h2v = d2 * rsqrtf(v2 + EPSF) * l2s[tid] + l2b[tid];
    float y = h2v * oW[tid];
    for (int o = 32; o; o >>= 1) y += __shfl_xor(y, o);
    if (tid == 0) outp[b] = y + ob[0];
  }
}

// ---------------- host orchestration ----------------
extern "C" void kernel_launch(void* const* d_in, const int* in_sizes, int n_in,
                              void* d_out, int out_size, void* d_ws, size_t ws_size,
                              hipStream_t stream)
{
  const float* cgm   = (const float*)d_in[0];
  const float* other = (const float*)d_in[1];
  const float* d0_W  = (const float*)d_in[2];
  const float* d0_b  = (const float*)d_in[3];
  const float* ln0_s = (const float*)d_in[4];
  const float* ln0_b = (const float*)d_in[5];
  const float* gWi   = (const float*)d_in[6];
  const float* gbi   = (const float*)d_in[7];
  const float* gWh   = (const float*)d_in[8];
  const float* gbhn  = (const float*)d_in[9];
  const float* ln1_s = (const float*)d_in[10];
  const float* ln1_b = (const float*)d_in[11];
  const float* Wq    = (const float*)d_in[12];
  const float* bq    = (const float*)d_in[13];
  const float* Wk    = (const float*)d_in[14];
  const float* bk    = (const float*)d_in[15];
  const float* Wv    = (const float*)d_in[16];
  const float* bv    = (const float*)d_in[17];
  const float* Wo    = (const float*)d_in[18];
  const float* bo    = (const float*)d_in[19];
  const float* ln2_s = (const float*)d_in[20];
  const float* ln2_b = (const float*)d_in[21];
  const float* m1W   = (const float*)d_in[22];
  const float* m1b   = (const float*)d_in[23];
  const float* l1s   = (const float*)d_in[24];
  const float* l1b   = (const float*)d_in[25];
  const float* m2W   = (const float*)d_in[26];
  const float* m2b   = (const float*)d_in[27];
  const float* l2s   = (const float*)d_in[28];
  const float* l2b   = (const float*)d_in[29];
  const float* oW    = (const float*)d_in[30];
  const float* ob    = (const float*)d_in[31];
  float* out = (float*)d_out;

  // workspace layout (floats)
  float* ws   = (float*)d_ws;
  float* big  = ws;                   // xg16 | qkv16 | wo16 (f16) + vt16
  float* xr   = big  + 28311552;      // (spare; x is now f16 in Sbuf region)
  float* go   = xr   +  9437184;      // g16, later o16 (f16)
  float* Sbuf = go   +  9437184;      // x16 + packed weights
  (void)in_sizes; (void)n_in; (void)out_size; (void)ws_size;

  // f16 views
  _Float16* h0    = (_Float16*)Sbuf;
  _Float16* x16   = h0;                          // residual stream, MT*256
  _Float16* wtWi  = h0 + 9437184;                // 2 x 196608
  _Float16* wtQKV = h0 + 9830400;                // 2 x 196608
  _Float16* wtWo  = h0 + 10223616;               // 2 x  65536
  float*    bqkv  = Sbuf + 5177344;              // 2 x    768 floats
  _Float16* xg16  = (_Float16*)big;              // MT*768 halves
  _Float16* qkv16 = (_Float16*)big;              // MT*768 halves (after GRU)
  _Float16* wo16  = (_Float16*)big;              // MT*256 halves (after attn)
  _Float16* vt16  = (_Float16*)big + 28311552;   // B*H*64*288 halves
  _Float16* g16   = (_Float16*)go;               // MT*256 halves
  _Float16* o16   = (_Float16*)go;               // MT*256 halves (after ln1)

  // one-shot weight packing for BOTH layers
  packall_kernel<<<dim3(24, 8, 12), 256, 0, stream>>>(
      gWi, Wq, Wk, Wv, Wo, bq, bk, bv, wtWi, wtQKV, wtWo, bqkv);

  // x16 = f16(LN(cgm @ d0_W + d0_b))  -- fused GEMV(K=16)+LN
  d0ln_kernel<<<MT/4, 256, 0, stream>>>(cgm, d0_W, d0_b, ln0_s, ln0_b, x16);

  for (int i = 0; i < 2; ++i) {
    const float* Wh_i = gWh + (long)i*196608;

    // xg = x16 @ Wi + bi  (128^2 MFMA, f16 out)
    gemm128_kernel<true><<<dim3(6, 288), 256, 0, stream>>>(
        x16, wtWi + (long)i*196608, xg16, gbi + i*768, MT, 768, 256, 768);
    // GRU scan (f16 in/out; structure frozen)
    gru_scan_kernel<<<128, 1024, 0, stream>>>(xg16, Wh_i, gbhn + i*256, g16);
    // x16 = f16( LN(g16) + x16 )  (in-place skip, POST)
    ln256f16_kernel<false><<<MT/4, 256, 0, stream>>>(
        g16, x16, ln1_s + i*256, ln1_b + i*256, x16);

    // qkv in one 128^2 gemm, f16 output
    gemm128_kernel<true><<<dim3(6, 288), 256, 0, stream>>>(
        x16, wtQKV + (long)i*196608, qkv16, bqkv + i*768, MT, 768, 256, 768);

    // V transpose, then fused attention
    vtpack_kernel<<<dim3(5, 512), 256, 0, stream>>>(qkv16, vt16);
    fused_attn_kernel<<<dim3(5, 512), 256, 0, stream>>>(qkv16, vt16, o16);

    // a = o16 @ Wo + bo  (f16 out; qkv16 region is dead now)
    gemm128_kernel<true><<<dim3(2, 288), 256, 0, stream>>>(
        o16, wtWo + (long)i*65536, wo16, bo + i*256, MT, 256, 256, 256);
    // x16 = f16( LN(wo16 + x16) )  (in-place skip, PRE)
    ln256f16_kernel<true><<<MT/4, 256, 0, stream>>>(
        wo16, x16, ln2_s + i*256, ln2_b + i*256, x16);
  }

  head_kernel<<<128, 128, 0, stream>>>(x16, other, m1W, m1b, l1s, l1b,
                                       m2W, m2b, l2s, l2b, oW, ob, out);
}